// Round 9
// baseline (782.788 us; speedup 1.0000x reference)
//
#include <hip/hip_runtime.h>
#include <hip/hip_bf16.h>
#include <math.h>

// Problem constants
#define Bq 2
#define Tq 2048
#define Cq 1024
#define Hq 16
#define Dq 64
#define Eq 8
#define HDq 1536
#define NTOK (Bq*Tq)        // 4096 tokens

typedef unsigned short u16;
typedef unsigned int u32;
typedef _Float16 f16;
typedef __bf16 bf16x8 __attribute__((ext_vector_type(8)));
typedef _Float16 f16x8 __attribute__((ext_vector_type(8)));
typedef float f32x4v __attribute__((ext_vector_type(4)));

#define MB(x) ((size_t)(x) * 262144)   // x MiB in floats

__device__ __forceinline__ float silu_f(float a) {
    return a / (1.0f + __expf(-a));
}
__device__ __forceinline__ u16 f2bf(float f) {
    union { float f; unsigned u; } a; a.f = f;
    unsigned r = a.u + 0x7fffu + ((a.u >> 16) & 1u);
    return (u16)(r >> 16);
}
__device__ __forceinline__ u16 f16bits(f16 h) {
    union { f16 f; u16 u; } a; a.f = h; return a.u;
}

// async global->LDS, 16B per lane (per-lane global addr OK; LDS side is
// wave-uniform base + lane*16)
__device__ __forceinline__ void stage16(const void* g, void* l) {
    __builtin_amdgcn_global_load_lds(
        (const __attribute__((address_space(1))) unsigned int*)g,
        (__attribute__((address_space(3))) unsigned int*)l, 16, 0, 0);
}

// ---------------------------------------------------------------------------
// RMSNorm -> split-f16 hi/lo (attention branch input)
// ---------------------------------------------------------------------------
__global__ __launch_bounds__(256) void rmsnorm_split_k(const float* __restrict__ x,
                                                       const float* __restrict__ w,
                                                       u16* __restrict__ hh,
                                                       u16* __restrict__ hl) {
    int row = blockIdx.x;
    int tid = threadIdx.x;
    const float* xr = x + (size_t)row * Cq;
    float4 v = *(const float4*)(xr + tid * 4);
    float ss = v.x*v.x + v.y*v.y + v.z*v.z + v.w*v.w;
    #pragma unroll
    for (int off = 32; off; off >>= 1) ss += __shfl_xor(ss, off);
    __shared__ float red[4];
    if ((tid & 63) == 0) red[tid >> 6] = ss;
    __syncthreads();
    float tot = red[0] + red[1] + red[2] + red[3];
    float scale = rsqrtf(tot * (1.0f / (float)Cq) + 1e-6f);
    float4 wv = *(const float4*)(w + tid * 4);
    float o[4] = { v.x*wv.x*scale, v.y*wv.y*scale, v.z*wv.z*scale, v.w*wv.w*scale };
    ushort4 oh, ol;
    u16* ph = (u16*)&oh; u16* pl = (u16*)&ol;
    #pragma unroll
    for (int i = 0; i < 4; i++) {
        f16 hi = (f16)o[i]; f16 lo = (f16)(o[i] - (float)hi);
        ph[i] = f16bits(hi); pl[i] = f16bits(lo);
    }
    *(ushort4*)(hh + (size_t)row * Cq + tid * 4) = oh;
    *(ushort4*)(hl + (size_t)row * Cq + tid * 4) = ol;
}

// ---------------------------------------------------------------------------
// RMSNorm -> fp32 + bf16 (FFN branch). Block 0 also zeroes the expert
// counters (router launches strictly after this kernel -> ordering safe).
// ---------------------------------------------------------------------------
__global__ __launch_bounds__(256) void rmsnorm2_k(const float* __restrict__ x,
                                                  const float* __restrict__ w,
                                                  float* __restrict__ hn,
                                                  u16* __restrict__ hnb,
                                                  int* __restrict__ cnt) {
    int row = blockIdx.x;
    int tid = threadIdx.x;
    if (row == 0 && tid < Eq) cnt[tid] = 0;
    const float* xr = x + (size_t)row * Cq;
    float4 v = *(const float4*)(xr + tid * 4);
    float ss = v.x*v.x + v.y*v.y + v.z*v.z + v.w*v.w;
    #pragma unroll
    for (int off = 32; off; off >>= 1) ss += __shfl_xor(ss, off);
    __shared__ float red[4];
    if ((tid & 63) == 0) red[tid >> 6] = ss;
    __syncthreads();
    float tot = red[0] + red[1] + red[2] + red[3];
    float scale = rsqrtf(tot * (1.0f / (float)Cq) + 1e-6f);
    float4 wv = *(const float4*)(w + tid * 4);
    float4 o = make_float4(v.x*wv.x*scale, v.y*wv.y*scale, v.z*wv.z*scale, v.w*wv.w*scale);
    *(float4*)(hn + (size_t)row * Cq + tid * 4) = o;
    ushort4 ob = make_ushort4(f2bf(o.x), f2bf(o.y), f2bf(o.z), f2bf(o.w));
    *(ushort4*)(hnb + (size_t)row * Cq + tid * 4) = ob;
}

// ---------------------------------------------------------------------------
// Merged weight prep (one launch):
//  y<3:  MoE fp32 -> bf16 (w1/w3/w2), 6144 blocks x 2048 elems.
//  y==3: attn fp32 -> f16 hi/lo planes (q/k/v/o), 4 x 512 blocks (x<2048).
// Identical rounding/split as always -> MFMA inputs bitwise unchanged.
// ---------------------------------------------------------------------------
__global__ __launch_bounds__(256) void wprep_k(const float* __restrict__ w1,
                                               const float* __restrict__ w3,
                                               const float* __restrict__ w2,
                                               const float* __restrict__ qw,
                                               const float* __restrict__ kw,
                                               const float* __restrict__ vw,
                                               const float* __restrict__ ow,
                                               u16* __restrict__ w1b,
                                               u16* __restrict__ w3b,
                                               u16* __restrict__ w2b,
                                               u16* __restrict__ qhp, u16* __restrict__ qlp,
                                               u16* __restrict__ khp, u16* __restrict__ klp,
                                               u16* __restrict__ vhp, u16* __restrict__ vlp,
                                               u16* __restrict__ ohp, u16* __restrict__ olp) {
    int yg = blockIdx.y;
    if (yg < 3) {
        const float* src = (yg == 0) ? w1 : ((yg == 1) ? w3 : w2);
        u16* dst = (yg == 0) ? w1b : ((yg == 1) ? w3b : w2b);
        size_t i = ((size_t)blockIdx.x * 256 + threadIdx.x) * 8;
        float4 f0 = *(const float4*)(src + i);
        float4 f1 = *(const float4*)(src + i + 4);
        ushort4 o0 = make_ushort4(f2bf(f0.x), f2bf(f0.y), f2bf(f0.z), f2bf(f0.w));
        ushort4 o1 = make_ushort4(f2bf(f1.x), f2bf(f1.y), f2bf(f1.z), f2bf(f1.w));
        *(ushort4*)(dst + i)     = o0;
        *(ushort4*)(dst + i + 4) = o1;
    } else {
        int x = blockIdx.x;
        if (x >= 2048) return;
        int a = x >> 9;
        const float* src = (a == 0) ? qw : ((a == 1) ? kw : ((a == 2) ? vw : ow));
        u16* dh = (a == 0) ? qhp : ((a == 1) ? khp : ((a == 2) ? vhp : ohp));
        u16* dl = (a == 0) ? qlp : ((a == 1) ? klp : ((a == 2) ? vlp : olp));
        size_t i = ((size_t)(x & 511) * 256 + threadIdx.x) * 8;
        float f[8];
        *(float4*)&f[0] = *(const float4*)(src + i);
        *(float4*)&f[4] = *(const float4*)(src + i + 4);
        u16 oh[8], ol[8];
        #pragma unroll
        for (int j = 0; j < 8; j++) {
            f16 hi = (f16)f[j]; f16 lo = (f16)(f[j] - (float)hi);
            oh[j] = f16bits(hi); ol[j] = f16bits(lo);
        }
        *(uint4*)(dh + i) = *(uint4*)oh;
        *(uint4*)(dl + i) = *(uint4*)ol;
    }
}

// ---------------------------------------------------------------------------
// Split-f16 MFMA GEMM, fallback version (fp32 W through registers).
// ---------------------------------------------------------------------------
__global__ __launch_bounds__(256, 3) void gemm_fused(const u16* __restrict__ Ahg,
                                                     const u16* __restrict__ Alg,
                                                     const float* __restrict__ Wq,
                                                     const float* __restrict__ Wk,
                                                     const float* __restrict__ Wv,
                                                     u16* __restrict__ qh_o,
                                                     u16* __restrict__ ql_o,
                                                     u16* __restrict__ kh_o,
                                                     u16* __restrict__ kl_o,
                                                     float* __restrict__ vf_o,
                                                     const float* __restrict__ cosb,
                                                     const float* __restrict__ sinb,
                                                     const float* __restrict__ aux,
                                                     float* __restrict__ outf,
                                                     int kind) {
    __shared__ u16 AhS[2][128*32], AlS[2][128*32], BhS[128*32], BlS[128*32];
    int tid = threadIdx.x;
    int wave = tid >> 6, lane = tid & 63;
    int wm = wave >> 1, wn = wave & 1;
    int bx = blockIdx.x, by = blockIdx.y;
    int proj, nx;
    const float* W;
    if (kind == 0) {
        proj = bx >> 3; nx = bx & 7;
        W = (proj == 0) ? Wq : ((proj == 1) ? Wk : Wv);
    } else {
        proj = 3; nx = bx; W = Wq;
    }

    int srow = tid >> 2, sch = (tid & 3) * 8;
    const u16* A0 = Ahg + (size_t)(by*128 + srow) * Cq + sch;
    const u16* A1 = A0 + (size_t)64 * Cq;
    const u16* L0 = Alg + (size_t)(by*128 + srow) * Cq + sch;
    const u16* L1 = L0 + (size_t)64 * Cq;
    const float* W0 = W + (size_t)(nx*128 + srow) * Cq + sch;
    const float* W1 = W0 + (size_t)64 * Cq;
    int lo0 = srow*32 + sch, lo1 = lo0 + 2048;

    f32x4v acc[4][4];
    #pragma unroll
    for (int i = 0; i < 4; i++)
        #pragma unroll
        for (int j = 0; j < 4; j++)
            #pragma unroll
            for (int r = 0; r < 4; r++) acc[i][j][r] = 0.0f;

    float wr0[8], wr1[8];
    stage16(A0, &AhS[0][lo0]);
    stage16(A1, &AhS[0][lo1]);
    stage16(L0, &AlS[0][lo0]);
    stage16(L1, &AlS[0][lo1]);
    *(float4*)&wr0[0] = *(const float4*)(W0);
    *(float4*)&wr0[4] = *(const float4*)(W0 + 4);
    *(float4*)&wr1[0] = *(const float4*)(W1);
    *(float4*)&wr1[4] = *(const float4*)(W1 + 4);

    int fr = lane & 15, fk = (lane >> 4) * 8;
    int cur = 0;
    for (int k0 = 0; k0 < Cq; k0 += 32, cur ^= 1) {
        __syncthreads();
        {
            f16x8 bh0, bl0, bh1, bl1;
            #pragma unroll
            for (int i = 0; i < 8; i++) {
                f16 h0 = (f16)wr0[i]; bh0[i] = h0; bl0[i] = (f16)(wr0[i] - (float)h0);
                f16 h1 = (f16)wr1[i]; bh1[i] = h1; bl1[i] = (f16)(wr1[i] - (float)h1);
            }
            *(f16x8*)(void*)&BhS[lo0] = bh0;
            *(f16x8*)(void*)&BlS[lo0] = bl0;
            *(f16x8*)(void*)&BhS[lo1] = bh1;
            *(f16x8*)(void*)&BlS[lo1] = bl1;
        }
        __syncthreads();
        int kn = k0 + 32;
        if (kn < Cq) {
            stage16(A0 + kn, &AhS[cur^1][lo0]);
            stage16(A1 + kn, &AhS[cur^1][lo1]);
            stage16(L0 + kn, &AlS[cur^1][lo0]);
            stage16(L1 + kn, &AlS[cur^1][lo1]);
            *(float4*)&wr0[0] = *(const float4*)(W0 + kn);
            *(float4*)&wr0[4] = *(const float4*)(W0 + kn + 4);
            *(float4*)&wr1[0] = *(const float4*)(W1 + kn);
            *(float4*)&wr1[4] = *(const float4*)(W1 + kn + 4);
        }
        f16x8 ah[4], al[4];
        #pragma unroll
        for (int mi = 0; mi < 4; mi++) {
            ah[mi] = *(const f16x8*)(const void*)&AhS[cur][(wm*64 + mi*16 + fr)*32 + fk];
            al[mi] = *(const f16x8*)(const void*)&AlS[cur][(wm*64 + mi*16 + fr)*32 + fk];
        }
        #pragma unroll
        for (int ni = 0; ni < 4; ni++) {
            f16x8 bhf = *(const f16x8*)(const void*)&BhS[(wn*64 + ni*16 + fr)*32 + fk];
            f16x8 blf = *(const f16x8*)(const void*)&BlS[(wn*64 + ni*16 + fr)*32 + fk];
            #pragma unroll
            for (int mi = 0; mi < 4; mi++) {
                acc[mi][ni] = __builtin_amdgcn_mfma_f32_16x16x32_f16(ah[mi], bhf, acc[mi][ni], 0, 0, 0);
                acc[mi][ni] = __builtin_amdgcn_mfma_f32_16x16x32_f16(ah[mi], blf, acc[mi][ni], 0, 0, 0);
                acc[mi][ni] = __builtin_amdgcn_mfma_f32_16x16x32_f16(al[mi], bhf, acc[mi][ni], 0, 0, 0);
            }
        }
    }

    int cr = (lane >> 4) * 4, cc = lane & 15;
    if (proj < 2) {
        u16* dh = (proj == 0) ? qh_o : kh_o;
        u16* dl = (proj == 0) ? ql_o : kl_o;
        float scale = (proj == 0) ? 0.125f : 1.0f;
        int hd = (nx * 2 + wn) * 64;
        #pragma unroll
        for (int mi = 0; mi < 4; mi++)
            #pragma unroll
            for (int r = 0; r < 4; r++) {
                int row = by*128 + wm*64 + mi*16 + cr + r;
                int t = row & (Tq - 1);
                #pragma unroll
                for (int ni = 0; ni < 2; ni++) {
                    int d0 = ni*16 + cc;
                    float a = acc[mi][ni][r];
                    float b = acc[mi][ni+2][r];
                    float c0 = cosb[t*Dq + d0],      s0 = sinb[t*Dq + d0];
                    float c1 = cosb[t*Dq + d0 + 32], s1 = sinb[t*Dq + d0 + 32];
                    float oa = (a * c0 - b * s0) * scale;
                    float ob = (b * c1 + a * s1) * scale;
                    size_t off = (size_t)row * Cq + hd + d0;
                    f16 ha = (f16)oa;
                    f16 hb = (f16)ob;
                    dh[off]      = f16bits(ha);
                    dl[off]      = f16bits((f16)(oa - (float)ha));
                    dh[off + 32] = f16bits(hb);
                    dl[off + 32] = f16bits((f16)(ob - (float)hb));
                }
            }
    } else if (proj == 2) {
        #pragma unroll
        for (int mi = 0; mi < 4; mi++)
            #pragma unroll
            for (int r = 0; r < 4; r++) {
                int row = by*128 + wm*64 + mi*16 + cr + r;
                #pragma unroll
                for (int ni = 0; ni < 4; ni++)
                    vf_o[(size_t)row * Cq + nx*128 + wn*64 + ni*16 + cc] = acc[mi][ni][r];
            }
    } else {
        #pragma unroll
        for (int mi = 0; mi < 4; mi++)
            #pragma unroll
            for (int r = 0; r < 4; r++) {
                int row = by*128 + wm*64 + mi*16 + cr + r;
                #pragma unroll
                for (int ni = 0; ni < 4; ni++) {
                    size_t off = (size_t)row * Cq + nx*128 + wn*64 + ni*16 + cc;
                    outf[off] = acc[mi][ni][r] + aux[off];
                }
            }
    }
}

// ---------------------------------------------------------------------------
// Split-f16 MFMA GEMM, fast path v3 (Round 9):
//  - A staged via stage16, double-buffered LDS (32 KiB) -> 3 blocks/CU.
//  - B per-lane f16x8 fragments from global, DOUBLE-BUFFERED IN REGISTERS:
//    B(k+32) issued right after the barrier, in flight under the 48-MFMA
//    phase; current step consumes bhc/blc. (v2 had no B lookahead -> every
//    wave ate L2 latency inside the phase; MfmaUtil 31->23.7. This restores
//    the pipelining the B-LDS path had, without its 32 KiB.)
//  - MFMA sequence and operand values unchanged -> bitwise-identical.
// ---------------------------------------------------------------------------
__global__ __launch_bounds__(256, 3) void gemm_fused2(const u16* __restrict__ Ahg,
                                                      const u16* __restrict__ Alg,
                                                      const u16* __restrict__ Bh0,
                                                      const u16* __restrict__ Bl0,
                                                      const u16* __restrict__ Bh1,
                                                      const u16* __restrict__ Bl1,
                                                      const u16* __restrict__ Bh2,
                                                      const u16* __restrict__ Bl2,
                                                      u16* __restrict__ qh_o,
                                                      u16* __restrict__ ql_o,
                                                      u16* __restrict__ kh_o,
                                                      u16* __restrict__ kl_o,
                                                      float* __restrict__ vf_o,
                                                      const float* __restrict__ cosb,
                                                      const float* __restrict__ sinb,
                                                      const float* __restrict__ aux,
                                                      float* __restrict__ outf,
                                                      int kind) {
    __shared__ u16 AhS[2][128*32], AlS[2][128*32];   // 32 KiB
    int tid = threadIdx.x;
    int wave = tid >> 6, lane = tid & 63;
    int wm = wave >> 1, wn = wave & 1;
    int bx = blockIdx.x, by = blockIdx.y;
    int proj, nx;
    const u16 *Bh, *Bl;
    if (kind == 0) {
        proj = bx >> 3; nx = bx & 7;
        Bh = (proj == 0) ? Bh0 : ((proj == 1) ? Bh1 : Bh2);
        Bl = (proj == 0) ? Bl0 : ((proj == 1) ? Bl1 : Bl2);
    } else {
        proj = 3; nx = bx; Bh = Bh0; Bl = Bl0;
    }

    int srow = tid >> 2, sch = (tid & 3) * 8;
    const u16* A0 = Ahg + (size_t)(by*128 + srow) * Cq + sch;
    const u16* A1 = A0 + (size_t)64 * Cq;
    const u16* L0 = Alg + (size_t)(by*128 + srow) * Cq + sch;
    const u16* L1 = L0 + (size_t)64 * Cq;
    int lo0 = srow*32 + sch, lo1 = lo0 + 2048;

    int fr = lane & 15, fk = (lane >> 4) * 8;
    // per-lane B fragment base offsets (row = weight row = output col)
    size_t bbase[4];
    #pragma unroll
    for (int ni = 0; ni < 4; ni++)
        bbase[ni] = (size_t)(nx*128 + wn*64 + ni*16 + fr) * Cq + fk;

    f32x4v acc[4][4];
    #pragma unroll
    for (int i = 0; i < 4; i++)
        #pragma unroll
        for (int j = 0; j < 4; j++)
            #pragma unroll
            for (int r = 0; r < 4; r++) acc[i][j][r] = 0.0f;

    // prologue: stage A(k=0) into buf 0; load B(k=0) into regs
    stage16(A0, &AhS[0][lo0]); stage16(A1, &AhS[0][lo1]);
    stage16(L0, &AlS[0][lo0]); stage16(L1, &AlS[0][lo1]);
    f16x8 bhc[4], blc[4];
    #pragma unroll
    for (int ni = 0; ni < 4; ni++) {
        bhc[ni] = *(const f16x8*)(const void*)(Bh + bbase[ni]);
        blc[ni] = *(const f16x8*)(const void*)(Bl + bbase[ni]);
    }

    int cur = 0;
    for (int k0 = 0; k0 < Cq; k0 += 32, cur ^= 1) {
        __syncthreads();   // A[cur] staged (vmcnt drained); prev reads done
        int kn = k0 + 32;
        f16x8 bhn[4], bln[4];
        if (kn < Cq) {     // prefetch next A K-tile + next B frags under MFMA
            stage16(A0 + kn, &AhS[cur^1][lo0]); stage16(A1 + kn, &AhS[cur^1][lo1]);
            stage16(L0 + kn, &AlS[cur^1][lo0]); stage16(L1 + kn, &AlS[cur^1][lo1]);
            #pragma unroll
            for (int ni = 0; ni < 4; ni++) {
                bhn[ni] = *(const f16x8*)(const void*)(Bh + bbase[ni] + kn);
                bln[ni] = *(const f16x8*)(const void*)(Bl + bbase[ni] + kn);
            }
        }
        f16x8 ah[4], al[4];
        #pragma unroll
        for (int mi = 0; mi < 4; mi++) {
            ah[mi] = *(const f16x8*)(const void*)&AhS[cur][(wm*64 + mi*16 + fr)*32 + fk];
            al[mi] = *(const f16x8*)(const void*)&AlS[cur][(wm*64 + mi*16 + fr)*32 + fk];
        }
        #pragma unroll
        for (int ni = 0; ni < 4; ni++) {
            #pragma unroll
            for (int mi = 0; mi < 4; mi++) {
                acc[mi][ni] = __builtin_amdgcn_mfma_f32_16x16x32_f16(ah[mi], bhc[ni], acc[mi][ni], 0, 0, 0);
                acc[mi][ni] = __builtin_amdgcn_mfma_f32_16x16x32_f16(ah[mi], blc[ni], acc[mi][ni], 0, 0, 0);
                acc[mi][ni] = __builtin_amdgcn_mfma_f32_16x16x32_f16(al[mi], bhc[ni], acc[mi][ni], 0, 0, 0);
            }
        }
        if (kn < Cq) {
            #pragma unroll
            for (int ni = 0; ni < 4; ni++) { bhc[ni] = bhn[ni]; blc[ni] = bln[ni]; }
        }
    }

    int cr = (lane >> 4) * 4, cc = lane & 15;
    if (proj < 2) {
        u16* dh = (proj == 0) ? qh_o : kh_o;
        u16* dl = (proj == 0) ? ql_o : kl_o;
        float scale = (proj == 0) ? 0.125f : 1.0f;
        int hd = (nx * 2 + wn) * 64;
        #pragma unroll
        for (int mi = 0; mi < 4; mi++)
            #pragma unroll
            for (int r = 0; r < 4; r++) {
                int row = by*128 + wm*64 + mi*16 + cr + r;
                int t = row & (Tq - 1);
                #pragma unroll
                for (int ni = 0; ni < 2; ni++) {
                    int d0 = ni*16 + cc;
                    float a = acc[mi][ni][r];
                    float b = acc[mi][ni+2][r];
                    float c0 = cosb[t*Dq + d0],      s0 = sinb[t*Dq + d0];
                    float c1 = cosb[t*Dq + d0 + 32], s1 = sinb[t*Dq + d0 + 32];
                    float oa = (a * c0 - b * s0) * scale;
                    float ob = (b * c1 + a * s1) * scale;
                    size_t off = (size_t)row * Cq + hd + d0;
                    f16 ha = (f16)oa;
                    f16 hb = (f16)ob;
                    dh[off]      = f16bits(ha);
                    dl[off]      = f16bits((f16)(oa - (float)ha));
                    dh[off + 32] = f16bits(hb);
                    dl[off + 32] = f16bits((f16)(ob - (float)hb));
                }
            }
    } else if (proj == 2) {
        #pragma unroll
        for (int mi = 0; mi < 4; mi++)
            #pragma unroll
            for (int r = 0; r < 4; r++) {
                int row = by*128 + wm*64 + mi*16 + cr + r;
                #pragma unroll
                for (int ni = 0; ni < 4; ni++)
                    vf_o[(size_t)row * Cq + nx*128 + wn*64 + ni*16 + cc] = acc[mi][ni][r];
            }
    } else {
        #pragma unroll
        for (int mi = 0; mi < 4; mi++)
            #pragma unroll
            for (int r = 0; r < 4; r++) {
                int row = by*128 + wm*64 + mi*16 + cr + r;
                #pragma unroll
                for (int ni = 0; ni < 4; ni++) {
                    size_t off = (size_t)row * Cq + nx*128 + wn*64 + ni*16 + cc;
                    outf[off] = acc[mi][ni][r] + aux[off];
                }
            }
    }
}

// ---------------------------------------------------------------------------
// V transpose + split: v fp32 [b][t][h*64+d] -> vth/vtl u16 [bh][d][t]
// ---------------------------------------------------------------------------
__global__ __launch_bounds__(256) void vtrans_k(const float* __restrict__ v,
                                                u16* __restrict__ vth,
                                                u16* __restrict__ vtl) {
    __shared__ u16 Th[64 * 72];
    __shared__ u16 Tl[64 * 72];
    int tc = blockIdx.x;
    int bh = blockIdx.y;
    int b = bh >> 4, h = bh & 15;
    int tid = threadIdx.x;
    int tr = tid >> 2;
    int dc = (tid & 3) * 16;
    size_t gin = ((size_t)(b * Tq + tc * 64 + tr)) * Cq + h * Dq + dc;
    #pragma unroll
    for (int i = 0; i < 16; i += 4) {
        float4 f = *(const float4*)(v + gin + i);
        float fv[4] = {f.x, f.y, f.z, f.w};
        #pragma unroll
        for (int j = 0; j < 4; j++) {
            f16 hi = (f16)fv[j];
            f16 lo = (f16)(fv[j] - (float)hi);
            Th[(dc + i + j) * 72 + tr] = f16bits(hi);
            Tl[(dc + i + j) * 72 + tr] = f16bits(lo);
        }
    }
    __syncthreads();
    int dr = tid >> 2;
    int cc = (tid & 3) * 16;
    size_t gout = ((size_t)(bh * 64 + dr)) * Tq + tc * 64 + cc;
    *(uint4*)(vth + gout)     = *(uint4*)(Th + dr * 72 + cc);
    *(uint4*)(vth + gout + 8) = *(uint4*)(Th + dr * 72 + cc + 8);
    *(uint4*)(vtl + gout)     = *(uint4*)(Tl + dr * 72 + cc);
    *(uint4*)(vtl + gout + 8) = *(uint4*)(Tl + dr * 72 + cc + 8);
}

// ---------------------------------------------------------------------------
// Flash attention, swapped-QK^T, 1024 blocks (one q-tile each, 4 blocks/CU),
// LPT order, XCD-local heads. Unchanged from Round 6.
// ---------------------------------------------------------------------------
#define AST 72
__global__ __launch_bounds__(256, 3) void attn_f16(const u16* __restrict__ qh_g,
                                                   const u16* __restrict__ ql_g,
                                                   const u16* __restrict__ kh_g,
                                                   const u16* __restrict__ kl_g,
                                                   const u16* __restrict__ vth_g,
                                                   const u16* __restrict__ vtl_g,
                                                   u16* __restrict__ yh_g,
                                                   u16* __restrict__ yl_g) {
    __shared__ u16 Kh[64*AST], Kl[64*AST];
    __shared__ u16 Vh[64*AST], Vl[64*AST];

    int id = blockIdx.x;           // 0..1023
    int bh = id & 31;              // id%8 == bh%8 -> same-head blocks share XCD
    int qt = 31 - (id >> 5);       // LPT: largest q-tiles dispatched first
    int b = bh >> 4, h = bh & 15;
    int tid = threadIdx.x;
    int wv = tid >> 6, lane = tid & 63;
    int fr = lane & 15, fg = lane >> 4;
    int sr = tid >> 2, sc = (tid & 3) * 16;

    int idx0 = fr + ((fg & 1) << 5);
    int idx1 = idx0 + 16;
    int hiw = fg >> 1;

    uint4 rkh0, rkh1, rkl0, rkl1, rvh0, rvh1, rvl0, rvl1;
    auto ldkv = [&](int kt) {
        size_t kg = ((size_t)(b * Tq + kt * 64 + sr)) * Cq + h * Dq + sc;
        size_t vg = ((size_t)(bh * 64 + sr)) * Tq + kt * 64 + sc;
        rkh0 = *(const uint4*)(kh_g + kg);  rkh1 = *(const uint4*)(kh_g + kg + 8);
        rkl0 = *(const uint4*)(kl_g + kg);  rkl1 = *(const uint4*)(kl_g + kg + 8);
        rvh0 = *(const uint4*)(vth_g + vg); rvh1 = *(const uint4*)(vth_g + vg + 8);
        rvl0 = *(const uint4*)(vtl_g + vg); rvl1 = *(const uint4*)(vtl_g + vg + 8);
    };

    size_t qg = ((size_t)(b * Tq + qt * 64 + wv * 16 + fr)) * Cq + h * Dq + fg * 8;
    f16x8 aqh0 = *(const f16x8*)(const void*)(qh_g + qg);
    f16x8 aqh1 = *(const f16x8*)(const void*)(qh_g + qg + 32);
    f16x8 aql0 = *(const f16x8*)(const void*)(ql_g + qg);
    f16x8 aql1 = *(const f16x8*)(const void*)(ql_g + qg + 32);
    ldkv(0);

    f32x4v acc_o[4];
    float m_i = -1e30f, l_i = 0.0f;   // state for q-row = wv*16+fr
    #pragma unroll
    for (int i = 0; i < 4; i++)
        #pragma unroll
        for (int r = 0; r < 4; r++) acc_o[i][r] = 0.0f;

    for (int kt = 0; kt <= qt; kt++) {
        __syncthreads();   // (a) prev MFMA done reading Ks/Vs
        *(uint4*)(Kh + sr*AST + sc)     = rkh0;
        *(uint4*)(Kh + sr*AST + sc + 8) = rkh1;
        *(uint4*)(Kl + sr*AST + sc)     = rkl0;
        *(uint4*)(Kl + sr*AST + sc + 8) = rkl1;
        *(uint4*)(Vh + sr*AST + sc)     = rvh0;
        *(uint4*)(Vh + sr*AST + sc + 8) = rvh1;
        *(uint4*)(Vl + sr*AST + sc)     = rvl0;
        *(uint4*)(Vl + sr*AST + sc + 8) = rvl1;
        __syncthreads();   // (b) K/V visible
        if (kt < qt) ldkv(kt + 1);   // prefetch under MFMA

        // S^T = K Q^T (3-term split; same partial products as S = Q K^T)
        f32x4v s[4];
        __builtin_amdgcn_s_setprio(1);
        #pragma unroll
        for (int ni = 0; ni < 4; ni++) {
            int boff = (ni * 16 + fr) * AST + fg * 8;
            f16x8 kh0 = *(const f16x8*)(const void*)(Kh + boff);
            f16x8 kh1 = *(const f16x8*)(const void*)(Kh + boff + 32);
            f16x8 kl0 = *(const f16x8*)(const void*)(Kl + boff);
            f16x8 kl1 = *(const f16x8*)(const void*)(Kl + boff + 32);
            f32x4v t;
            #pragma unroll
            for (int r = 0; r < 4; r++) t[r] = 0.0f;
            t = __builtin_amdgcn_mfma_f32_16x16x32_f16(kh0, aqh0, t, 0, 0, 0);
            t = __builtin_amdgcn_mfma_f32_16x16x32_f16(kh1, aqh1, t, 0, 0, 0);
            t = __builtin_amdgcn_mfma_f32_16x16x32_f16(kl0, aqh0, t, 0, 0, 0);
            t = __builtin_amdgcn_mfma_f32_16x16x32_f16(kl1, aqh1, t, 0, 0, 0);
            t = __builtin_amdgcn_mfma_f32_16x16x32_f16(kh0, aql0, t, 0, 0, 0);
            t = __builtin_amdgcn_mfma_f32_16x16x32_f16(kh1, aql1, t, 0, 0, 0);
            s[ni] = t;
        }
        __builtin_amdgcn_s_setprio(0);

        // causal mask: lane holds (q = wv*16+fr, k = ni*16 + fg*4 + r)
        if (kt == qt) {
            int qloc = wv * 16 + fr;
            #pragma unroll
            for (int ni = 0; ni < 4; ni++) {
                #pragma unroll
                for (int r = 0; r < 4; r++) {
                    if (ni * 16 + fg * 4 + r > qloc) s[ni][r] = -1e30f;
                }
            }
        }

        // online softmax for q = wv*16+fr (16 values/lane + 2 xor steps)
        float mx = s[0][0];
        #pragma unroll
        for (int ni = 0; ni < 4; ni++)
            #pragma unroll
            for (int r = 0; r < 4; r++) mx = fmaxf(mx, s[ni][r]);
        mx = fmaxf(mx, __shfl_xor(mx, 16));
        mx = fmaxf(mx, __shfl_xor(mx, 32));
        float mn = fmaxf(m_i, mx);
        float p[4][4];
        float rs = 0.0f;
        #pragma unroll
        for (int ni = 0; ni < 4; ni++)
            #pragma unroll
            for (int r = 0; r < 4; r++) {
                p[ni][r] = __expf(s[ni][r] - mn);
                rs += p[ni][r];
            }
        rs += __shfl_xor(rs, 16);
        rs += __shfl_xor(rs, 32);
        float alpha = __expf(m_i - mn);
        l_i = l_i * alpha + rs;
        m_i = mn;

        // rescale acc rows (row q = fg*4+r): gather alpha from lane 20*fg+r
        #pragma unroll
        for (int r = 0; r < 4; r++) {
            float ar = __shfl(alpha, 20 * fg + r);
            #pragma unroll
            for (int ni = 0; ni < 4; ni++) acc_o[ni][r] *= ar;
        }

        // pack P to f16 pairs (RNE hi + exact residual lo, same as before)
        u32 wh[8], wl[8];
        #pragma unroll
        for (int ni = 0; ni < 4; ni++) {
            #pragma unroll
            for (int pr = 0; pr < 2; pr++) {
                float pa = p[ni][pr*2], pb = p[ni][pr*2 + 1];
                f16 ha = (f16)pa, hb = (f16)pb;
                wh[ni*2 + pr] = (u32)f16bits(ha) | ((u32)f16bits(hb) << 16);
                f16 la = (f16)(pa - (float)ha), lb = (f16)(pb - (float)hb);
                wl[ni*2 + pr] = (u32)f16bits(la) | ((u32)f16bits(lb) << 16);
            }
        }

        // assemble PV A-fragments via bpermute (no LDS round-trip)
        union { u32 u[4]; f16x8 v; } fh0, fh1, fl0, fl1;
        {
            u32 a, c;
            a = __shfl((int)wh[0], idx0); c = __shfl((int)wh[2], idx0);
            fh0.u[0] = hiw ? c : a;
            a = __shfl((int)wh[1], idx0); c = __shfl((int)wh[3], idx0);
            fh0.u[1] = hiw ? c : a;
            a = __shfl((int)wh[0], idx1); c = __shfl((int)wh[2], idx1);
            fh0.u[2] = hiw ? c : a;
            a = __shfl((int)wh[1], idx1); c = __shfl((int)wh[3], idx1);
            fh0.u[3] = hiw ? c : a;
            a = __shfl((int)wh[4], idx0); c = __shfl((int)wh[6], idx0);
            fh1.u[0] = hiw ? c : a;
            a = __shfl((int)wh[5], idx0); c = __shfl((int)wh[7], idx0);
            fh1.u[1] = hiw ? c : a;
            a = __shfl((int)wh[4], idx1); c = __shfl((int)wh[6], idx1);
            fh1.u[2] = hiw ? c : a;
            a = __shfl((int)wh[5], idx1); c = __shfl((int)wh[7], idx1);
            fh1.u[3] = hiw ? c : a;
            a = __shfl((int)wl[0], idx0); c = __shfl((int)wl[2], idx0);
            fl0.u[0] = hiw ? c : a;
            a = __shfl((int)wl[1], idx0); c = __shfl((int)wl[3], idx0);
            fl0.u[1] = hiw ? c : a;
            a = __shfl((int)wl[0], idx1); c = __shfl((int)wl[2], idx1);
            fl0.u[2] = hiw ? c : a;
            a = __shfl((int)wl[1], idx1); c = __shfl((int)wl[3], idx1);
            fl0.u[3] = hiw ? c : a;
            a = __shfl((int)wl[4], idx0); c = __shfl((int)wl[6], idx0);
            fl1.u[0] = hiw ? c : a;
            a = __shfl((int)wl[5], idx0); c = __shfl((int)wl[7], idx0);
            fl1.u[1] = hiw ? c : a;
            a = __shfl((int)wl[4], idx1); c = __shfl((int)wl[6], idx1);
            fl1.u[2] = hiw ? c : a;
            a = __shfl((int)wl[5], idx1); c = __shfl((int)wl[7], idx1);
            fl1.u[3] = hiw ? c : a;
        }

        // O += P V (3-term split)
        __builtin_amdgcn_s_setprio(1);
        #pragma unroll
        for (int ni = 0; ni < 4; ni++) {
            int boff = (ni * 16 + fr) * AST + fg * 8;
            f16x8 vh0 = *(const f16x8*)(const void*)(Vh + boff);
            f16x8 vh1 = *(const f16x8*)(const void*)(Vh + boff + 32);
            f16x8 vl0 = *(const f16x8*)(const void*)(Vl + boff);
            f16x8 vl1 = *(const f16x8*)(const void*)(Vl + boff + 32);
            f32x4v t = acc_o[ni];
            t = __builtin_amdgcn_mfma_f32_16x16x32_f16(fh0.v, vh0, t, 0, 0, 0);
            t = __builtin_amdgcn_mfma_f32_16x16x32_f16(fh1.v, vh1, t, 0, 0, 0);
            t = __builtin_amdgcn_mfma_f32_16x16x32_f16(fh0.v, vl0, t, 0, 0, 0);
            t = __builtin_amdgcn_mfma_f32_16x16x32_f16(fh1.v, vl1, t, 0, 0, 0);
            t = __builtin_amdgcn_mfma_f32_16x16x32_f16(fl0.v, vh0, t, 0, 0, 0);
            t = __builtin_amdgcn_mfma_f32_16x16x32_f16(fl1.v, vh1, t, 0, 0, 0);
            acc_o[ni] = t;
        }
        __builtin_amdgcn_s_setprio(0);
    }

    // epilogue: split y write (acc rows q = fg*4+r; l from lane 20*fg+r)
    #pragma unroll
    for (int r = 0; r < 4; r++) {
        float lq = __shfl(l_i, 20 * fg + r);
        float inv = 1.0f / lq;
        int row = qt * 64 + wv * 16 + fg * 4 + r;
        size_t base = ((size_t)(b * Tq + row)) * Cq + h * Dq + fr;
        #pragma unroll
        for (int ni = 0; ni < 4; ni++) {
            float yv = acc_o[ni][r] * inv;
            f16 hi = (f16)yv;
            f16 lo = (f16)(yv - (float)hi);
            yh_g[base + ni * 16] = f16bits(hi);
            yl_g[base + ni * 16] = f16bits(lo);
        }
    }
}

// ---------------------------------------------------------------------------
// Router: fp32 logits, top-2; emit per-expert (token, gate) lists via atomics.
// ---------------------------------------------------------------------------
__global__ __launch_bounds__(64) void router_k(const float* __restrict__ hn,
                                               const float* __restrict__ rw,
                                               int* __restrict__ cnt,
                                               int* __restrict__ idxl,
                                               float* __restrict__ gvl) {
    int tkn = blockIdx.x;
    int lane = threadIdx.x;
    float acc[Eq] = {};
    for (int it = 0; it < Cq / 64; it++) {
        float hv = hn[(size_t)tkn * Cq + it * 64 + lane];
        #pragma unroll
        for (int e = 0; e < Eq; e++)
            acc[e] = fmaf(hv, rw[e * Cq + it * 64 + lane], acc[e]);
    }
    #pragma unroll
    for (int e = 0; e < Eq; e++) {
        #pragma unroll
        for (int off = 32; off; off >>= 1) acc[e] += __shfl_xor(acc[e], off);
    }
    int i0 = 0;
    #pragma unroll
    for (int e = 1; e < Eq; e++) if (acc[e] > acc[i0]) i0 = e;
    int i1 = (i0 == 0) ? 1 : 0;
    #pragma unroll
    for (int e = 0; e < Eq; e++)
        if (e != i0 && acc[e] > acc[i1]) i1 = e;
    float p1 = __expf(acc[i1] - acc[i0]);
    float g0 = 1.0f / (1.0f + p1);
    float g1 = p1 / (1.0f + p1);
    if (lane == 0) {
        int p0 = atomicAdd(&cnt[i0], 1);
        idxl[i0 * NTOK + p0] = tkn;
        gvl[i0 * NTOK + p0] = g0;
        int p1i = atomicAdd(&cnt[i1], 1);
        idxl[i1 * NTOK + p1i] = tkn;
        gvl[i1 * NTOK + p1i] = g1;
    }
}

// ---------------------------------------------------------------------------
// Setup: 128-padded segment offsets + tile->expert table (<= 72 tiles).
// ---------------------------------------------------------------------------
__global__ void setup_k(const int* __restrict__ cnt, int* __restrict__ seg,
                        int* __restrict__ texp, int* __restrict__ ttot) {
    if (threadIdx.x == 0) {
        int base = 0;
        for (int e = 0; e < Eq; e++) {
            seg[e] = base * 128;
            int t = (cnt[e] + 127) >> 7;
            for (int i = 0; i < t; i++) texp[base + i] = e;
            base += t;
        }
        *ttot = base;
    }
}

// ---------------------------------------------------------------------------
// MoE up-proj, bf16-weight fast path (m97 structure).
// ---------------------------------------------------------------------------
__global__ __launch_bounds__(256, 2) void moe_w13b(const u16* __restrict__ hnb,
                                                   const u16* __restrict__ w1b,
                                                   const u16* __restrict__ w3b,
                                                   u16* __restrict__ gbuf,
                                                   const int* __restrict__ cnt,
                                                   const int* __restrict__ seg,
                                                   const int* __restrict__ texp,
                                                   const int* __restrict__ ttot,
                                                   const int* __restrict__ idxl) {
    int by = blockIdx.y;
    if (by >= *ttot) return;
    int e = texp[by];
    const u16* w1e = w1b + (size_t)e * HDq * Cq;
    const u16* w3e = w3b + (size_t)e * HDq * Cq;
    int cnte = cnt[e], sege = seg[e];
    const int* idxe = idxl + e * NTOK;

    __shared__ u16 As[2][128*32], B1S[2][128*32], B3S[2][128*32];   // 48 KiB
    int tid = threadIdx.x;
    int wave = tid >> 6, lane = tid & 63;
    int wm = wave >> 1, wn = wave & 1;
    int bx = blockIdx.x;
    int srow = tid >> 2, sch = (tid & 3) * 8;

    int r0 = by*128 + srow, r1 = r0 + 64;
    int li0 = r0 - sege, li1 = r1 - sege;
    int tok0 = idxe[li0 < cnte ? li0 : 0];
    int tok1 = idxe[li1 < cnte ? li1 : 0];
    const u16* A0 = hnb + (size_t)tok0 * Cq + sch;
    const u16* A1 = hnb + (size_t)tok1 * Cq + sch;
    const u16* W10 = w1e + (size_t)(bx*128 + srow) * Cq + sch;
    const u16* W11 = W10 + (size_t)64 * Cq;
    const u16* W30 = w3e + (size_t)(bx*128 + srow) * Cq + sch;
    const u16* W31 = W30 + (size_t)64 * Cq;
    int lo0 = srow*32 + sch, lo1 = lo0 + 2048;

    f32x4v acc1[4][4], acc3[4][4];
    #pragma unroll
    for (int i = 0; i < 4; i++)
        #pragma unroll
        for (int j = 0; j < 4; j++)
            #pragma unroll
            for (int r = 0; r < 4; r++) { acc1[i][j][r] = 0.0f; acc3[i][j][r] = 0.0f; }

    stage16(A0,  &As[0][lo0]);  stage16(A1,  &As[0][lo1]);
    stage16(W10, &B1S[0][lo0]); stage16(W11, &B1S[0][lo1]);
    stage16(W30, &B3S[0][lo0]); stage16(W31, &B3S[0][lo1]);

    int fr = lane & 15, fk = (lane >> 4) * 8;
    int cur = 0;
    for (int k0 = 0; k0 < Cq; k0 += 32, cur ^= 1) {
        __syncthreads();
        int kn = k0 + 32;
        if (kn < Cq) {
            stage16(A0 + kn,  &As[cur^1][lo0]);  stage16(A1 + kn,  &As[cur^1][lo1]);
            stage16(W10 + kn, &B1S[cur^1][lo0]); stage16(W11 + kn, &B1S[cur^1][lo1]);
            stage16(W30 + kn, &B3S[cur^1][lo0]); stage16(W31 + kn, &B3S[cur^1][lo1]);
        }
        bf16x8 af[4];
        #pragma unroll
        for (int mi = 0; mi < 4; mi++)
            af[mi] = *(const bf16x8*)&As[cur][(wm*64 + mi*16 + fr) * 32 + fk];
        #pragma unroll
        for (int ni = 0; ni < 4; ni++) {
            bf16x8 b1f = *(const bf16x8*)&B1S[cur][(wn*64 + ni*16 + fr) * 32 + fk];
            bf16x8 b3f = *(const bf16x8*)&B3S[cur][(wn*64 + ni*16 + fr) * 32 + fk];
            #pragma unroll
            for (int mi = 0; mi < 4; mi++) {
                acc1[mi][ni] = __builtin_amdgcn_mfma_f32_16x16x32_bf16(af[mi], b1f, acc1[mi][ni], 0, 0, 0);
                acc3[mi][ni] = __builtin_amdgcn_mfma_f32_16x16x32_bf16(af[mi], b3f, acc3[mi][ni], 0, 0, 0);
            }
        }
    }

    int cr = (lane >> 4) * 4, cc = lane & 15;
    #pragma unroll
    for (int mi = 0; mi < 4; mi++)
        #pragma unroll
        for (int ni = 0; ni < 4; ni++)
            #pragma unroll
            for (int r = 0; r < 4; r++) {
                int row = by*128 + wm*64 + mi*16 + cr + r;
                int col = bx*128 + wn*64 + ni*16 + cc;
                gbuf[(size_t)row * HDq + col] = f2bf(silu_f(acc1[mi][ni][r]) * acc3[mi][ni][r]);
            }
}

// ---------------------------------------------------------------------------
// MoE down-proj, bf16-weight fast path (m97 structure).
// ---------------------------------------------------------------------------
__global__ __launch_bounds__(256, 3) void moe_w2b_k(const u16* __restrict__ gbuf,
                                                    const u16* __restrict__ w2b,
                                                    float* __restrict__ out,
                                                    const int* __restrict__ cnt,
                                                    const int* __restrict__ seg,
                                                    const int* __restrict__ texp,
                                                    const int* __restrict__ ttot,
                                                    const int* __restrict__ idxl,
                                                    const float* __restrict__ gvl) {
    int by = blockIdx.y;
    if (by >= *ttot) return;
    int e = texp[by];
    const u16* w2e = w2b + (size_t)e * Cq * HDq;
    int cnte = cnt[e], sege = seg[e];
    const int* idxe = idxl + e * NTOK;
    const float* gve = gvl + e * NTOK;

    __shared__ u16 As[2][128*32], Bs[2][128*32];   // 32 KiB
    int tid = threadIdx.x;
    int wave = tid >> 6, lane = tid & 63;
    int wm = wave >> 1, wn = wave & 1;
    int bx = blockIdx.x;
    int srow = tid >> 2, sch = (tid & 3) * 8;

    const u16* A0 = gbuf + (size_t)(by*128 + srow) * HDq + sch;
    const u16* A1 = A0 + (size_t)64 * HDq;
    const u16* W0 = w2e + (size_t)(bx*128 + srow) * HDq + sch;
    const u16* W1 = W0 + (size_t)64 * HDq;
    int lo0 = srow*32 + sch, lo1 = lo0 + 2048;

    f32x4v acc[4][4];
    #pragma unroll
    for (int i = 0; i < 4; i++)
        #pragma unroll
        for (int j = 0; j < 4; j++)
            #pragma unroll
            for (int r = 0; r < 4; r++) acc[i][j][r] = 0.0f;

    stage16(A0, &As[0][lo0]); stage16(A1, &As[0][lo1]);
    stage16(W0, &Bs[0][lo0]); stage16(W1, &Bs[0][lo1]);

    int fr = lane & 15, fk = (lane >> 4) * 8;
    int cur = 0;
    for (int k0 = 0; k0 < HDq; k0 += 32, cur ^= 1) {
        __syncthreads();
        int kn = k0 + 32;
        if (kn < HDq) {
            stage16(A0 + kn, &As[cur^1][lo0]); stage16(A1 + kn, &As[cur^1][lo1]);
            stage16(W0 + kn, &Bs[cur^1][lo0]); stage16(W1 + kn, &Bs[cur^1][lo1]);
        }
        bf16x8 af[4];
        #pragma unroll
        for (int mi = 0; mi < 4; mi++)
            af[mi] = *(const bf16x8*)&As[cur][(wm*64 + mi*16 + fr) * 32 + fk];
        #pragma unroll
        for (int ni = 0; ni < 4; ni++) {
            bf16x8 bf_ = *(const bf16x8*)&Bs[cur][(wn*64 + ni*16 + fr) * 32 + fk];
            #pragma unroll
            for (int mi = 0; mi < 4; mi++)
                acc[mi][ni] = __builtin_amdgcn_mfma_f32_16x16x32_bf16(af[mi], bf_, acc[mi][ni], 0, 0, 0);
        }
    }

    int cr = (lane >> 4) * 4, cc = lane & 15;
    #pragma unroll
    for (int mi = 0; mi < 4; mi++)
        #pragma unroll
        for (int r = 0; r < 4; r++) {
            int row = by*128 + wm*64 + mi*16 + cr + r;
            int local = row - sege;
            if (local < cnte) {
                int token = idxe[local];
                float g = gve[local];
                #pragma unroll
                for (int ni = 0; ni < 4; ni++) {
                    int col = bx*128 + wn*64 + ni*16 + cc;
                    atomicAdd(&out[(size_t)token * Cq + col], g * acc[mi][ni][r]);
                }
            }
        }
}

// ---------------------------------------------------------------------------
// MoE fp32-weight fallbacks (ws too small for bf16 planes).
// ---------------------------------------------------------------------------
__global__ __launch_bounds__(256, 2) void moe_w13(const u16* __restrict__ hnb,
                                                  const float* __restrict__ w1,
                                                  const float* __restrict__ w3,
                                                  u16* __restrict__ gbuf,
                                                  const int* __restrict__ cnt,
                                                  const int* __restrict__ seg,
                                                  const int* __restrict__ texp,
                                                  const int* __restrict__ ttot,
                                                  const int* __restrict__ idxl) {
    int by = blockIdx.y;
    if (by >= *ttot) return;
    int e = texp[by];
    const float* w1e = w1 + (size_t)e * HDq * Cq;
    const float* w3e = w3 + (size_t)e * HDq * Cq;
    int cnte = cnt[e], sege = seg[e];
    const int* idxe = idxl + e * NTOK;

    __shared__ u16 As[2][128*32], B1S[128*32], B3S[128*32];
    int tid = threadIdx.x;
    int wave = tid >> 6, lane = tid & 63;
    int wm = wave >> 1, wn = wave & 1;
    int bx = blockIdx.x;
    int srow = tid >> 2, sch = (tid & 3) * 8;

    int r0 = by*128 + srow, r1 = r0 + 64;
    int li0 = r0 - sege, li1 = r1 - sege;
    int tok0 = idxe[li0 < cnte ? li0 : 0];
    int tok1 = idxe[li1 < cnte ? li1 : 0];
    const u16* A0 = hnb + (size_t)tok0 * Cq + sch;
    const u16* A1 = hnb + (size_t)tok1 * Cq + sch;
    const float* W10 = w1e + (size_t)(bx*128 + srow) * Cq + sch;
    const float* W11 = W10 + (size_t)64 * Cq;
    const float* W30 = w3e + (size_t)(bx*128 + srow) * Cq + sch;
    const float* W31 = W30 + (size_t)64 * Cq;
    int lo0 = srow*32 + sch, lo1 = lo0 + 2048;

    f32x4v acc1[4][4], acc3[4][4];
    #pragma unroll
    for (int i = 0; i < 4; i++)
        #pragma unroll
        for (int j = 0; j < 4; j++)
            #pragma unroll
            for (int r = 0; r < 4; r++) { acc1[i][j][r] = 0.0f; acc3[i][j][r] = 0.0f; }

    float x1a[8], x1b[8], x3a[8], x3b[8];
    stage16(A0, &As[0][lo0]);
    stage16(A1, &As[0][lo1]);
    *(float4*)&x1a[0] = *(const float4*)(W10);
    *(float4*)&x1a[4] = *(const float4*)(W10 + 4);
    *(float4*)&x1b[0] = *(const float4*)(W11);
    *(float4*)&x1b[4] = *(const float4*)(W11 + 4);
    *(float4*)&x3a[0] = *(const float4*)(W30);
    *(float4*)&x3a[4] = *(const float4*)(W30 + 4);
    *(float4*)&x3b[0] = *(const float4*)(W31);
    *(float4*)&x3b[4] = *(const float4*)(W31 + 4);

    int fr = lane & 15, fk = (lane >> 4) * 8;
    int cur = 0;
    for (int k0 = 0; k0 < Cq; k0 += 32, cur ^= 1) {
        __syncthreads();
        {
            u16 t0[8], t1[8], t2[8], t3[8];
            #pragma unroll
            for (int i = 0; i < 8; i++) {
                t0[i] = f2bf(x1a[i]); t1[i] = f2bf(x1b[i]);
                t2[i] = f2bf(x3a[i]); t3[i] = f2bf(x3b[i]);
            }
            *(uint4*)&B1S[lo0] = *(uint4*)t0;
            *(uint4*)&B1S[lo1] = *(uint4*)t1;
            *(uint4*)&B3S[lo0] = *(uint4*)t2;
            *(uint4*)&B3S[lo1] = *(uint4*)t3;
        }
        __syncthreads();
        int kn = k0 + 32;
        if (kn < Cq) {
            stage16(A0 + kn, &As[cur^1][lo0]);
            stage16(A1 + kn, &As[cur^1][lo1]);
            *(float4*)&x1a[0] = *(const float4*)(W10 + kn);
            *(float4*)&x1a[4] = *(const float4*)(W10 + kn + 4);
            *(float4*)&x1b[0] = *(const float4*)(W11 + kn);
            *(float4*)&x1b[4] = *(const float4*)(W11 + kn + 4);
            *(float4*)&x3a[0] = *(const float4*)(W30 + kn);
            *(float4*)&x3a[4] = *(const float4*)(W30 + kn + 4);
            *(float4*)&x3b[0] = *(const float4*)(W31 + kn);
            *(float4*)&x3b[4] = *(const float4*)(W31 + kn + 4);
        }
        bf16x8 af[4];
        #pragma unroll
        for (int mi = 0; mi < 4; mi++)
            af[mi] = *(const bf16x8*)&As[cur][(wm*64 + mi*16 + fr) * 32 + fk];
        #pragma unroll
        for (int ni = 0; ni < 4; ni++) {
            bf16x8 b1f = *(const bf16x8*)&B1S[(wn*64 + ni*16 + fr) * 32 + fk];
            bf16x8 b3f = *(const bf16x8*)&B3S[(wn*64 + ni*16 + fr) * 32 + fk];
            #pragma unroll
            for (int mi = 0; mi < 4; mi++) {
                acc1[mi][ni] = __builtin_amdgcn_mfma_f32_16x16x32_bf16(af[mi], b1f, acc1[mi][ni], 0, 0, 0);
                acc3[mi][ni] = __builtin_amdgcn_mfma_f32_16x16x32_bf16(af[mi], b3f, acc3[mi][ni], 0, 0, 0);
            }
        }
    }

    int cr = (lane >> 4) * 4, cc = lane & 15;
    #pragma unroll
    for (int mi = 0; mi < 4; mi++)
        #pragma unroll
        for (int ni = 0; ni < 4; ni++)
            #pragma unroll
            for (int r = 0; r < 4; r++) {
                int row = by*128 + wm*64 + mi*16 + cr + r;
                int col = bx*128 + wn*64 + ni*16 + cc;
                gbuf[(size_t)row * HDq + col] = f2bf(silu_f(acc1[mi][ni][r]) * acc3[mi][ni][r]);
            }
}

__global__ __launch_bounds__(256, 3) void moe_w2(const u16* __restrict__ gbuf,
                                                 const float* __restrict__ w2,
                                                 float* __restrict__ out,
                                                 const int* __restrict__ cnt,
                                                 const int* __restrict__ seg,
                                                 const int* __restrict__ texp,
                                                 const int* __restrict__ ttot,
                                                 const int* __restrict__ idxl,
                                                 const float* __restrict__ gvl) {
    int by = blockIdx.y;
    if (by >= *ttot) return;
    int e = texp[by];
    const float* w2e = w2 + (size_t)e * Cq * HDq;
    int cnte = cnt[e], sege = seg[e];
    const int* idxe = idxl + e * NTOK;
    const float* gve = gvl + e * NTOK;

    __shared__ u16 As[2][128*32], Bs[128*32];
    int tid = threadIdx.x;
    int wave = tid >> 6, lane = tid & 63;
    int wm = wave >> 1, wn = wave & 1;
    int bx = blockIdx.x;
    int srow = tid >> 2, sch = (tid & 3) * 8;

    const u16* A0 = gbuf + (size_t)(by*128 + srow) * HDq + sch;
    const u16* A1 = A0 + (size_t)64 * HDq;
    const float* W0 = w2e + (size_t)(bx*128 + srow) * HDq + sch;
    const float* W1 = W0 + (size_t)64 * HDq;
    int lo0 = srow*32 + sch, lo1 = lo0 + 2048;

    f32x4v acc[4][4];
    #pragma unroll
    for (int i = 0; i < 4; i++)
        #pragma unroll
        for (int j = 0; j < 4; j++)
            #pragma unroll
            for (int r = 0; r < 4; r++) acc[i][j][r] = 0.0f;

    float xa[8], xb[8];
    stage16(A0, &As[0][lo0]);
    stage16(A1, &As[0][lo1]);
    *(float4*)&xa[0] = *(const float4*)(W0);
    *(float4*)&xa[4] = *(const float4*)(W0 + 4);
    *(float4*)&xb[0] = *(const float4*)(W1);
    *(float4*)&xb[4] = *(const float4*)(W1 + 4);

    int fr = lane & 15, fk = (lane >> 4) * 8;
    int cur = 0;
    for (int k0 = 0; k0 < HDq; k0 += 32, cur ^= 1) {
        __syncthreads();
        {
            u16 ta[8], tb[8];
            #pragma unroll
            for (int i = 0; i < 8; i++) { ta[i] = f2bf(xa[i]); tb[i] = f2bf(xb[i]); }
            *(uint4*)&Bs[lo0] = *(uint4*)ta;
            *(uint4*)&Bs[lo1] = *(uint4*)tb;
        }
        __syncthreads();
        int kn = k0 + 32;
        if (kn < HDq) {
            stage16(A0 + kn, &As[cur^1][lo0]);
            stage16(A1 + kn, &As[cur^1][lo1]);
            *(float4*)&xa[0] = *(const float4*)(W0 + kn);
            *(float4*)&xa[4] = *(const float4*)(W0 + kn + 4);
            *(float4*)&xb[0] = *(const float4*)(W1 + kn);
            *(float4*)&xb[4] = *(const float4*)(W1 + kn + 4);
        }
        bf16x8 af[4];
        #pragma unroll
        for (int mi = 0; mi < 4; mi++)
            af[mi] = *(const bf16x8*)&As[cur][(wm*64 + mi*16 + fr) * 32 + fk];
        #pragma unroll
        for (int ni = 0; ni < 4; ni++) {
            bf16x8 bf_ = *(const bf16x8*)&Bs[(wn*64 + ni*16 + fr) * 32 + fk];
            #pragma unroll
            for (int mi = 0; mi < 4; mi++)
                acc[mi][ni] = __builtin_amdgcn_mfma_f32_16x16x32_bf16(af[mi], bf_, acc[mi][ni], 0, 0, 0);
        }
    }

    int cr = (lane >> 4) * 4, cc = lane & 15;
    #pragma unroll
    for (int mi = 0; mi < 4; mi++)
        #pragma unroll
        for (int r = 0; r < 4; r++) {
            int row = by*128 + wm*64 + mi*16 + cr + r;
            int local = row - sege;
            if (local < cnte) {
                int token = idxe[local];
                float g = gve[local];
                #pragma unroll
                for (int ni = 0; ni < 4; ni++) {
                    int col = bx*128 + wn*64 + ni*16 + cc;
                    atomicAdd(&out[(size_t)token * Cq + col], g * acc[mi][ni][r]);
                }
            }
        }
}

// ---------------------------------------------------------------------------
// Launch
// ---------------------------------------------------------------------------
extern "C" void kernel_launch(void* const* d_in, const int* in_sizes, int n_in,
                              void* d_out, int out_size, void* d_ws, size_t ws_size,
                              hipStream_t stream) {
    (void)in_sizes; (void)n_in; (void)out_size;

    const float* x     = (const float*)d_in[0];
    const float* ropec = (const float*)d_in[1];
    const float* ropes = (const float*)d_in[2];
    const float* anw   = (const float*)d_in[3];
    const float* q_w   = (const float*)d_in[4];
    const float* k_w   = (const float*)d_in[5];
    const float* v_w   = (const float*)d_in[6];
    const float* o_w   = (const float*)d_in[7];
    const float* fnw   = (const float*)d_in[8];
    const float* rtw   = (const float*)d_in[9];
    const float* w1    = (const float*)d_in[10];
    const float* w2    = (const float*)d_in[11];
    const float* w3    = (const float*)d_in[12];
    float* out = (float*)d_out;

    // workspace map (MiB offsets):
    //  P1 (QKV): hh@0-8 hl@8-16 | vf fp32@16-32 | qh@32-40 ql@40-48 kh@48-56 kl@56-64
    //  P2 (attn): vth@0-8 vtl@8-16 (vf dead) | yh@16-24 yl@24-32 (after attn)
    //  P3 (MoE): gbuf@0-28 | hn@32-48 hnb@48-56 meta@56-57
    //  pre  (>=136 MiB): MoE bf16 weights w1b@64-88 w3b@88-112 w2b@112-136
    //  pre2 (>=152 MiB): attn f16 weight planes q@136-140 k@140-144 v@144-148 o@148-152
    float* ws = (float*)d_ws;
    u16* hh = (u16*)(ws + MB(0));
    u16* hl = (u16*)(ws + MB(8));
    float* vf = ws + MB(16);
    u16* qh = (u16*)(ws + MB(32));
    u16* ql = (u16*)(ws + MB(40));
    u16* kh = (u16*)(ws + MB(48));
    u16* kl = (u16*)(ws + MB(56));
    u16* vth = (u16*)(ws + MB(0));
    u16* vtl = (u16*)(ws + MB(8));
    u16* yh  = (u16*)(ws + MB(16));
    u16* yl  = (u16*)(ws + MB(24));
    u16* gbuf = (u16*)(ws + MB(0));           // 9216x1536 bf16 = 27 MiB
    float* hn = ws + MB(32);                  // 16 MiB fp32
    u16* hnb  = (u16*)(ws + MB(48));          // 8 MiB
    int* cntp = (int*)(ws + MB(56));
    int* segp = cntp + 8;
    int* texp = cntp + 16;    // 72 entries
    int* ttot = cntp + 96;
    int* idxl = cntp + 256;                   // 8*4096 ints
    float* gvl = (float*)(cntp + 256 + Eq*NTOK);
    u16* w1b = (u16*)(ws + MB(64));           // 24 MiB bf16
    u16* w3b = (u16*)(ws + MB(88));           // 24 MiB bf16
    u16* w2b = (u16*)(ws + MB(112));          // 24 MiB bf16
    u16* wqh = (u16*)(ws + MB(136));          // f16 planes, 2 MiB each
    u16* wql = (u16*)(ws + MB(138));
    u16* wkh = (u16*)(ws + MB(140));
    u16* wkl = (u16*)(ws + MB(142));
    u16* wvh = (u16*)(ws + MB(144));
    u16* wvl = (u16*)(ws + MB(146));
    u16* woh = (u16*)(ws + MB(148));
    u16* wol = (u16*)(ws + MB(150));

    const int M = NTOK;
    const bool pre  = ws_size >= ((size_t)136 << 20);   // MoE bf16 path
    const bool pre2 = ws_size >= ((size_t)152 << 20);   // attn f16-plane path

    // 0. merged weight prep (one launch; y=3 slice only when pre2 fits)
    if (pre)
        hipLaunchKernelGGL(wprep_k, dim3(6144, pre2 ? 4 : 3), dim3(256), 0, stream,
                           w1, w3, w2, q_w, k_w, v_w, o_w,
                           w1b, w3b, w2b,
                           wqh, wql, wkh, wkl, wvh, wvl, woh, wol);

    // 1. attn rmsnorm -> split hi/lo
    hipLaunchKernelGGL(rmsnorm_split_k, dim3(M), dim3(256), 0, stream, x, anw, hh, hl);

    // 2. fused Q,K,V projection + RoPE + split epilogues (V -> fp32 vf)
    if (pre2)
        hipLaunchKernelGGL(gemm_fused2, dim3(24, M/128), dim3(256), 0, stream,
                           hh, hl, wqh, wql, wkh, wkl, wvh, wvl,
                           qh, ql, kh, kl, vf,
                           ropec, ropes, (const float*)nullptr, (float*)nullptr, 0);
    else
        hipLaunchKernelGGL(gemm_fused, dim3(24, M/128), dim3(256), 0, stream,
                           hh, hl, q_w, k_w, v_w, qh, ql, kh, kl, vf,
                           ropec, ropes, (const float*)nullptr, (float*)nullptr, 0);

    // 3. V transpose+split -> vth/vtl (hh/hl region, dead)
    hipLaunchKernelGGL(vtrans_k, dim3(32, 32), dim3(256), 0, stream, vf, vth, vtl);

    // 4. flash attention (swapped-QK^T, 1024 blocks = 4/CU, LPT order) -> yh/yl
    hipLaunchKernelGGL(attn_f16, dim3(1024), dim3(256), 0, stream,
                       qh, ql, kh, kl, vth, vtl, yh, yl);

    // 5. O projection + residual -> out
    if (pre2)
        hipLaunchKernelGGL(gemm_fused2, dim3(8, M/128), dim3(256), 0, stream,
                           yh, yl, woh, wol,
                           (const u16*)nullptr, (const u16*)nullptr,
                           (const u16*)nullptr, (const u16*)nullptr,
                           (u16*)nullptr, (u16*)nullptr, (u16*)nullptr, (u16*)nullptr,
                           (float*)nullptr, ropec, ropes, x, out, 1);
    else
        hipLaunchKernelGGL(gemm_fused, dim3(8, M/128), dim3(256), 0, stream,
                           yh, yl, o_w, (const float*)nullptr, (const float*)nullptr,
                           (u16*)nullptr, (u16*)nullptr, (u16*)nullptr, (u16*)nullptr,
                           (float*)nullptr, ropec, ropes, x, out, 1);

    // 6. ffn rmsnorm -> hn fp32 + hnb bf16 (+ zero expert counters)
    hipLaunchKernelGGL(rmsnorm2_k, dim3(M), dim3(256), 0, stream, out, fnw, hn, hnb, cntp);

    // 7. router (fp32) -> per-expert lists; then tile table
    hipLaunchKernelGGL(router_k, dim3(M), dim3(64), 0, stream, hn, rtw, cntp, idxl, gvl);
    hipLaunchKernelGGL(setup_k, dim3(1), dim3(64), 0, stream, cntp, segp, texp, ttot);

    // 8. MoE over gathered tokens
    if (pre) {
        hipLaunchKernelGGL(moe_w13b, dim3(HDq/128, 72), dim3(256), 0, stream,
                           hnb, w1b, w3b, gbuf, cntp, segp, texp, ttot, idxl);
        hipLaunchKernelGGL(moe_w2b_k, dim3(Cq/128, 72), dim3(256), 0, stream,
                           gbuf, w2b, out, cntp, segp, texp, ttot, idxl, gvl);
    } else {
        hipLaunchKernelGGL(moe_w13, dim3(HDq/128, 72), dim3(256), 0, stream,
                           hnb, w1, w3, gbuf, cntp, segp, texp, ttot, idxl);
        hipLaunchKernelGGL(moe_w2, dim3(Cq/128, 72), dim3(256), 0, stream,
                           gbuf, w2, out, cntp, segp, texp, ttot, idxl, gvl);
    }
}

// Round 10
// 713.300 us; speedup vs baseline: 1.0974x; 1.0974x over previous
//
#include <hip/hip_runtime.h>
#include <hip/hip_bf16.h>
#include <math.h>

// Problem constants
#define Bq 2
#define Tq 2048
#define Cq 1024
#define Hq 16
#define Dq 64
#define Eq 8
#define HDq 1536
#define NTOK (Bq*Tq)        // 4096 tokens

typedef unsigned short u16;
typedef unsigned int u32;
typedef _Float16 f16;
typedef __bf16 bf16x8 __attribute__((ext_vector_type(8)));
typedef _Float16 f16x8 __attribute__((ext_vector_type(8)));
typedef float f32x4v __attribute__((ext_vector_type(4)));

#define MB(x) ((size_t)(x) * 262144)   // x MiB in floats

__device__ __forceinline__ float silu_f(float a) {
    return a / (1.0f + __expf(-a));
}
__device__ __forceinline__ u16 f2bf(float f) {
    union { float f; unsigned u; } a; a.f = f;
    unsigned r = a.u + 0x7fffu + ((a.u >> 16) & 1u);
    return (u16)(r >> 16);
}
__device__ __forceinline__ u16 f16bits(f16 h) {
    union { f16 f; u16 u; } a; a.f = h; return a.u;
}

// async global->LDS, 16B per lane (per-lane global addr OK; LDS side is
// wave-uniform base + lane*16)
__device__ __forceinline__ void stage16(const void* g, void* l) {
    __builtin_amdgcn_global_load_lds(
        (const __attribute__((address_space(1))) unsigned int*)g,
        (__attribute__((address_space(3))) unsigned int*)l, 16, 0, 0);
}

// ---------------------------------------------------------------------------
// RMSNorm -> split-f16 hi/lo (attention branch input)
// ---------------------------------------------------------------------------
__global__ __launch_bounds__(256) void rmsnorm_split_k(const float* __restrict__ x,
                                                       const float* __restrict__ w,
                                                       u16* __restrict__ hh,
                                                       u16* __restrict__ hl) {
    int row = blockIdx.x;
    int tid = threadIdx.x;
    const float* xr = x + (size_t)row * Cq;
    float4 v = *(const float4*)(xr + tid * 4);
    float ss = v.x*v.x + v.y*v.y + v.z*v.z + v.w*v.w;
    #pragma unroll
    for (int off = 32; off; off >>= 1) ss += __shfl_xor(ss, off);
    __shared__ float red[4];
    if ((tid & 63) == 0) red[tid >> 6] = ss;
    __syncthreads();
    float tot = red[0] + red[1] + red[2] + red[3];
    float scale = rsqrtf(tot * (1.0f / (float)Cq) + 1e-6f);
    float4 wv = *(const float4*)(w + tid * 4);
    float o[4] = { v.x*wv.x*scale, v.y*wv.y*scale, v.z*wv.z*scale, v.w*wv.w*scale };
    ushort4 oh, ol;
    u16* ph = (u16*)&oh; u16* pl = (u16*)&ol;
    #pragma unroll
    for (int i = 0; i < 4; i++) {
        f16 hi = (f16)o[i]; f16 lo = (f16)(o[i] - (float)hi);
        ph[i] = f16bits(hi); pl[i] = f16bits(lo);
    }
    *(ushort4*)(hh + (size_t)row * Cq + tid * 4) = oh;
    *(ushort4*)(hl + (size_t)row * Cq + tid * 4) = ol;
}

// ---------------------------------------------------------------------------
// RMSNorm -> fp32 + bf16 (FFN branch). Block 0 also zeroes the expert
// counters (router launches strictly after this kernel -> ordering safe).
// ---------------------------------------------------------------------------
__global__ __launch_bounds__(256) void rmsnorm2_k(const float* __restrict__ x,
                                                  const float* __restrict__ w,
                                                  float* __restrict__ hn,
                                                  u16* __restrict__ hnb,
                                                  int* __restrict__ cnt) {
    int row = blockIdx.x;
    int tid = threadIdx.x;
    if (row == 0 && tid < Eq) cnt[tid] = 0;
    const float* xr = x + (size_t)row * Cq;
    float4 v = *(const float4*)(xr + tid * 4);
    float ss = v.x*v.x + v.y*v.y + v.z*v.z + v.w*v.w;
    #pragma unroll
    for (int off = 32; off; off >>= 1) ss += __shfl_xor(ss, off);
    __shared__ float red[4];
    if ((tid & 63) == 0) red[tid >> 6] = ss;
    __syncthreads();
    float tot = red[0] + red[1] + red[2] + red[3];
    float scale = rsqrtf(tot * (1.0f / (float)Cq) + 1e-6f);
    float4 wv = *(const float4*)(w + tid * 4);
    float4 o = make_float4(v.x*wv.x*scale, v.y*wv.y*scale, v.z*wv.z*scale, v.w*wv.w*scale);
    *(float4*)(hn + (size_t)row * Cq + tid * 4) = o;
    ushort4 ob = make_ushort4(f2bf(o.x), f2bf(o.y), f2bf(o.z), f2bf(o.w));
    *(ushort4*)(hnb + (size_t)row * Cq + tid * 4) = ob;
}

// ---------------------------------------------------------------------------
// Merged weight prep (one launch):
//  y<3:  MoE fp32 -> bf16 (w1/w3/w2), 6144 blocks x 2048 elems.
//  y==3: attn fp32 -> f16 hi/lo planes (q/k/v/o), 4 x 512 blocks (x<2048).
// Identical rounding/split as always -> MFMA inputs bitwise unchanged.
// ---------------------------------------------------------------------------
__global__ __launch_bounds__(256) void wprep_k(const float* __restrict__ w1,
                                               const float* __restrict__ w3,
                                               const float* __restrict__ w2,
                                               const float* __restrict__ qw,
                                               const float* __restrict__ kw,
                                               const float* __restrict__ vw,
                                               const float* __restrict__ ow,
                                               u16* __restrict__ w1b,
                                               u16* __restrict__ w3b,
                                               u16* __restrict__ w2b,
                                               u16* __restrict__ qhp, u16* __restrict__ qlp,
                                               u16* __restrict__ khp, u16* __restrict__ klp,
                                               u16* __restrict__ vhp, u16* __restrict__ vlp,
                                               u16* __restrict__ ohp, u16* __restrict__ olp) {
    int yg = blockIdx.y;
    if (yg < 3) {
        const float* src = (yg == 0) ? w1 : ((yg == 1) ? w3 : w2);
        u16* dst = (yg == 0) ? w1b : ((yg == 1) ? w3b : w2b);
        size_t i = ((size_t)blockIdx.x * 256 + threadIdx.x) * 8;
        float4 f0 = *(const float4*)(src + i);
        float4 f1 = *(const float4*)(src + i + 4);
        ushort4 o0 = make_ushort4(f2bf(f0.x), f2bf(f0.y), f2bf(f0.z), f2bf(f0.w));
        ushort4 o1 = make_ushort4(f2bf(f1.x), f2bf(f1.y), f2bf(f1.z), f2bf(f1.w));
        *(ushort4*)(dst + i)     = o0;
        *(ushort4*)(dst + i + 4) = o1;
    } else {
        int x = blockIdx.x;
        if (x >= 2048) return;
        int a = x >> 9;
        const float* src = (a == 0) ? qw : ((a == 1) ? kw : ((a == 2) ? vw : ow));
        u16* dh = (a == 0) ? qhp : ((a == 1) ? khp : ((a == 2) ? vhp : ohp));
        u16* dl = (a == 0) ? qlp : ((a == 1) ? klp : ((a == 2) ? vlp : olp));
        size_t i = ((size_t)(x & 511) * 256 + threadIdx.x) * 8;
        float f[8];
        *(float4*)&f[0] = *(const float4*)(src + i);
        *(float4*)&f[4] = *(const float4*)(src + i + 4);
        u16 oh[8], ol[8];
        #pragma unroll
        for (int j = 0; j < 8; j++) {
            f16 hi = (f16)f[j]; f16 lo = (f16)(f[j] - (float)hi);
            oh[j] = f16bits(hi); ol[j] = f16bits(lo);
        }
        *(uint4*)(dh + i) = *(uint4*)oh;
        *(uint4*)(dl + i) = *(uint4*)ol;
    }
}

// ---------------------------------------------------------------------------
// Split-f16 MFMA GEMM, fallback version (fp32 W through registers).
// ---------------------------------------------------------------------------
__global__ __launch_bounds__(256, 3) void gemm_fused(const u16* __restrict__ Ahg,
                                                     const u16* __restrict__ Alg,
                                                     const float* __restrict__ Wq,
                                                     const float* __restrict__ Wk,
                                                     const float* __restrict__ Wv,
                                                     u16* __restrict__ qh_o,
                                                     u16* __restrict__ ql_o,
                                                     u16* __restrict__ kh_o,
                                                     u16* __restrict__ kl_o,
                                                     float* __restrict__ vf_o,
                                                     const float* __restrict__ cosb,
                                                     const float* __restrict__ sinb,
                                                     const float* __restrict__ aux,
                                                     float* __restrict__ outf,
                                                     int kind) {
    __shared__ u16 AhS[2][128*32], AlS[2][128*32], BhS[128*32], BlS[128*32];
    int tid = threadIdx.x;
    int wave = tid >> 6, lane = tid & 63;
    int wm = wave >> 1, wn = wave & 1;
    int bx = blockIdx.x, by = blockIdx.y;
    int proj, nx;
    const float* W;
    if (kind == 0) {
        proj = bx >> 3; nx = bx & 7;
        W = (proj == 0) ? Wq : ((proj == 1) ? Wk : Wv);
    } else {
        proj = 3; nx = bx; W = Wq;
    }

    int srow = tid >> 2, sch = (tid & 3) * 8;
    const u16* A0 = Ahg + (size_t)(by*128 + srow) * Cq + sch;
    const u16* A1 = A0 + (size_t)64 * Cq;
    const u16* L0 = Alg + (size_t)(by*128 + srow) * Cq + sch;
    const u16* L1 = L0 + (size_t)64 * Cq;
    const float* W0 = W + (size_t)(nx*128 + srow) * Cq + sch;
    const float* W1 = W0 + (size_t)64 * Cq;
    int lo0 = srow*32 + sch, lo1 = lo0 + 2048;

    f32x4v acc[4][4];
    #pragma unroll
    for (int i = 0; i < 4; i++)
        #pragma unroll
        for (int j = 0; j < 4; j++)
            #pragma unroll
            for (int r = 0; r < 4; r++) acc[i][j][r] = 0.0f;

    float wr0[8], wr1[8];
    stage16(A0, &AhS[0][lo0]);
    stage16(A1, &AhS[0][lo1]);
    stage16(L0, &AlS[0][lo0]);
    stage16(L1, &AlS[0][lo1]);
    *(float4*)&wr0[0] = *(const float4*)(W0);
    *(float4*)&wr0[4] = *(const float4*)(W0 + 4);
    *(float4*)&wr1[0] = *(const float4*)(W1);
    *(float4*)&wr1[4] = *(const float4*)(W1 + 4);

    int fr = lane & 15, fk = (lane >> 4) * 8;
    int cur = 0;
    for (int k0 = 0; k0 < Cq; k0 += 32, cur ^= 1) {
        __syncthreads();
        {
            f16x8 bh0, bl0, bh1, bl1;
            #pragma unroll
            for (int i = 0; i < 8; i++) {
                f16 h0 = (f16)wr0[i]; bh0[i] = h0; bl0[i] = (f16)(wr0[i] - (float)h0);
                f16 h1 = (f16)wr1[i]; bh1[i] = h1; bl1[i] = (f16)(wr1[i] - (float)h1);
            }
            *(f16x8*)(void*)&BhS[lo0] = bh0;
            *(f16x8*)(void*)&BlS[lo0] = bl0;
            *(f16x8*)(void*)&BhS[lo1] = bh1;
            *(f16x8*)(void*)&BlS[lo1] = bl1;
        }
        __syncthreads();
        int kn = k0 + 32;
        if (kn < Cq) {
            stage16(A0 + kn, &AhS[cur^1][lo0]);
            stage16(A1 + kn, &AhS[cur^1][lo1]);
            stage16(L0 + kn, &AlS[cur^1][lo0]);
            stage16(L1 + kn, &AlS[cur^1][lo1]);
            *(float4*)&wr0[0] = *(const float4*)(W0 + kn);
            *(float4*)&wr0[4] = *(const float4*)(W0 + kn + 4);
            *(float4*)&wr1[0] = *(const float4*)(W1 + kn);
            *(float4*)&wr1[4] = *(const float4*)(W1 + kn + 4);
        }
        f16x8 ah[4], al[4];
        #pragma unroll
        for (int mi = 0; mi < 4; mi++) {
            ah[mi] = *(const f16x8*)(const void*)&AhS[cur][(wm*64 + mi*16 + fr)*32 + fk];
            al[mi] = *(const f16x8*)(const void*)&AlS[cur][(wm*64 + mi*16 + fr)*32 + fk];
        }
        #pragma unroll
        for (int ni = 0; ni < 4; ni++) {
            f16x8 bhf = *(const f16x8*)(const void*)&BhS[(wn*64 + ni*16 + fr)*32 + fk];
            f16x8 blf = *(const f16x8*)(const void*)&BlS[(wn*64 + ni*16 + fr)*32 + fk];
            #pragma unroll
            for (int mi = 0; mi < 4; mi++) {
                acc[mi][ni] = __builtin_amdgcn_mfma_f32_16x16x32_f16(ah[mi], bhf, acc[mi][ni], 0, 0, 0);
                acc[mi][ni] = __builtin_amdgcn_mfma_f32_16x16x32_f16(ah[mi], blf, acc[mi][ni], 0, 0, 0);
                acc[mi][ni] = __builtin_amdgcn_mfma_f32_16x16x32_f16(al[mi], bhf, acc[mi][ni], 0, 0, 0);
            }
        }
    }

    int cr = (lane >> 4) * 4, cc = lane & 15;
    if (proj < 2) {
        u16* dh = (proj == 0) ? qh_o : kh_o;
        u16* dl = (proj == 0) ? ql_o : kl_o;
        float scale = (proj == 0) ? 0.125f : 1.0f;
        int hd = (nx * 2 + wn) * 64;
        #pragma unroll
        for (int mi = 0; mi < 4; mi++)
            #pragma unroll
            for (int r = 0; r < 4; r++) {
                int row = by*128 + wm*64 + mi*16 + cr + r;
                int t = row & (Tq - 1);
                #pragma unroll
                for (int ni = 0; ni < 2; ni++) {
                    int d0 = ni*16 + cc;
                    float a = acc[mi][ni][r];
                    float b = acc[mi][ni+2][r];
                    float c0 = cosb[t*Dq + d0],      s0 = sinb[t*Dq + d0];
                    float c1 = cosb[t*Dq + d0 + 32], s1 = sinb[t*Dq + d0 + 32];
                    float oa = (a * c0 - b * s0) * scale;
                    float ob = (b * c1 + a * s1) * scale;
                    size_t off = (size_t)row * Cq + hd + d0;
                    f16 ha = (f16)oa;
                    f16 hb = (f16)ob;
                    dh[off]      = f16bits(ha);
                    dl[off]      = f16bits((f16)(oa - (float)ha));
                    dh[off + 32] = f16bits(hb);
                    dl[off + 32] = f16bits((f16)(ob - (float)hb));
                }
            }
    } else if (proj == 2) {
        #pragma unroll
        for (int mi = 0; mi < 4; mi++)
            #pragma unroll
            for (int r = 0; r < 4; r++) {
                int row = by*128 + wm*64 + mi*16 + cr + r;
                #pragma unroll
                for (int ni = 0; ni < 4; ni++)
                    vf_o[(size_t)row * Cq + nx*128 + wn*64 + ni*16 + cc] = acc[mi][ni][r];
            }
    } else {
        #pragma unroll
        for (int mi = 0; mi < 4; mi++)
            #pragma unroll
            for (int r = 0; r < 4; r++) {
                int row = by*128 + wm*64 + mi*16 + cr + r;
                #pragma unroll
                for (int ni = 0; ni < 4; ni++) {
                    size_t off = (size_t)row * Cq + nx*128 + wn*64 + ni*16 + cc;
                    outf[off] = acc[mi][ni][r] + aux[off];
                }
            }
    }
}

// ---------------------------------------------------------------------------
// Split-f16 MFMA GEMM, fast path (Round-6 proven variant, REVERTED to after
// the register-B experiments of R8/R9 regressed): B pre-split f16 hi/lo
// planes staged via 16B global_load_lds into double-buffered LDS alongside
// A. 64 KiB LDS, 2 blocks/CU, ONE barrier per K-step, zero staging VALU.
// Measured 105.8 us / MfmaUtil 31% on QKV. Bitwise-identical numerics.
// ---------------------------------------------------------------------------
__global__ __launch_bounds__(256, 2) void gemm_fused2(const u16* __restrict__ Ahg,
                                                      const u16* __restrict__ Alg,
                                                      const u16* __restrict__ Bh0,
                                                      const u16* __restrict__ Bl0,
                                                      const u16* __restrict__ Bh1,
                                                      const u16* __restrict__ Bl1,
                                                      const u16* __restrict__ Bh2,
                                                      const u16* __restrict__ Bl2,
                                                      u16* __restrict__ qh_o,
                                                      u16* __restrict__ ql_o,
                                                      u16* __restrict__ kh_o,
                                                      u16* __restrict__ kl_o,
                                                      float* __restrict__ vf_o,
                                                      const float* __restrict__ cosb,
                                                      const float* __restrict__ sinb,
                                                      const float* __restrict__ aux,
                                                      float* __restrict__ outf,
                                                      int kind) {
    __shared__ u16 AhS[2][128*32], AlS[2][128*32], BhS[2][128*32], BlS[2][128*32];  // 64 KiB
    int tid = threadIdx.x;
    int wave = tid >> 6, lane = tid & 63;
    int wm = wave >> 1, wn = wave & 1;
    int bx = blockIdx.x, by = blockIdx.y;
    int proj, nx;
    const u16 *Bh, *Bl;
    if (kind == 0) {
        proj = bx >> 3; nx = bx & 7;
        Bh = (proj == 0) ? Bh0 : ((proj == 1) ? Bh1 : Bh2);
        Bl = (proj == 0) ? Bl0 : ((proj == 1) ? Bl1 : Bl2);
    } else {
        proj = 3; nx = bx; Bh = Bh0; Bl = Bl0;
    }

    int srow = tid >> 2, sch = (tid & 3) * 8;
    const u16* A0 = Ahg + (size_t)(by*128 + srow) * Cq + sch;
    const u16* A1 = A0 + (size_t)64 * Cq;
    const u16* L0 = Alg + (size_t)(by*128 + srow) * Cq + sch;
    const u16* L1 = L0 + (size_t)64 * Cq;
    const u16* H0 = Bh + (size_t)(nx*128 + srow) * Cq + sch;
    const u16* H1 = H0 + (size_t)64 * Cq;
    const u16* G0 = Bl + (size_t)(nx*128 + srow) * Cq + sch;
    const u16* G1 = G0 + (size_t)64 * Cq;
    int lo0 = srow*32 + sch, lo1 = lo0 + 2048;

    f32x4v acc[4][4];
    #pragma unroll
    for (int i = 0; i < 4; i++)
        #pragma unroll
        for (int j = 0; j < 4; j++)
            #pragma unroll
            for (int r = 0; r < 4; r++) acc[i][j][r] = 0.0f;

    // prologue: stage k=0 into buf 0
    stage16(A0, &AhS[0][lo0]); stage16(A1, &AhS[0][lo1]);
    stage16(L0, &AlS[0][lo0]); stage16(L1, &AlS[0][lo1]);
    stage16(H0, &BhS[0][lo0]); stage16(H1, &BhS[0][lo1]);
    stage16(G0, &BlS[0][lo0]); stage16(G1, &BlS[0][lo1]);

    int fr = lane & 15, fk = (lane >> 4) * 8;
    int cur = 0;
    for (int k0 = 0; k0 < Cq; k0 += 32, cur ^= 1) {
        __syncthreads();   // buf[cur] staged (vmcnt drained); prev reads done
        int kn = k0 + 32;
        if (kn < Cq) {     // prefetch next K-tile under the MFMA phase
            stage16(A0 + kn, &AhS[cur^1][lo0]); stage16(A1 + kn, &AhS[cur^1][lo1]);
            stage16(L0 + kn, &AlS[cur^1][lo0]); stage16(L1 + kn, &AlS[cur^1][lo1]);
            stage16(H0 + kn, &BhS[cur^1][lo0]); stage16(H1 + kn, &BhS[cur^1][lo1]);
            stage16(G0 + kn, &BlS[cur^1][lo0]); stage16(G1 + kn, &BlS[cur^1][lo1]);
        }
        f16x8 ah[4], al[4];
        #pragma unroll
        for (int mi = 0; mi < 4; mi++) {
            ah[mi] = *(const f16x8*)(const void*)&AhS[cur][(wm*64 + mi*16 + fr)*32 + fk];
            al[mi] = *(const f16x8*)(const void*)&AlS[cur][(wm*64 + mi*16 + fr)*32 + fk];
        }
        #pragma unroll
        for (int ni = 0; ni < 4; ni++) {
            f16x8 bhf = *(const f16x8*)(const void*)&BhS[cur][(wn*64 + ni*16 + fr)*32 + fk];
            f16x8 blf = *(const f16x8*)(const void*)&BlS[cur][(wn*64 + ni*16 + fr)*32 + fk];
            #pragma unroll
            for (int mi = 0; mi < 4; mi++) {
                acc[mi][ni] = __builtin_amdgcn_mfma_f32_16x16x32_f16(ah[mi], bhf, acc[mi][ni], 0, 0, 0);
                acc[mi][ni] = __builtin_amdgcn_mfma_f32_16x16x32_f16(ah[mi], blf, acc[mi][ni], 0, 0, 0);
                acc[mi][ni] = __builtin_amdgcn_mfma_f32_16x16x32_f16(al[mi], bhf, acc[mi][ni], 0, 0, 0);
            }
        }
    }

    int cr = (lane >> 4) * 4, cc = lane & 15;
    if (proj < 2) {
        u16* dh = (proj == 0) ? qh_o : kh_o;
        u16* dl = (proj == 0) ? ql_o : kl_o;
        float scale = (proj == 0) ? 0.125f : 1.0f;
        int hd = (nx * 2 + wn) * 64;
        #pragma unroll
        for (int mi = 0; mi < 4; mi++)
            #pragma unroll
            for (int r = 0; r < 4; r++) {
                int row = by*128 + wm*64 + mi*16 + cr + r;
                int t = row & (Tq - 1);
                #pragma unroll
                for (int ni = 0; ni < 2; ni++) {
                    int d0 = ni*16 + cc;
                    float a = acc[mi][ni][r];
                    float b = acc[mi][ni+2][r];
                    float c0 = cosb[t*Dq + d0],      s0 = sinb[t*Dq + d0];
                    float c1 = cosb[t*Dq + d0 + 32], s1 = sinb[t*Dq + d0 + 32];
                    float oa = (a * c0 - b * s0) * scale;
                    float ob = (b * c1 + a * s1) * scale;
                    size_t off = (size_t)row * Cq + hd + d0;
                    f16 ha = (f16)oa;
                    f16 hb = (f16)ob;
                    dh[off]      = f16bits(ha);
                    dl[off]      = f16bits((f16)(oa - (float)ha));
                    dh[off + 32] = f16bits(hb);
                    dl[off + 32] = f16bits((f16)(ob - (float)hb));
                }
            }
    } else if (proj == 2) {
        #pragma unroll
        for (int mi = 0; mi < 4; mi++)
            #pragma unroll
            for (int r = 0; r < 4; r++) {
                int row = by*128 + wm*64 + mi*16 + cr + r;
                #pragma unroll
                for (int ni = 0; ni < 4; ni++)
                    vf_o[(size_t)row * Cq + nx*128 + wn*64 + ni*16 + cc] = acc[mi][ni][r];
            }
    } else {
        #pragma unroll
        for (int mi = 0; mi < 4; mi++)
            #pragma unroll
            for (int r = 0; r < 4; r++) {
                int row = by*128 + wm*64 + mi*16 + cr + r;
                #pragma unroll
                for (int ni = 0; ni < 4; ni++) {
                    size_t off = (size_t)row * Cq + nx*128 + wn*64 + ni*16 + cc;
                    outf[off] = acc[mi][ni][r] + aux[off];
                }
            }
    }
}

// ---------------------------------------------------------------------------
// V transpose + split: v fp32 [b][t][h*64+d] -> vth/vtl u16 [bh][d][t]
// ---------------------------------------------------------------------------
__global__ __launch_bounds__(256) void vtrans_k(const float* __restrict__ v,
                                                u16* __restrict__ vth,
                                                u16* __restrict__ vtl) {
    __shared__ u16 Th[64 * 72];
    __shared__ u16 Tl[64 * 72];
    int tc = blockIdx.x;
    int bh = blockIdx.y;
    int b = bh >> 4, h = bh & 15;
    int tid = threadIdx.x;
    int tr = tid >> 2;
    int dc = (tid & 3) * 16;
    size_t gin = ((size_t)(b * Tq + tc * 64 + tr)) * Cq + h * Dq + dc;
    #pragma unroll
    for (int i = 0; i < 16; i += 4) {
        float4 f = *(const float4*)(v + gin + i);
        float fv[4] = {f.x, f.y, f.z, f.w};
        #pragma unroll
        for (int j = 0; j < 4; j++) {
            f16 hi = (f16)fv[j];
            f16 lo = (f16)(fv[j] - (float)hi);
            Th[(dc + i + j) * 72 + tr] = f16bits(hi);
            Tl[(dc + i + j) * 72 + tr] = f16bits(lo);
        }
    }
    __syncthreads();
    int dr = tid >> 2;
    int cc = (tid & 3) * 16;
    size_t gout = ((size_t)(bh * 64 + dr)) * Tq + tc * 64 + cc;
    *(uint4*)(vth + gout)     = *(uint4*)(Th + dr * 72 + cc);
    *(uint4*)(vth + gout + 8) = *(uint4*)(Th + dr * 72 + cc + 8);
    *(uint4*)(vtl + gout)     = *(uint4*)(Tl + dr * 72 + cc);
    *(uint4*)(vtl + gout + 8) = *(uint4*)(Tl + dr * 72 + cc + 8);
}

// ---------------------------------------------------------------------------
// Flash attention, swapped-QK^T, 1024 blocks (one q-tile each, 4 blocks/CU),
// LPT order, XCD-local heads. Unchanged from Round 6.
// ---------------------------------------------------------------------------
#define AST 72
__global__ __launch_bounds__(256, 3) void attn_f16(const u16* __restrict__ qh_g,
                                                   const u16* __restrict__ ql_g,
                                                   const u16* __restrict__ kh_g,
                                                   const u16* __restrict__ kl_g,
                                                   const u16* __restrict__ vth_g,
                                                   const u16* __restrict__ vtl_g,
                                                   u16* __restrict__ yh_g,
                                                   u16* __restrict__ yl_g) {
    __shared__ u16 Kh[64*AST], Kl[64*AST];
    __shared__ u16 Vh[64*AST], Vl[64*AST];

    int id = blockIdx.x;           // 0..1023
    int bh = id & 31;              // id%8 == bh%8 -> same-head blocks share XCD
    int qt = 31 - (id >> 5);       // LPT: largest q-tiles dispatched first
    int b = bh >> 4, h = bh & 15;
    int tid = threadIdx.x;
    int wv = tid >> 6, lane = tid & 63;
    int fr = lane & 15, fg = lane >> 4;
    int sr = tid >> 2, sc = (tid & 3) * 16;

    int idx0 = fr + ((fg & 1) << 5);
    int idx1 = idx0 + 16;
    int hiw = fg >> 1;

    uint4 rkh0, rkh1, rkl0, rkl1, rvh0, rvh1, rvl0, rvl1;
    auto ldkv = [&](int kt) {
        size_t kg = ((size_t)(b * Tq + kt * 64 + sr)) * Cq + h * Dq + sc;
        size_t vg = ((size_t)(bh * 64 + sr)) * Tq + kt * 64 + sc;
        rkh0 = *(const uint4*)(kh_g + kg);  rkh1 = *(const uint4*)(kh_g + kg + 8);
        rkl0 = *(const uint4*)(kl_g + kg);  rkl1 = *(const uint4*)(kl_g + kg + 8);
        rvh0 = *(const uint4*)(vth_g + vg); rvh1 = *(const uint4*)(vth_g + vg + 8);
        rvl0 = *(const uint4*)(vtl_g + vg); rvl1 = *(const uint4*)(vtl_g + vg + 8);
    };

    size_t qg = ((size_t)(b * Tq + qt * 64 + wv * 16 + fr)) * Cq + h * Dq + fg * 8;
    f16x8 aqh0 = *(const f16x8*)(const void*)(qh_g + qg);
    f16x8 aqh1 = *(const f16x8*)(const void*)(qh_g + qg + 32);
    f16x8 aql0 = *(const f16x8*)(const void*)(ql_g + qg);
    f16x8 aql1 = *(const f16x8*)(const void*)(ql_g + qg + 32);
    ldkv(0);

    f32x4v acc_o[4];
    float m_i = -1e30f, l_i = 0.0f;   // state for q-row = wv*16+fr
    #pragma unroll
    for (int i = 0; i < 4; i++)
        #pragma unroll
        for (int r = 0; r < 4; r++) acc_o[i][r] = 0.0f;

    for (int kt = 0; kt <= qt; kt++) {
        __syncthreads();   // (a) prev MFMA done reading Ks/Vs
        *(uint4*)(Kh + sr*AST + sc)     = rkh0;
        *(uint4*)(Kh + sr*AST + sc + 8) = rkh1;
        *(uint4*)(Kl + sr*AST + sc)     = rkl0;
        *(uint4*)(Kl + sr*AST + sc + 8) = rkl1;
        *(uint4*)(Vh + sr*AST + sc)     = rvh0;
        *(uint4*)(Vh + sr*AST + sc + 8) = rvh1;
        *(uint4*)(Vl + sr*AST + sc)     = rvl0;
        *(uint4*)(Vl + sr*AST + sc + 8) = rvl1;
        __syncthreads();   // (b) K/V visible
        if (kt < qt) ldkv(kt + 1);   // prefetch under MFMA

        // S^T = K Q^T (3-term split; same partial products as S = Q K^T)
        f32x4v s[4];
        __builtin_amdgcn_s_setprio(1);
        #pragma unroll
        for (int ni = 0; ni < 4; ni++) {
            int boff = (ni * 16 + fr) * AST + fg * 8;
            f16x8 kh0 = *(const f16x8*)(const void*)(Kh + boff);
            f16x8 kh1 = *(const f16x8*)(const void*)(Kh + boff + 32);
            f16x8 kl0 = *(const f16x8*)(const void*)(Kl + boff);
            f16x8 kl1 = *(const f16x8*)(const void*)(Kl + boff + 32);
            f32x4v t;
            #pragma unroll
            for (int r = 0; r < 4; r++) t[r] = 0.0f;
            t = __builtin_amdgcn_mfma_f32_16x16x32_f16(kh0, aqh0, t, 0, 0, 0);
            t = __builtin_amdgcn_mfma_f32_16x16x32_f16(kh1, aqh1, t, 0, 0, 0);
            t = __builtin_amdgcn_mfma_f32_16x16x32_f16(kl0, aqh0, t, 0, 0, 0);
            t = __builtin_amdgcn_mfma_f32_16x16x32_f16(kl1, aqh1, t, 0, 0, 0);
            t = __builtin_amdgcn_mfma_f32_16x16x32_f16(kh0, aql0, t, 0, 0, 0);
            t = __builtin_amdgcn_mfma_f32_16x16x32_f16(kh1, aql1, t, 0, 0, 0);
            s[ni] = t;
        }
        __builtin_amdgcn_s_setprio(0);

        // causal mask: lane holds (q = wv*16+fr, k = ni*16 + fg*4 + r)
        if (kt == qt) {
            int qloc = wv * 16 + fr;
            #pragma unroll
            for (int ni = 0; ni < 4; ni++) {
                #pragma unroll
                for (int r = 0; r < 4; r++) {
                    if (ni * 16 + fg * 4 + r > qloc) s[ni][r] = -1e30f;
                }
            }
        }

        // online softmax for q = wv*16+fr (16 values/lane + 2 xor steps)
        float mx = s[0][0];
        #pragma unroll
        for (int ni = 0; ni < 4; ni++)
            #pragma unroll
            for (int r = 0; r < 4; r++) mx = fmaxf(mx, s[ni][r]);
        mx = fmaxf(mx, __shfl_xor(mx, 16));
        mx = fmaxf(mx, __shfl_xor(mx, 32));
        float mn = fmaxf(m_i, mx);
        float p[4][4];
        float rs = 0.0f;
        #pragma unroll
        for (int ni = 0; ni < 4; ni++)
            #pragma unroll
            for (int r = 0; r < 4; r++) {
                p[ni][r] = __expf(s[ni][r] - mn);
                rs += p[ni][r];
            }
        rs += __shfl_xor(rs, 16);
        rs += __shfl_xor(rs, 32);
        float alpha = __expf(m_i - mn);
        l_i = l_i * alpha + rs;
        m_i = mn;

        // rescale acc rows (row q = fg*4+r): gather alpha from lane 20*fg+r
        #pragma unroll
        for (int r = 0; r < 4; r++) {
            float ar = __shfl(alpha, 20 * fg + r);
            #pragma unroll
            for (int ni = 0; ni < 4; ni++) acc_o[ni][r] *= ar;
        }

        // pack P to f16 pairs (RNE hi + exact residual lo, same as before)
        u32 wh[8], wl[8];
        #pragma unroll
        for (int ni = 0; ni < 4; ni++) {
            #pragma unroll
            for (int pr = 0; pr < 2; pr++) {
                float pa = p[ni][pr*2], pb = p[ni][pr*2 + 1];
                f16 ha = (f16)pa, hb = (f16)pb;
                wh[ni*2 + pr] = (u32)f16bits(ha) | ((u32)f16bits(hb) << 16);
                f16 la = (f16)(pa - (float)ha), lb = (f16)(pb - (float)hb);
                wl[ni*2 + pr] = (u32)f16bits(la) | ((u32)f16bits(lb) << 16);
            }
        }

        // assemble PV A-fragments via bpermute (no LDS round-trip)
        union { u32 u[4]; f16x8 v; } fh0, fh1, fl0, fl1;
        {
            u32 a, c;
            a = __shfl((int)wh[0], idx0); c = __shfl((int)wh[2], idx0);
            fh0.u[0] = hiw ? c : a;
            a = __shfl((int)wh[1], idx0); c = __shfl((int)wh[3], idx0);
            fh0.u[1] = hiw ? c : a;
            a = __shfl((int)wh[0], idx1); c = __shfl((int)wh[2], idx1);
            fh0.u[2] = hiw ? c : a;
            a = __shfl((int)wh[1], idx1); c = __shfl((int)wh[3], idx1);
            fh0.u[3] = hiw ? c : a;
            a = __shfl((int)wh[4], idx0); c = __shfl((int)wh[6], idx0);
            fh1.u[0] = hiw ? c : a;
            a = __shfl((int)wh[5], idx0); c = __shfl((int)wh[7], idx0);
            fh1.u[1] = hiw ? c : a;
            a = __shfl((int)wh[4], idx1); c = __shfl((int)wh[6], idx1);
            fh1.u[2] = hiw ? c : a;
            a = __shfl((int)wh[5], idx1); c = __shfl((int)wh[7], idx1);
            fh1.u[3] = hiw ? c : a;
            a = __shfl((int)wl[0], idx0); c = __shfl((int)wl[2], idx0);
            fl0.u[0] = hiw ? c : a;
            a = __shfl((int)wl[1], idx0); c = __shfl((int)wl[3], idx0);
            fl0.u[1] = hiw ? c : a;
            a = __shfl((int)wl[0], idx1); c = __shfl((int)wl[2], idx1);
            fl0.u[2] = hiw ? c : a;
            a = __shfl((int)wl[1], idx1); c = __shfl((int)wl[3], idx1);
            fl0.u[3] = hiw ? c : a;
            a = __shfl((int)wl[4], idx0); c = __shfl((int)wl[6], idx0);
            fl1.u[0] = hiw ? c : a;
            a = __shfl((int)wl[5], idx0); c = __shfl((int)wl[7], idx0);
            fl1.u[1] = hiw ? c : a;
            a = __shfl((int)wl[4], idx1); c = __shfl((int)wl[6], idx1);
            fl1.u[2] = hiw ? c : a;
            a = __shfl((int)wl[5], idx1); c = __shfl((int)wl[7], idx1);
            fl1.u[3] = hiw ? c : a;
        }

        // O += P V (3-term split)
        __builtin_amdgcn_s_setprio(1);
        #pragma unroll
        for (int ni = 0; ni < 4; ni++) {
            int boff = (ni * 16 + fr) * AST + fg * 8;
            f16x8 vh0 = *(const f16x8*)(const void*)(Vh + boff);
            f16x8 vh1 = *(const f16x8*)(const void*)(Vh + boff + 32);
            f16x8 vl0 = *(const f16x8*)(const void*)(Vl + boff);
            f16x8 vl1 = *(const f16x8*)(const void*)(Vl + boff + 32);
            f32x4v t = acc_o[ni];
            t = __builtin_amdgcn_mfma_f32_16x16x32_f16(fh0.v, vh0, t, 0, 0, 0);
            t = __builtin_amdgcn_mfma_f32_16x16x32_f16(fh1.v, vh1, t, 0, 0, 0);
            t = __builtin_amdgcn_mfma_f32_16x16x32_f16(fh0.v, vl0, t, 0, 0, 0);
            t = __builtin_amdgcn_mfma_f32_16x16x32_f16(fh1.v, vl1, t, 0, 0, 0);
            t = __builtin_amdgcn_mfma_f32_16x16x32_f16(fl0.v, vh0, t, 0, 0, 0);
            t = __builtin_amdgcn_mfma_f32_16x16x32_f16(fl1.v, vh1, t, 0, 0, 0);
            acc_o[ni] = t;
        }
        __builtin_amdgcn_s_setprio(0);
    }

    // epilogue: split y write (acc rows q = fg*4+r; l from lane 20*fg+r)
    #pragma unroll
    for (int r = 0; r < 4; r++) {
        float lq = __shfl(l_i, 20 * fg + r);
        float inv = 1.0f / lq;
        int row = qt * 64 + wv * 16 + fg * 4 + r;
        size_t base = ((size_t)(b * Tq + row)) * Cq + h * Dq + fr;
        #pragma unroll
        for (int ni = 0; ni < 4; ni++) {
            float yv = acc_o[ni][r] * inv;
            f16 hi = (f16)yv;
            f16 lo = (f16)(yv - (float)hi);
            yh_g[base + ni * 16] = f16bits(hi);
            yl_g[base + ni * 16] = f16bits(lo);
        }
    }
}

// ---------------------------------------------------------------------------
// Router: fp32 logits, top-2; emit per-expert (token, gate) lists via atomics.
// ---------------------------------------------------------------------------
__global__ __launch_bounds__(64) void router_k(const float* __restrict__ hn,
                                               const float* __restrict__ rw,
                                               int* __restrict__ cnt,
                                               int* __restrict__ idxl,
                                               float* __restrict__ gvl) {
    int tkn = blockIdx.x;
    int lane = threadIdx.x;
    float acc[Eq] = {};
    for (int it = 0; it < Cq / 64; it++) {
        float hv = hn[(size_t)tkn * Cq + it * 64 + lane];
        #pragma unroll
        for (int e = 0; e < Eq; e++)
            acc[e] = fmaf(hv, rw[e * Cq + it * 64 + lane], acc[e]);
    }
    #pragma unroll
    for (int e = 0; e < Eq; e++) {
        #pragma unroll
        for (int off = 32; off; off >>= 1) acc[e] += __shfl_xor(acc[e], off);
    }
    int i0 = 0;
    #pragma unroll
    for (int e = 1; e < Eq; e++) if (acc[e] > acc[i0]) i0 = e;
    int i1 = (i0 == 0) ? 1 : 0;
    #pragma unroll
    for (int e = 0; e < Eq; e++)
        if (e != i0 && acc[e] > acc[i1]) i1 = e;
    float p1 = __expf(acc[i1] - acc[i0]);
    float g0 = 1.0f / (1.0f + p1);
    float g1 = p1 / (1.0f + p1);
    if (lane == 0) {
        int p0 = atomicAdd(&cnt[i0], 1);
        idxl[i0 * NTOK + p0] = tkn;
        gvl[i0 * NTOK + p0] = g0;
        int p1i = atomicAdd(&cnt[i1], 1);
        idxl[i1 * NTOK + p1i] = tkn;
        gvl[i1 * NTOK + p1i] = g1;
    }
}

// ---------------------------------------------------------------------------
// Setup: 128-padded segment offsets + tile->expert table (<= 72 tiles).
// ---------------------------------------------------------------------------
__global__ void setup_k(const int* __restrict__ cnt, int* __restrict__ seg,
                        int* __restrict__ texp, int* __restrict__ ttot) {
    if (threadIdx.x == 0) {
        int base = 0;
        for (int e = 0; e < Eq; e++) {
            seg[e] = base * 128;
            int t = (cnt[e] + 127) >> 7;
            for (int i = 0; i < t; i++) texp[base + i] = e;
            base += t;
        }
        *ttot = base;
    }
}

// ---------------------------------------------------------------------------
// MoE up-proj, bf16-weight fast path (m97 structure).
// ---------------------------------------------------------------------------
__global__ __launch_bounds__(256, 2) void moe_w13b(const u16* __restrict__ hnb,
                                                   const u16* __restrict__ w1b,
                                                   const u16* __restrict__ w3b,
                                                   u16* __restrict__ gbuf,
                                                   const int* __restrict__ cnt,
                                                   const int* __restrict__ seg,
                                                   const int* __restrict__ texp,
                                                   const int* __restrict__ ttot,
                                                   const int* __restrict__ idxl) {
    int by = blockIdx.y;
    if (by >= *ttot) return;
    int e = texp[by];
    const u16* w1e = w1b + (size_t)e * HDq * Cq;
    const u16* w3e = w3b + (size_t)e * HDq * Cq;
    int cnte = cnt[e], sege = seg[e];
    const int* idxe = idxl + e * NTOK;

    __shared__ u16 As[2][128*32], B1S[2][128*32], B3S[2][128*32];   // 48 KiB
    int tid = threadIdx.x;
    int wave = tid >> 6, lane = tid & 63;
    int wm = wave >> 1, wn = wave & 1;
    int bx = blockIdx.x;
    int srow = tid >> 2, sch = (tid & 3) * 8;

    int r0 = by*128 + srow, r1 = r0 + 64;
    int li0 = r0 - sege, li1 = r1 - sege;
    int tok0 = idxe[li0 < cnte ? li0 : 0];
    int tok1 = idxe[li1 < cnte ? li1 : 0];
    const u16* A0 = hnb + (size_t)tok0 * Cq + sch;
    const u16* A1 = hnb + (size_t)tok1 * Cq + sch;
    const u16* W10 = w1e + (size_t)(bx*128 + srow) * Cq + sch;
    const u16* W11 = W10 + (size_t)64 * Cq;
    const u16* W30 = w3e + (size_t)(bx*128 + srow) * Cq + sch;
    const u16* W31 = W30 + (size_t)64 * Cq;
    int lo0 = srow*32 + sch, lo1 = lo0 + 2048;

    f32x4v acc1[4][4], acc3[4][4];
    #pragma unroll
    for (int i = 0; i < 4; i++)
        #pragma unroll
        for (int j = 0; j < 4; j++)
            #pragma unroll
            for (int r = 0; r < 4; r++) { acc1[i][j][r] = 0.0f; acc3[i][j][r] = 0.0f; }

    stage16(A0,  &As[0][lo0]);  stage16(A1,  &As[0][lo1]);
    stage16(W10, &B1S[0][lo0]); stage16(W11, &B1S[0][lo1]);
    stage16(W30, &B3S[0][lo0]); stage16(W31, &B3S[0][lo1]);

    int fr = lane & 15, fk = (lane >> 4) * 8;
    int cur = 0;
    for (int k0 = 0; k0 < Cq; k0 += 32, cur ^= 1) {
        __syncthreads();
        int kn = k0 + 32;
        if (kn < Cq) {
            stage16(A0 + kn,  &As[cur^1][lo0]);  stage16(A1 + kn,  &As[cur^1][lo1]);
            stage16(W10 + kn, &B1S[cur^1][lo0]); stage16(W11 + kn, &B1S[cur^1][lo1]);
            stage16(W30 + kn, &B3S[cur^1][lo0]); stage16(W31 + kn, &B3S[cur^1][lo1]);
        }
        bf16x8 af[4];
        #pragma unroll
        for (int mi = 0; mi < 4; mi++)
            af[mi] = *(const bf16x8*)&As[cur][(wm*64 + mi*16 + fr) * 32 + fk];
        #pragma unroll
        for (int ni = 0; ni < 4; ni++) {
            bf16x8 b1f = *(const bf16x8*)&B1S[cur][(wn*64 + ni*16 + fr) * 32 + fk];
            bf16x8 b3f = *(const bf16x8*)&B3S[cur][(wn*64 + ni*16 + fr) * 32 + fk];
            #pragma unroll
            for (int mi = 0; mi < 4; mi++) {
                acc1[mi][ni] = __builtin_amdgcn_mfma_f32_16x16x32_bf16(af[mi], b1f, acc1[mi][ni], 0, 0, 0);
                acc3[mi][ni] = __builtin_amdgcn_mfma_f32_16x16x32_bf16(af[mi], b3f, acc3[mi][ni], 0, 0, 0);
            }
        }
    }

    int cr = (lane >> 4) * 4, cc = lane & 15;
    #pragma unroll
    for (int mi = 0; mi < 4; mi++)
        #pragma unroll
        for (int ni = 0; ni < 4; ni++)
            #pragma unroll
            for (int r = 0; r < 4; r++) {
                int row = by*128 + wm*64 + mi*16 + cr + r;
                int col = bx*128 + wn*64 + ni*16 + cc;
                gbuf[(size_t)row * HDq + col] = f2bf(silu_f(acc1[mi][ni][r]) * acc3[mi][ni][r]);
            }
}

// ---------------------------------------------------------------------------
// MoE down-proj, bf16-weight fast path (m97 structure).
// ---------------------------------------------------------------------------
__global__ __launch_bounds__(256, 3) void moe_w2b_k(const u16* __restrict__ gbuf,
                                                    const u16* __restrict__ w2b,
                                                    float* __restrict__ out,
                                                    const int* __restrict__ cnt,
                                                    const int* __restrict__ seg,
                                                    const int* __restrict__ texp,
                                                    const int* __restrict__ ttot,
                                                    const int* __restrict__ idxl,
                                                    const float* __restrict__ gvl) {
    int by = blockIdx.y;
    if (by >= *ttot) return;
    int e = texp[by];
    const u16* w2e = w2b + (size_t)e * Cq * HDq;
    int cnte = cnt[e], sege = seg[e];
    const int* idxe = idxl + e * NTOK;
    const float* gve = gvl + e * NTOK;

    __shared__ u16 As[2][128*32], Bs[2][128*32];   // 32 KiB
    int tid = threadIdx.x;
    int wave = tid >> 6, lane = tid & 63;
    int wm = wave >> 1, wn = wave & 1;
    int bx = blockIdx.x;
    int srow = tid >> 2, sch = (tid & 3) * 8;

    const u16* A0 = gbuf + (size_t)(by*128 + srow) * HDq + sch;
    const u16* A1 = A0 + (size_t)64 * HDq;
    const u16* W0 = w2e + (size_t)(bx*128 + srow) * HDq + sch;
    const u16* W1 = W0 + (size_t)64 * HDq;
    int lo0 = srow*32 + sch, lo1 = lo0 + 2048;

    f32x4v acc[4][4];
    #pragma unroll
    for (int i = 0; i < 4; i++)
        #pragma unroll
        for (int j = 0; j < 4; j++)
            #pragma unroll
            for (int r = 0; r < 4; r++) acc[i][j][r] = 0.0f;

    stage16(A0, &As[0][lo0]); stage16(A1, &As[0][lo1]);
    stage16(W0, &Bs[0][lo0]); stage16(W1, &Bs[0][lo1]);

    int fr = lane & 15, fk = (lane >> 4) * 8;
    int cur = 0;
    for (int k0 = 0; k0 < HDq; k0 += 32, cur ^= 1) {
        __syncthreads();
        int kn = k0 + 32;
        if (kn < HDq) {
            stage16(A0 + kn, &As[cur^1][lo0]); stage16(A1 + kn, &As[cur^1][lo1]);
            stage16(W0 + kn, &Bs[cur^1][lo0]); stage16(W1 + kn, &Bs[cur^1][lo1]);
        }
        bf16x8 af[4];
        #pragma unroll
        for (int mi = 0; mi < 4; mi++)
            af[mi] = *(const bf16x8*)&As[cur][(wm*64 + mi*16 + fr) * 32 + fk];
        #pragma unroll
        for (int ni = 0; ni < 4; ni++) {
            bf16x8 bf_ = *(const bf16x8*)&Bs[cur][(wn*64 + ni*16 + fr) * 32 + fk];
            #pragma unroll
            for (int mi = 0; mi < 4; mi++)
                acc[mi][ni] = __builtin_amdgcn_mfma_f32_16x16x32_bf16(af[mi], bf_, acc[mi][ni], 0, 0, 0);
        }
    }

    int cr = (lane >> 4) * 4, cc = lane & 15;
    #pragma unroll
    for (int mi = 0; mi < 4; mi++)
        #pragma unroll
        for (int r = 0; r < 4; r++) {
            int row = by*128 + wm*64 + mi*16 + cr + r;
            int local = row - sege;
            if (local < cnte) {
                int token = idxe[local];
                float g = gve[local];
                #pragma unroll
                for (int ni = 0; ni < 4; ni++) {
                    int col = bx*128 + wn*64 + ni*16 + cc;
                    atomicAdd(&out[(size_t)token * Cq + col], g * acc[mi][ni][r]);
                }
            }
        }
}

// ---------------------------------------------------------------------------
// MoE fp32-weight fallbacks (ws too small for bf16 planes).
// ---------------------------------------------------------------------------
__global__ __launch_bounds__(256, 2) void moe_w13(const u16* __restrict__ hnb,
                                                  const float* __restrict__ w1,
                                                  const float* __restrict__ w3,
                                                  u16* __restrict__ gbuf,
                                                  const int* __restrict__ cnt,
                                                  const int* __restrict__ seg,
                                                  const int* __restrict__ texp,
                                                  const int* __restrict__ ttot,
                                                  const int* __restrict__ idxl) {
    int by = blockIdx.y;
    if (by >= *ttot) return;
    int e = texp[by];
    const float* w1e = w1 + (size_t)e * HDq * Cq;
    const float* w3e = w3 + (size_t)e * HDq * Cq;
    int cnte = cnt[e], sege = seg[e];
    const int* idxe = idxl + e * NTOK;

    __shared__ u16 As[2][128*32], B1S[128*32], B3S[128*32];
    int tid = threadIdx.x;
    int wave = tid >> 6, lane = tid & 63;
    int wm = wave >> 1, wn = wave & 1;
    int bx = blockIdx.x;
    int srow = tid >> 2, sch = (tid & 3) * 8;

    int r0 = by*128 + srow, r1 = r0 + 64;
    int li0 = r0 - sege, li1 = r1 - sege;
    int tok0 = idxe[li0 < cnte ? li0 : 0];
    int tok1 = idxe[li1 < cnte ? li1 : 0];
    const u16* A0 = hnb + (size_t)tok0 * Cq + sch;
    const u16* A1 = hnb + (size_t)tok1 * Cq + sch;
    const float* W10 = w1e + (size_t)(bx*128 + srow) * Cq + sch;
    const float* W11 = W10 + (size_t)64 * Cq;
    const float* W30 = w3e + (size_t)(bx*128 + srow) * Cq + sch;
    const float* W31 = W30 + (size_t)64 * Cq;
    int lo0 = srow*32 + sch, lo1 = lo0 + 2048;

    f32x4v acc1[4][4], acc3[4][4];
    #pragma unroll
    for (int i = 0; i < 4; i++)
        #pragma unroll
        for (int j = 0; j < 4; j++)
            #pragma unroll
            for (int r = 0; r < 4; r++) { acc1[i][j][r] = 0.0f; acc3[i][j][r] = 0.0f; }

    float x1a[8], x1b[8], x3a[8], x3b[8];
    stage16(A0, &As[0][lo0]);
    stage16(A1, &As[0][lo1]);
    *(float4*)&x1a[0] = *(const float4*)(W10);
    *(float4*)&x1a[4] = *(const float4*)(W10 + 4);
    *(float4*)&x1b[0] = *(const float4*)(W11);
    *(float4*)&x1b[4] = *(const float4*)(W11 + 4);
    *(float4*)&x3a[0] = *(const float4*)(W30);
    *(float4*)&x3a[4] = *(const float4*)(W30 + 4);
    *(float4*)&x3b[0] = *(const float4*)(W31);
    *(float4*)&x3b[4] = *(const float4*)(W31 + 4);

    int fr = lane & 15, fk = (lane >> 4) * 8;
    int cur = 0;
    for (int k0 = 0; k0 < Cq; k0 += 32, cur ^= 1) {
        __syncthreads();
        {
            u16 t0[8], t1[8], t2[8], t3[8];
            #pragma unroll
            for (int i = 0; i < 8; i++) {
                t0[i] = f2bf(x1a[i]); t1[i] = f2bf(x1b[i]);
                t2[i] = f2bf(x3a[i]); t3[i] = f2bf(x3b[i]);
            }
            *(uint4*)&B1S[lo0] = *(uint4*)t0;
            *(uint4*)&B1S[lo1] = *(uint4*)t1;
            *(uint4*)&B3S[lo0] = *(uint4*)t2;
            *(uint4*)&B3S[lo1] = *(uint4*)t3;
        }
        __syncthreads();
        int kn = k0 + 32;
        if (kn < Cq) {
            stage16(A0 + kn, &As[cur^1][lo0]);
            stage16(A1 + kn, &As[cur^1][lo1]);
            *(float4*)&x1a[0] = *(const float4*)(W10 + kn);
            *(float4*)&x1a[4] = *(const float4*)(W10 + kn + 4);
            *(float4*)&x1b[0] = *(const float4*)(W11 + kn);
            *(float4*)&x1b[4] = *(const float4*)(W11 + kn + 4);
            *(float4*)&x3a[0] = *(const float4*)(W30 + kn);
            *(float4*)&x3a[4] = *(const float4*)(W30 + kn + 4);
            *(float4*)&x3b[0] = *(const float4*)(W31 + kn);
            *(float4*)&x3b[4] = *(const float4*)(W31 + kn + 4);
        }
        bf16x8 af[4];
        #pragma unroll
        for (int mi = 0; mi < 4; mi++)
            af[mi] = *(const bf16x8*)&As[cur][(wm*64 + mi*16 + fr) * 32 + fk];
        #pragma unroll
        for (int ni = 0; ni < 4; ni++) {
            bf16x8 b1f = *(const bf16x8*)&B1S[(wn*64 + ni*16 + fr) * 32 + fk];
            bf16x8 b3f = *(const bf16x8*)&B3S[(wn*64 + ni*16 + fr) * 32 + fk];
            #pragma unroll
            for (int mi = 0; mi < 4; mi++) {
                acc1[mi][ni] = __builtin_amdgcn_mfma_f32_16x16x32_bf16(af[mi], b1f, acc1[mi][ni], 0, 0, 0);
                acc3[mi][ni] = __builtin_amdgcn_mfma_f32_16x16x32_bf16(af[mi], b3f, acc3[mi][ni], 0, 0, 0);
            }
        }
    }

    int cr = (lane >> 4) * 4, cc = lane & 15;
    #pragma unroll
    for (int mi = 0; mi < 4; mi++)
        #pragma unroll
        for (int ni = 0; ni < 4; ni++)
            #pragma unroll
            for (int r = 0; r < 4; r++) {
                int row = by*128 + wm*64 + mi*16 + cr + r;
                int col = bx*128 + wn*64 + ni*16 + cc;
                gbuf[(size_t)row * HDq + col] = f2bf(silu_f(acc1[mi][ni][r]) * acc3[mi][ni][r]);
            }
}

__global__ __launch_bounds__(256, 3) void moe_w2(const u16* __restrict__ gbuf,
                                                 const float* __restrict__ w2,
                                                 float* __restrict__ out,
                                                 const int* __restrict__ cnt,
                                                 const int* __restrict__ seg,
                                                 const int* __restrict__ texp,
                                                 const int* __restrict__ ttot,
                                                 const int* __restrict__ idxl,
                                                 const float* __restrict__ gvl) {
    int by = blockIdx.y;
    if (by >= *ttot) return;
    int e = texp[by];
    const float* w2e = w2 + (size_t)e * Cq * HDq;
    int cnte = cnt[e], sege = seg[e];
    const int* idxe = idxl + e * NTOK;
    const float* gve = gvl + e * NTOK;

    __shared__ u16 As[2][128*32], Bs[128*32];
    int tid = threadIdx.x;
    int wave = tid >> 6, lane = tid & 63;
    int wm = wave >> 1, wn = wave & 1;
    int bx = blockIdx.x;
    int srow = tid >> 2, sch = (tid & 3) * 8;

    const u16* A0 = gbuf + (size_t)(by*128 + srow) * HDq + sch;
    const u16* A1 = A0 + (size_t)64 * HDq;
    const float* W0 = w2e + (size_t)(bx*128 + srow) * HDq + sch;
    const float* W1 = W0 + (size_t)64 * HDq;
    int lo0 = srow*32 + sch, lo1 = lo0 + 2048;

    f32x4v acc[4][4];
    #pragma unroll
    for (int i = 0; i < 4; i++)
        #pragma unroll
        for (int j = 0; j < 4; j++)
            #pragma unroll
            for (int r = 0; r < 4; r++) acc[i][j][r] = 0.0f;

    float xa[8], xb[8];
    stage16(A0, &As[0][lo0]);
    stage16(A1, &As[0][lo1]);
    *(float4*)&xa[0] = *(const float4*)(W0);
    *(float4*)&xa[4] = *(const float4*)(W0 + 4);
    *(float4*)&xb[0] = *(const float4*)(W1);
    *(float4*)&xb[4] = *(const float4*)(W1 + 4);

    int fr = lane & 15, fk = (lane >> 4) * 8;
    int cur = 0;
    for (int k0 = 0; k0 < HDq; k0 += 32, cur ^= 1) {
        __syncthreads();
        {
            u16 ta[8], tb[8];
            #pragma unroll
            for (int i = 0; i < 8; i++) { ta[i] = f2bf(xa[i]); tb[i] = f2bf(xb[i]); }
            *(uint4*)&Bs[lo0] = *(uint4*)ta;
            *(uint4*)&Bs[lo1] = *(uint4*)tb;
        }
        __syncthreads();
        int kn = k0 + 32;
        if (kn < HDq) {
            stage16(A0 + kn, &As[cur^1][lo0]);
            stage16(A1 + kn, &As[cur^1][lo1]);
            *(float4*)&xa[0] = *(const float4*)(W0 + kn);
            *(float4*)&xa[4] = *(const float4*)(W0 + kn + 4);
            *(float4*)&xb[0] = *(const float4*)(W1 + kn);
            *(float4*)&xb[4] = *(const float4*)(W1 + kn + 4);
        }
        bf16x8 af[4];
        #pragma unroll
        for (int mi = 0; mi < 4; mi++)
            af[mi] = *(const bf16x8*)&As[cur][(wm*64 + mi*16 + fr) * 32 + fk];
        #pragma unroll
        for (int ni = 0; ni < 4; ni++) {
            bf16x8 bf_ = *(const bf16x8*)&Bs[(wn*64 + ni*16 + fr) * 32 + fk];
            #pragma unroll
            for (int mi = 0; mi < 4; mi++)
                acc[mi][ni] = __builtin_amdgcn_mfma_f32_16x16x32_bf16(af[mi], bf_, acc[mi][ni], 0, 0, 0);
        }
    }

    int cr = (lane >> 4) * 4, cc = lane & 15;
    #pragma unroll
    for (int mi = 0; mi < 4; mi++)
        #pragma unroll
        for (int r = 0; r < 4; r++) {
            int row = by*128 + wm*64 + mi*16 + cr + r;
            int local = row - sege;
            if (local < cnte) {
                int token = idxe[local];
                float g = gve[local];
                #pragma unroll
                for (int ni = 0; ni < 4; ni++) {
                    int col = bx*128 + wn*64 + ni*16 + cc;
                    atomicAdd(&out[(size_t)token * Cq + col], g * acc[mi][ni][r]);
                }
            }
        }
}

// ---------------------------------------------------------------------------
// Launch
// ---------------------------------------------------------------------------
extern "C" void kernel_launch(void* const* d_in, const int* in_sizes, int n_in,
                              void* d_out, int out_size, void* d_ws, size_t ws_size,
                              hipStream_t stream) {
    (void)in_sizes; (void)n_in; (void)out_size;

    const float* x     = (const float*)d_in[0];
    const float* ropec = (const float*)d_in[1];
    const float* ropes = (const float*)d_in[2];
    const float* anw   = (const float*)d_in[3];
    const float* q_w   = (const float*)d_in[4];
    const float* k_w   = (const float*)d_in[5];
    const float* v_w   = (const float*)d_in[6];
    const float* o_w   = (const float*)d_in[7];
    const float* fnw   = (const float*)d_in[8];
    const float* rtw   = (const float*)d_in[9];
    const float* w1    = (const float*)d_in[10];
    const float* w2    = (const float*)d_in[11];
    const float* w3    = (const float*)d_in[12];
    float* out = (float*)d_out;

    // workspace map (MiB offsets):
    //  P1 (QKV): hh@0-8 hl@8-16 | vf fp32@16-32 | qh@32-40 ql@40-48 kh@48-56 kl@56-64
    //  P2 (attn): vth@0-8 vtl@8-16 (vf dead) | yh@16-24 yl@24-32 (after attn)
    //  P3 (MoE): gbuf@0-28 | hn@32-48 hnb@48-56 meta@56-57
    //  pre  (>=136 MiB): MoE bf16 weights w1b@64-88 w3b@88-112 w2b@112-136
    //  pre2 (>=152 MiB): attn f16 weight planes q@136-140 k@140-144 v@144-148 o@148-152
    float* ws = (float*)d_ws;
    u16* hh = (u16*)(ws + MB(0));
    u16* hl = (u16*)(ws + MB(8));
    float* vf = ws + MB(16);
    u16* qh = (u16*)(ws + MB(32));
    u16* ql = (u16*)(ws + MB(40));
    u16* kh = (u16*)(ws + MB(48));
    u16* kl = (u16*)(ws + MB(56));
    u16* vth = (u16*)(ws + MB(0));
    u16* vtl = (u16*)(ws + MB(8));
    u16* yh  = (u16*)(ws + MB(16));
    u16* yl  = (u16*)(ws + MB(24));
    u16* gbuf = (u16*)(ws + MB(0));           // 9216x1536 bf16 = 27 MiB
    float* hn = ws + MB(32);                  // 16 MiB fp32
    u16* hnb  = (u16*)(ws + MB(48));          // 8 MiB
    int* cntp = (int*)(ws + MB(56));
    int* segp = cntp + 8;
    int* texp = cntp + 16;    // 72 entries
    int* ttot = cntp + 96;
    int* idxl = cntp + 256;                   // 8*4096 ints
    float* gvl = (float*)(cntp + 256 + Eq*NTOK);
    u16* w1b = (u16*)(ws + MB(64));           // 24 MiB bf16
    u16* w3b = (u16*)(ws + MB(88));           // 24 MiB bf16
    u16* w2b = (u16*)(ws + MB(112));          // 24 MiB bf16
    u16* wqh = (u16*)(ws + MB(136));          // f16 planes, 2 MiB each
    u16* wql = (u16*)(ws + MB(138));
    u16* wkh = (u16*)(ws + MB(140));
    u16* wkl = (u16*)(ws + MB(142));
    u16* wvh = (u16*)(ws + MB(144));
    u16* wvl = (u16*)(ws + MB(146));
    u16* woh = (u16*)(ws + MB(148));
    u16* wol = (u16*)(ws + MB(150));

    const int M = NTOK;
    const bool pre  = ws_size >= ((size_t)136 << 20);   // MoE bf16 path
    const bool pre2 = ws_size >= ((size_t)152 << 20);   // attn f16-plane path

    // 0. merged weight prep (one launch; y=3 slice only when pre2 fits)
    if (pre)
        hipLaunchKernelGGL(wprep_k, dim3(6144, pre2 ? 4 : 3), dim3(256), 0, stream,
                           w1, w3, w2, q_w, k_w, v_w, o_w,
                           w1b, w3b, w2b,
                           wqh, wql, wkh, wkl, wvh, wvl, woh, wol);

    // 1. attn rmsnorm -> split hi/lo
    hipLaunchKernelGGL(rmsnorm_split_k, dim3(M), dim3(256), 0, stream, x, anw, hh, hl);

    // 2. fused Q,K,V projection + RoPE + split epilogues (V -> fp32 vf)
    if (pre2)
        hipLaunchKernelGGL(gemm_fused2, dim3(24, M/128), dim3(256), 0, stream,
                           hh, hl, wqh, wql, wkh, wkl, wvh, wvl,
                           qh, ql, kh, kl, vf,
                           ropec, ropes, (const float*)nullptr, (float*)nullptr, 0);
    else
        hipLaunchKernelGGL(gemm_fused, dim3(24, M/128), dim3(256), 0, stream,
                           hh, hl, q_w, k_w, v_w, qh, ql, kh, kl, vf,
                           ropec, ropes, (const float*)nullptr, (float*)nullptr, 0);

    // 3. V transpose+split -> vth/vtl (hh/hl region, dead)
    hipLaunchKernelGGL(vtrans_k, dim3(32, 32), dim3(256), 0, stream, vf, vth, vtl);

    // 4. flash attention (swapped-QK^T, 1024 blocks = 4/CU, LPT order) -> yh/yl
    hipLaunchKernelGGL(attn_f16, dim3(1024), dim3(256), 0, stream,
                       qh, ql, kh, kl, vth, vtl, yh, yl);

    // 5. O projection + residual -> out
    if (pre2)
        hipLaunchKernelGGL(gemm_fused2, dim3(8, M/128), dim3(256), 0, stream,
                           yh, yl, woh, wol,
                           (const u16*)nullptr, (const u16*)nullptr,
                           (const u16*)nullptr, (const u16*)nullptr,
                           (u16*)nullptr, (u16*)nullptr, (u16*)nullptr, (u16*)nullptr,
                           (float*)nullptr, ropec, ropes, x, out, 1);
    else
        hipLaunchKernelGGL(gemm_fused, dim3(8, M/128), dim3(256), 0, stream,
                           yh, yl, o_w, (const float*)nullptr, (const float*)nullptr,
                           (u16*)nullptr, (u16*)nullptr, (u16*)nullptr, (u16*)nullptr,
                           (float*)nullptr, ropec, ropes, x, out, 1);

    // 6. ffn rmsnorm -> hn fp32 + hnb bf16 (+ zero expert counters)
    hipLaunchKernelGGL(rmsnorm2_k, dim3(M), dim3(256), 0, stream, out, fnw, hn, hnb, cntp);

    // 7. router (fp32) -> per-expert lists; then tile table
    hipLaunchKernelGGL(router_k, dim3(M), dim3(64), 0, stream, hn, rtw, cntp, idxl, gvl);
    hipLaunchKernelGGL(setup_k, dim3(1), dim3(64), 0, stream, cntp, segp, texp, ttot);

    // 8. MoE over gathered tokens
    if (pre) {
        hipLaunchKernelGGL(moe_w13b, dim3(HDq/128, 72), dim3(256), 0, stream,
                           hnb, w1b, w3b, gbuf, cntp, segp, texp, ttot, idxl);
        hipLaunchKernelGGL(moe_w2b_k, dim3(Cq/128, 72), dim3(256), 0, stream,
                           gbuf, w2b, out, cntp, segp, texp, ttot, idxl, gvl);
    } else {
        hipLaunchKernelGGL(moe_w13, dim3(HDq/128, 72), dim3(256), 0, stream,
                           hnb, w1, w3, gbuf, cntp, segp, texp, ttot, idxl);
        hipLaunchKernelGGL(moe_w2, dim3(Cq/128, 72), dim3(256), 0, stream,
                           gbuf, w2, out, cntp, segp, texp, ttot, idxl, gvl);
    }
}

// Round 11
// 695.451 us; speedup vs baseline: 1.1256x; 1.0257x over previous
//
#include <hip/hip_runtime.h>
#include <hip/hip_bf16.h>
#include <math.h>

// Problem constants
#define Bq 2
#define Tq 2048
#define Cq 1024
#define Hq 16
#define Dq 64
#define Eq 8
#define HDq 1536
#define NTOK (Bq*Tq)        // 4096 tokens

typedef unsigned short u16;
typedef unsigned int u32;
typedef _Float16 f16;
typedef __bf16 bf16x8 __attribute__((ext_vector_type(8)));
typedef _Float16 f16x8 __attribute__((ext_vector_type(8)));
typedef float f32x4v __attribute__((ext_vector_type(4)));

#define MB(x) ((size_t)(x) * 262144)   // x MiB in floats

__device__ __forceinline__ float silu_f(float a) {
    return a / (1.0f + __expf(-a));
}
__device__ __forceinline__ u16 f2bf(float f) {
    union { float f; unsigned u; } a; a.f = f;
    unsigned r = a.u + 0x7fffu + ((a.u >> 16) & 1u);
    return (u16)(r >> 16);
}
__device__ __forceinline__ u16 f16bits(f16 h) {
    union { f16 f; u16 u; } a; a.f = h; return a.u;
}

// async global->LDS, 16B per lane (per-lane global addr OK; LDS side is
// wave-uniform base + lane*16)
__device__ __forceinline__ void stage16(const void* g, void* l) {
    __builtin_amdgcn_global_load_lds(
        (const __attribute__((address_space(1))) unsigned int*)g,
        (__attribute__((address_space(3))) unsigned int*)l, 16, 0, 0);
}

// ---------------------------------------------------------------------------
// RMSNorm -> split-f16 hi/lo (attention branch input)
// ---------------------------------------------------------------------------
__global__ __launch_bounds__(256) void rmsnorm_split_k(const float* __restrict__ x,
                                                       const float* __restrict__ w,
                                                       u16* __restrict__ hh,
                                                       u16* __restrict__ hl) {
    int row = blockIdx.x;
    int tid = threadIdx.x;
    const float* xr = x + (size_t)row * Cq;
    float4 v = *(const float4*)(xr + tid * 4);
    float ss = v.x*v.x + v.y*v.y + v.z*v.z + v.w*v.w;
    #pragma unroll
    for (int off = 32; off; off >>= 1) ss += __shfl_xor(ss, off);
    __shared__ float red[4];
    if ((tid & 63) == 0) red[tid >> 6] = ss;
    __syncthreads();
    float tot = red[0] + red[1] + red[2] + red[3];
    float scale = rsqrtf(tot * (1.0f / (float)Cq) + 1e-6f);
    float4 wv = *(const float4*)(w + tid * 4);
    float o[4] = { v.x*wv.x*scale, v.y*wv.y*scale, v.z*wv.z*scale, v.w*wv.w*scale };
    ushort4 oh, ol;
    u16* ph = (u16*)&oh; u16* pl = (u16*)&ol;
    #pragma unroll
    for (int i = 0; i < 4; i++) {
        f16 hi = (f16)o[i]; f16 lo = (f16)(o[i] - (float)hi);
        ph[i] = f16bits(hi); pl[i] = f16bits(lo);
    }
    *(ushort4*)(hh + (size_t)row * Cq + tid * 4) = oh;
    *(ushort4*)(hl + (size_t)row * Cq + tid * 4) = ol;
}

// ---------------------------------------------------------------------------
// RMSNorm -> fp32 + bf16 (FFN branch). Block 0 also zeroes the expert
// counters (router launches strictly after this kernel -> ordering safe).
// ---------------------------------------------------------------------------
__global__ __launch_bounds__(256) void rmsnorm2_k(const float* __restrict__ x,
                                                  const float* __restrict__ w,
                                                  float* __restrict__ hn,
                                                  u16* __restrict__ hnb,
                                                  int* __restrict__ cnt) {
    int row = blockIdx.x;
    int tid = threadIdx.x;
    if (row == 0 && tid < Eq) cnt[tid] = 0;
    const float* xr = x + (size_t)row * Cq;
    float4 v = *(const float4*)(xr + tid * 4);
    float ss = v.x*v.x + v.y*v.y + v.z*v.z + v.w*v.w;
    #pragma unroll
    for (int off = 32; off; off >>= 1) ss += __shfl_xor(ss, off);
    __shared__ float red[4];
    if ((tid & 63) == 0) red[tid >> 6] = ss;
    __syncthreads();
    float tot = red[0] + red[1] + red[2] + red[3];
    float scale = rsqrtf(tot * (1.0f / (float)Cq) + 1e-6f);
    float4 wv = *(const float4*)(w + tid * 4);
    float4 o = make_float4(v.x*wv.x*scale, v.y*wv.y*scale, v.z*wv.z*scale, v.w*wv.w*scale);
    *(float4*)(hn + (size_t)row * Cq + tid * 4) = o;
    ushort4 ob = make_ushort4(f2bf(o.x), f2bf(o.y), f2bf(o.z), f2bf(o.w));
    *(ushort4*)(hnb + (size_t)row * Cq + tid * 4) = ob;
}

// ---------------------------------------------------------------------------
// Merged weight prep (one launch):
//  y<3:  MoE fp32 -> bf16 (w1/w3/w2), 6144 blocks x 2048 elems.
//  y==3: attn fp32 -> f16 hi/lo planes (q/k/v/o), 4 x 512 blocks (x<2048).
// Identical rounding/split as always -> MFMA inputs bitwise unchanged.
// ---------------------------------------------------------------------------
__global__ __launch_bounds__(256) void wprep_k(const float* __restrict__ w1,
                                               const float* __restrict__ w3,
                                               const float* __restrict__ w2,
                                               const float* __restrict__ qw,
                                               const float* __restrict__ kw,
                                               const float* __restrict__ vw,
                                               const float* __restrict__ ow,
                                               u16* __restrict__ w1b,
                                               u16* __restrict__ w3b,
                                               u16* __restrict__ w2b,
                                               u16* __restrict__ qhp, u16* __restrict__ qlp,
                                               u16* __restrict__ khp, u16* __restrict__ klp,
                                               u16* __restrict__ vhp, u16* __restrict__ vlp,
                                               u16* __restrict__ ohp, u16* __restrict__ olp) {
    int yg = blockIdx.y;
    if (yg < 3) {
        const float* src = (yg == 0) ? w1 : ((yg == 1) ? w3 : w2);
        u16* dst = (yg == 0) ? w1b : ((yg == 1) ? w3b : w2b);
        size_t i = ((size_t)blockIdx.x * 256 + threadIdx.x) * 8;
        float4 f0 = *(const float4*)(src + i);
        float4 f1 = *(const float4*)(src + i + 4);
        ushort4 o0 = make_ushort4(f2bf(f0.x), f2bf(f0.y), f2bf(f0.z), f2bf(f0.w));
        ushort4 o1 = make_ushort4(f2bf(f1.x), f2bf(f1.y), f2bf(f1.z), f2bf(f1.w));
        *(ushort4*)(dst + i)     = o0;
        *(ushort4*)(dst + i + 4) = o1;
    } else {
        int x = blockIdx.x;
        if (x >= 2048) return;
        int a = x >> 9;
        const float* src = (a == 0) ? qw : ((a == 1) ? kw : ((a == 2) ? vw : ow));
        u16* dh = (a == 0) ? qhp : ((a == 1) ? khp : ((a == 2) ? vhp : ohp));
        u16* dl = (a == 0) ? qlp : ((a == 1) ? klp : ((a == 2) ? vlp : olp));
        size_t i = ((size_t)(x & 511) * 256 + threadIdx.x) * 8;
        float f[8];
        *(float4*)&f[0] = *(const float4*)(src + i);
        *(float4*)&f[4] = *(const float4*)(src + i + 4);
        u16 oh[8], ol[8];
        #pragma unroll
        for (int j = 0; j < 8; j++) {
            f16 hi = (f16)f[j]; f16 lo = (f16)(f[j] - (float)hi);
            oh[j] = f16bits(hi); ol[j] = f16bits(lo);
        }
        *(uint4*)(dh + i) = *(uint4*)oh;
        *(uint4*)(dl + i) = *(uint4*)ol;
    }
}

// ---------------------------------------------------------------------------
// Split-f16 MFMA GEMM, fallback version (fp32 W through registers).
// ---------------------------------------------------------------------------
__global__ __launch_bounds__(256, 3) void gemm_fused(const u16* __restrict__ Ahg,
                                                     const u16* __restrict__ Alg,
                                                     const float* __restrict__ Wq,
                                                     const float* __restrict__ Wk,
                                                     const float* __restrict__ Wv,
                                                     u16* __restrict__ qh_o,
                                                     u16* __restrict__ ql_o,
                                                     u16* __restrict__ kh_o,
                                                     u16* __restrict__ kl_o,
                                                     float* __restrict__ vf_o,
                                                     const float* __restrict__ cosb,
                                                     const float* __restrict__ sinb,
                                                     const float* __restrict__ aux,
                                                     float* __restrict__ outf,
                                                     int kind) {
    __shared__ u16 AhS[2][128*32], AlS[2][128*32], BhS[128*32], BlS[128*32];
    int tid = threadIdx.x;
    int wave = tid >> 6, lane = tid & 63;
    int wm = wave >> 1, wn = wave & 1;
    int bx = blockIdx.x, by = blockIdx.y;
    int proj, nx;
    const float* W;
    if (kind == 0) {
        proj = bx >> 3; nx = bx & 7;
        W = (proj == 0) ? Wq : ((proj == 1) ? Wk : Wv);
    } else {
        proj = 3; nx = bx; W = Wq;
    }

    int srow = tid >> 2, sch = (tid & 3) * 8;
    const u16* A0 = Ahg + (size_t)(by*128 + srow) * Cq + sch;
    const u16* A1 = A0 + (size_t)64 * Cq;
    const u16* L0 = Alg + (size_t)(by*128 + srow) * Cq + sch;
    const u16* L1 = L0 + (size_t)64 * Cq;
    const float* W0 = W + (size_t)(nx*128 + srow) * Cq + sch;
    const float* W1 = W0 + (size_t)64 * Cq;
    int lo0 = srow*32 + sch, lo1 = lo0 + 2048;

    f32x4v acc[4][4];
    #pragma unroll
    for (int i = 0; i < 4; i++)
        #pragma unroll
        for (int j = 0; j < 4; j++)
            #pragma unroll
            for (int r = 0; r < 4; r++) acc[i][j][r] = 0.0f;

    float wr0[8], wr1[8];
    stage16(A0, &AhS[0][lo0]);
    stage16(A1, &AhS[0][lo1]);
    stage16(L0, &AlS[0][lo0]);
    stage16(L1, &AlS[0][lo1]);
    *(float4*)&wr0[0] = *(const float4*)(W0);
    *(float4*)&wr0[4] = *(const float4*)(W0 + 4);
    *(float4*)&wr1[0] = *(const float4*)(W1);
    *(float4*)&wr1[4] = *(const float4*)(W1 + 4);

    int fr = lane & 15, fk = (lane >> 4) * 8;
    int cur = 0;
    for (int k0 = 0; k0 < Cq; k0 += 32, cur ^= 1) {
        __syncthreads();
        {
            f16x8 bh0, bl0, bh1, bl1;
            #pragma unroll
            for (int i = 0; i < 8; i++) {
                f16 h0 = (f16)wr0[i]; bh0[i] = h0; bl0[i] = (f16)(wr0[i] - (float)h0);
                f16 h1 = (f16)wr1[i]; bh1[i] = h1; bl1[i] = (f16)(wr1[i] - (float)h1);
            }
            *(f16x8*)(void*)&BhS[lo0] = bh0;
            *(f16x8*)(void*)&BlS[lo0] = bl0;
            *(f16x8*)(void*)&BhS[lo1] = bh1;
            *(f16x8*)(void*)&BlS[lo1] = bl1;
        }
        __syncthreads();
        int kn = k0 + 32;
        if (kn < Cq) {
            stage16(A0 + kn, &AhS[cur^1][lo0]);
            stage16(A1 + kn, &AhS[cur^1][lo1]);
            stage16(L0 + kn, &AlS[cur^1][lo0]);
            stage16(L1 + kn, &AlS[cur^1][lo1]);
            *(float4*)&wr0[0] = *(const float4*)(W0 + kn);
            *(float4*)&wr0[4] = *(const float4*)(W0 + kn + 4);
            *(float4*)&wr1[0] = *(const float4*)(W1 + kn);
            *(float4*)&wr1[4] = *(const float4*)(W1 + kn + 4);
        }
        f16x8 ah[4], al[4];
        #pragma unroll
        for (int mi = 0; mi < 4; mi++) {
            ah[mi] = *(const f16x8*)(const void*)&AhS[cur][(wm*64 + mi*16 + fr)*32 + fk];
            al[mi] = *(const f16x8*)(const void*)&AlS[cur][(wm*64 + mi*16 + fr)*32 + fk];
        }
        #pragma unroll
        for (int ni = 0; ni < 4; ni++) {
            f16x8 bhf = *(const f16x8*)(const void*)&BhS[(wn*64 + ni*16 + fr)*32 + fk];
            f16x8 blf = *(const f16x8*)(const void*)&BlS[(wn*64 + ni*16 + fr)*32 + fk];
            #pragma unroll
            for (int mi = 0; mi < 4; mi++) {
                acc[mi][ni] = __builtin_amdgcn_mfma_f32_16x16x32_f16(ah[mi], bhf, acc[mi][ni], 0, 0, 0);
                acc[mi][ni] = __builtin_amdgcn_mfma_f32_16x16x32_f16(ah[mi], blf, acc[mi][ni], 0, 0, 0);
                acc[mi][ni] = __builtin_amdgcn_mfma_f32_16x16x32_f16(al[mi], bhf, acc[mi][ni], 0, 0, 0);
            }
        }
    }

    int cr = (lane >> 4) * 4, cc = lane & 15;
    if (proj < 2) {
        u16* dh = (proj == 0) ? qh_o : kh_o;
        u16* dl = (proj == 0) ? ql_o : kl_o;
        float scale = (proj == 0) ? 0.125f : 1.0f;
        int hd = (nx * 2 + wn) * 64;
        #pragma unroll
        for (int mi = 0; mi < 4; mi++)
            #pragma unroll
            for (int r = 0; r < 4; r++) {
                int row = by*128 + wm*64 + mi*16 + cr + r;
                int t = row & (Tq - 1);
                #pragma unroll
                for (int ni = 0; ni < 2; ni++) {
                    int d0 = ni*16 + cc;
                    float a = acc[mi][ni][r];
                    float b = acc[mi][ni+2][r];
                    float c0 = cosb[t*Dq + d0],      s0 = sinb[t*Dq + d0];
                    float c1 = cosb[t*Dq + d0 + 32], s1 = sinb[t*Dq + d0 + 32];
                    float oa = (a * c0 - b * s0) * scale;
                    float ob = (b * c1 + a * s1) * scale;
                    size_t off = (size_t)row * Cq + hd + d0;
                    f16 ha = (f16)oa;
                    f16 hb = (f16)ob;
                    dh[off]      = f16bits(ha);
                    dl[off]      = f16bits((f16)(oa - (float)ha));
                    dh[off + 32] = f16bits(hb);
                    dl[off + 32] = f16bits((f16)(ob - (float)hb));
                }
            }
    } else if (proj == 2) {
        #pragma unroll
        for (int mi = 0; mi < 4; mi++)
            #pragma unroll
            for (int r = 0; r < 4; r++) {
                int row = by*128 + wm*64 + mi*16 + cr + r;
                #pragma unroll
                for (int ni = 0; ni < 4; ni++)
                    vf_o[(size_t)row * Cq + nx*128 + wn*64 + ni*16 + cc] = acc[mi][ni][r];
            }
    } else {
        #pragma unroll
        for (int mi = 0; mi < 4; mi++)
            #pragma unroll
            for (int r = 0; r < 4; r++) {
                int row = by*128 + wm*64 + mi*16 + cr + r;
                #pragma unroll
                for (int ni = 0; ni < 4; ni++) {
                    size_t off = (size_t)row * Cq + nx*128 + wn*64 + ni*16 + cc;
                    outf[off] = acc[mi][ni][r] + aux[off];
                }
            }
    }
}

// ---------------------------------------------------------------------------
// Split-f16 MFMA GEMM, fast path v4 (Round 11):
//  - A double-buffered via stage16 (unchanged, prefetched under MFMA).
//  - B SINGLE-buffered via stage16, staged for the CURRENT K-step between
//    two barriers (fallback kernel's proven barrier topology, VALU-free).
//  - LDS 64 -> 48 KiB => 3 blocks/CU (vs 2): each block's exposed B-wait at
//    barrier (b) is hidden by the other two blocks' MFMA phases. No register
//    pressure change (R8/R9 lesson: B belongs in LDS on this structure).
//  - MFMA sequence and operand values unchanged -> bitwise-identical.
// ---------------------------------------------------------------------------
__global__ __launch_bounds__(256, 3) void gemm_fused2(const u16* __restrict__ Ahg,
                                                      const u16* __restrict__ Alg,
                                                      const u16* __restrict__ Bh0,
                                                      const u16* __restrict__ Bl0,
                                                      const u16* __restrict__ Bh1,
                                                      const u16* __restrict__ Bl1,
                                                      const u16* __restrict__ Bh2,
                                                      const u16* __restrict__ Bl2,
                                                      u16* __restrict__ qh_o,
                                                      u16* __restrict__ ql_o,
                                                      u16* __restrict__ kh_o,
                                                      u16* __restrict__ kl_o,
                                                      float* __restrict__ vf_o,
                                                      const float* __restrict__ cosb,
                                                      const float* __restrict__ sinb,
                                                      const float* __restrict__ aux,
                                                      float* __restrict__ outf,
                                                      int kind) {
    __shared__ u16 AhS[2][128*32], AlS[2][128*32], BhS[128*32], BlS[128*32];  // 48 KiB
    int tid = threadIdx.x;
    int wave = tid >> 6, lane = tid & 63;
    int wm = wave >> 1, wn = wave & 1;
    int bx = blockIdx.x, by = blockIdx.y;
    int proj, nx;
    const u16 *Bh, *Bl;
    if (kind == 0) {
        proj = bx >> 3; nx = bx & 7;
        Bh = (proj == 0) ? Bh0 : ((proj == 1) ? Bh1 : Bh2);
        Bl = (proj == 0) ? Bl0 : ((proj == 1) ? Bl1 : Bl2);
    } else {
        proj = 3; nx = bx; Bh = Bh0; Bl = Bl0;
    }

    int srow = tid >> 2, sch = (tid & 3) * 8;
    const u16* A0 = Ahg + (size_t)(by*128 + srow) * Cq + sch;
    const u16* A1 = A0 + (size_t)64 * Cq;
    const u16* L0 = Alg + (size_t)(by*128 + srow) * Cq + sch;
    const u16* L1 = L0 + (size_t)64 * Cq;
    const u16* H0 = Bh + (size_t)(nx*128 + srow) * Cq + sch;
    const u16* H1 = H0 + (size_t)64 * Cq;
    const u16* G0 = Bl + (size_t)(nx*128 + srow) * Cq + sch;
    const u16* G1 = G0 + (size_t)64 * Cq;
    int lo0 = srow*32 + sch, lo1 = lo0 + 2048;

    f32x4v acc[4][4];
    #pragma unroll
    for (int i = 0; i < 4; i++)
        #pragma unroll
        for (int j = 0; j < 4; j++)
            #pragma unroll
            for (int r = 0; r < 4; r++) acc[i][j][r] = 0.0f;

    // prologue: stage A(k=0) into buf 0
    stage16(A0, &AhS[0][lo0]); stage16(A1, &AhS[0][lo1]);
    stage16(L0, &AlS[0][lo0]); stage16(L1, &AlS[0][lo1]);

    int fr = lane & 15, fk = (lane >> 4) * 8;
    int cur = 0;
    for (int k0 = 0; k0 < Cq; k0 += 32, cur ^= 1) {
        __syncthreads();   // (a) prev MFMA done with B; A[cur] complete (vmcnt drained)
        // stage B for CURRENT k0 (single buffer)
        stage16(H0 + k0, &BhS[lo0]); stage16(H1 + k0, &BhS[lo1]);
        stage16(G0 + k0, &BlS[lo0]); stage16(G1 + k0, &BlS[lo1]);
        __syncthreads();   // (b) B staged (vmcnt drained)
        int kn = k0 + 32;
        if (kn < Cq) {     // prefetch next A K-tile under the MFMA phase
            stage16(A0 + kn, &AhS[cur^1][lo0]); stage16(A1 + kn, &AhS[cur^1][lo1]);
            stage16(L0 + kn, &AlS[cur^1][lo0]); stage16(L1 + kn, &AlS[cur^1][lo1]);
        }
        f16x8 ah[4], al[4];
        #pragma unroll
        for (int mi = 0; mi < 4; mi++) {
            ah[mi] = *(const f16x8*)(const void*)&AhS[cur][(wm*64 + mi*16 + fr)*32 + fk];
            al[mi] = *(const f16x8*)(const void*)&AlS[cur][(wm*64 + mi*16 + fr)*32 + fk];
        }
        #pragma unroll
        for (int ni = 0; ni < 4; ni++) {
            f16x8 bhf = *(const f16x8*)(const void*)&BhS[(wn*64 + ni*16 + fr)*32 + fk];
            f16x8 blf = *(const f16x8*)(const void*)&BlS[(wn*64 + ni*16 + fr)*32 + fk];
            #pragma unroll
            for (int mi = 0; mi < 4; mi++) {
                acc[mi][ni] = __builtin_amdgcn_mfma_f32_16x16x32_f16(ah[mi], bhf, acc[mi][ni], 0, 0, 0);
                acc[mi][ni] = __builtin_amdgcn_mfma_f32_16x16x32_f16(ah[mi], blf, acc[mi][ni], 0, 0, 0);
                acc[mi][ni] = __builtin_amdgcn_mfma_f32_16x16x32_f16(al[mi], bhf, acc[mi][ni], 0, 0, 0);
            }
        }
    }

    int cr = (lane >> 4) * 4, cc = lane & 15;
    if (proj < 2) {
        u16* dh = (proj == 0) ? qh_o : kh_o;
        u16* dl = (proj == 0) ? ql_o : kl_o;
        float scale = (proj == 0) ? 0.125f : 1.0f;
        int hd = (nx * 2 + wn) * 64;
        #pragma unroll
        for (int mi = 0; mi < 4; mi++)
            #pragma unroll
            for (int r = 0; r < 4; r++) {
                int row = by*128 + wm*64 + mi*16 + cr + r;
                int t = row & (Tq - 1);
                #pragma unroll
                for (int ni = 0; ni < 2; ni++) {
                    int d0 = ni*16 + cc;
                    float a = acc[mi][ni][r];
                    float b = acc[mi][ni+2][r];
                    float c0 = cosb[t*Dq + d0],      s0 = sinb[t*Dq + d0];
                    float c1 = cosb[t*Dq + d0 + 32], s1 = sinb[t*Dq + d0 + 32];
                    float oa = (a * c0 - b * s0) * scale;
                    float ob = (b * c1 + a * s1) * scale;
                    size_t off = (size_t)row * Cq + hd + d0;
                    f16 ha = (f16)oa;
                    f16 hb = (f16)ob;
                    dh[off]      = f16bits(ha);
                    dl[off]      = f16bits((f16)(oa - (float)ha));
                    dh[off + 32] = f16bits(hb);
                    dl[off + 32] = f16bits((f16)(ob - (float)hb));
                }
            }
    } else if (proj == 2) {
        #pragma unroll
        for (int mi = 0; mi < 4; mi++)
            #pragma unroll
            for (int r = 0; r < 4; r++) {
                int row = by*128 + wm*64 + mi*16 + cr + r;
                #pragma unroll
                for (int ni = 0; ni < 4; ni++)
                    vf_o[(size_t)row * Cq + nx*128 + wn*64 + ni*16 + cc] = acc[mi][ni][r];
            }
    } else {
        #pragma unroll
        for (int mi = 0; mi < 4; mi++)
            #pragma unroll
            for (int r = 0; r < 4; r++) {
                int row = by*128 + wm*64 + mi*16 + cr + r;
                #pragma unroll
                for (int ni = 0; ni < 4; ni++) {
                    size_t off = (size_t)row * Cq + nx*128 + wn*64 + ni*16 + cc;
                    outf[off] = acc[mi][ni][r] + aux[off];
                }
            }
    }
}

// ---------------------------------------------------------------------------
// V transpose + split: v fp32 [b][t][h*64+d] -> vth/vtl u16 [bh][d][t]
// ---------------------------------------------------------------------------
__global__ __launch_bounds__(256) void vtrans_k(const float* __restrict__ v,
                                                u16* __restrict__ vth,
                                                u16* __restrict__ vtl) {
    __shared__ u16 Th[64 * 72];
    __shared__ u16 Tl[64 * 72];
    int tc = blockIdx.x;
    int bh = blockIdx.y;
    int b = bh >> 4, h = bh & 15;
    int tid = threadIdx.x;
    int tr = tid >> 2;
    int dc = (tid & 3) * 16;
    size_t gin = ((size_t)(b * Tq + tc * 64 + tr)) * Cq + h * Dq + dc;
    #pragma unroll
    for (int i = 0; i < 16; i += 4) {
        float4 f = *(const float4*)(v + gin + i);
        float fv[4] = {f.x, f.y, f.z, f.w};
        #pragma unroll
        for (int j = 0; j < 4; j++) {
            f16 hi = (f16)fv[j];
            f16 lo = (f16)(fv[j] - (float)hi);
            Th[(dc + i + j) * 72 + tr] = f16bits(hi);
            Tl[(dc + i + j) * 72 + tr] = f16bits(lo);
        }
    }
    __syncthreads();
    int dr = tid >> 2;
    int cc = (tid & 3) * 16;
    size_t gout = ((size_t)(bh * 64 + dr)) * Tq + tc * 64 + cc;
    *(uint4*)(vth + gout)     = *(uint4*)(Th + dr * 72 + cc);
    *(uint4*)(vth + gout + 8) = *(uint4*)(Th + dr * 72 + cc + 8);
    *(uint4*)(vtl + gout)     = *(uint4*)(Tl + dr * 72 + cc);
    *(uint4*)(vtl + gout + 8) = *(uint4*)(Tl + dr * 72 + cc + 8);
}

// ---------------------------------------------------------------------------
// Flash attention, swapped-QK^T, 1024 blocks (one q-tile each, 4 blocks/CU),
// LPT order, XCD-local heads. Unchanged.
// ---------------------------------------------------------------------------
#define AST 72
__global__ __launch_bounds__(256, 3) void attn_f16(const u16* __restrict__ qh_g,
                                                   const u16* __restrict__ ql_g,
                                                   const u16* __restrict__ kh_g,
                                                   const u16* __restrict__ kl_g,
                                                   const u16* __restrict__ vth_g,
                                                   const u16* __restrict__ vtl_g,
                                                   u16* __restrict__ yh_g,
                                                   u16* __restrict__ yl_g) {
    __shared__ u16 Kh[64*AST], Kl[64*AST];
    __shared__ u16 Vh[64*AST], Vl[64*AST];

    int id = blockIdx.x;           // 0..1023
    int bh = id & 31;              // id%8 == bh%8 -> same-head blocks share XCD
    int qt = 31 - (id >> 5);       // LPT: largest q-tiles dispatched first
    int b = bh >> 4, h = bh & 15;
    int tid = threadIdx.x;
    int wv = tid >> 6, lane = tid & 63;
    int fr = lane & 15, fg = lane >> 4;
    int sr = tid >> 2, sc = (tid & 3) * 16;

    int idx0 = fr + ((fg & 1) << 5);
    int idx1 = idx0 + 16;
    int hiw = fg >> 1;

    uint4 rkh0, rkh1, rkl0, rkl1, rvh0, rvh1, rvl0, rvl1;
    auto ldkv = [&](int kt) {
        size_t kg = ((size_t)(b * Tq + kt * 64 + sr)) * Cq + h * Dq + sc;
        size_t vg = ((size_t)(bh * 64 + sr)) * Tq + kt * 64 + sc;
        rkh0 = *(const uint4*)(kh_g + kg);  rkh1 = *(const uint4*)(kh_g + kg + 8);
        rkl0 = *(const uint4*)(kl_g + kg);  rkl1 = *(const uint4*)(kl_g + kg + 8);
        rvh0 = *(const uint4*)(vth_g + vg); rvh1 = *(const uint4*)(vth_g + vg + 8);
        rvl0 = *(const uint4*)(vtl_g + vg); rvl1 = *(const uint4*)(vtl_g + vg + 8);
    };

    size_t qg = ((size_t)(b * Tq + qt * 64 + wv * 16 + fr)) * Cq + h * Dq + fg * 8;
    f16x8 aqh0 = *(const f16x8*)(const void*)(qh_g + qg);
    f16x8 aqh1 = *(const f16x8*)(const void*)(qh_g + qg + 32);
    f16x8 aql0 = *(const f16x8*)(const void*)(ql_g + qg);
    f16x8 aql1 = *(const f16x8*)(const void*)(ql_g + qg + 32);
    ldkv(0);

    f32x4v acc_o[4];
    float m_i = -1e30f, l_i = 0.0f;   // state for q-row = wv*16+fr
    #pragma unroll
    for (int i = 0; i < 4; i++)
        #pragma unroll
        for (int r = 0; r < 4; r++) acc_o[i][r] = 0.0f;

    for (int kt = 0; kt <= qt; kt++) {
        __syncthreads();   // (a) prev MFMA done reading Ks/Vs
        *(uint4*)(Kh + sr*AST + sc)     = rkh0;
        *(uint4*)(Kh + sr*AST + sc + 8) = rkh1;
        *(uint4*)(Kl + sr*AST + sc)     = rkl0;
        *(uint4*)(Kl + sr*AST + sc + 8) = rkl1;
        *(uint4*)(Vh + sr*AST + sc)     = rvh0;
        *(uint4*)(Vh + sr*AST + sc + 8) = rvh1;
        *(uint4*)(Vl + sr*AST + sc)     = rvl0;
        *(uint4*)(Vl + sr*AST + sc + 8) = rvl1;
        __syncthreads();   // (b) K/V visible
        if (kt < qt) ldkv(kt + 1);   // prefetch under MFMA

        // S^T = K Q^T (3-term split; same partial products as S = Q K^T)
        f32x4v s[4];
        __builtin_amdgcn_s_setprio(1);
        #pragma unroll
        for (int ni = 0; ni < 4; ni++) {
            int boff = (ni * 16 + fr) * AST + fg * 8;
            f16x8 kh0 = *(const f16x8*)(const void*)(Kh + boff);
            f16x8 kh1 = *(const f16x8*)(const void*)(Kh + boff + 32);
            f16x8 kl0 = *(const f16x8*)(const void*)(Kl + boff);
            f16x8 kl1 = *(const f16x8*)(const void*)(Kl + boff + 32);
            f32x4v t;
            #pragma unroll
            for (int r = 0; r < 4; r++) t[r] = 0.0f;
            t = __builtin_amdgcn_mfma_f32_16x16x32_f16(kh0, aqh0, t, 0, 0, 0);
            t = __builtin_amdgcn_mfma_f32_16x16x32_f16(kh1, aqh1, t, 0, 0, 0);
            t = __builtin_amdgcn_mfma_f32_16x16x32_f16(kl0, aqh0, t, 0, 0, 0);
            t = __builtin_amdgcn_mfma_f32_16x16x32_f16(kl1, aqh1, t, 0, 0, 0);
            t = __builtin_amdgcn_mfma_f32_16x16x32_f16(kh0, aql0, t, 0, 0, 0);
            t = __builtin_amdgcn_mfma_f32_16x16x32_f16(kh1, aql1, t, 0, 0, 0);
            s[ni] = t;
        }
        __builtin_amdgcn_s_setprio(0);

        // causal mask: lane holds (q = wv*16+fr, k = ni*16 + fg*4 + r)
        if (kt == qt) {
            int qloc = wv * 16 + fr;
            #pragma unroll
            for (int ni = 0; ni < 4; ni++) {
                #pragma unroll
                for (int r = 0; r < 4; r++) {
                    if (ni * 16 + fg * 4 + r > qloc) s[ni][r] = -1e30f;
                }
            }
        }

        // online softmax for q = wv*16+fr (16 values/lane + 2 xor steps)
        float mx = s[0][0];
        #pragma unroll
        for (int ni = 0; ni < 4; ni++)
            #pragma unroll
            for (int r = 0; r < 4; r++) mx = fmaxf(mx, s[ni][r]);
        mx = fmaxf(mx, __shfl_xor(mx, 16));
        mx = fmaxf(mx, __shfl_xor(mx, 32));
        float mn = fmaxf(m_i, mx);
        float p[4][4];
        float rs = 0.0f;
        #pragma unroll
        for (int ni = 0; ni < 4; ni++)
            #pragma unroll
            for (int r = 0; r < 4; r++) {
                p[ni][r] = __expf(s[ni][r] - mn);
                rs += p[ni][r];
            }
        rs += __shfl_xor(rs, 16);
        rs += __shfl_xor(rs, 32);
        float alpha = __expf(m_i - mn);
        l_i = l_i * alpha + rs;
        m_i = mn;

        // rescale acc rows (row q = fg*4+r): gather alpha from lane 20*fg+r
        #pragma unroll
        for (int r = 0; r < 4; r++) {
            float ar = __shfl(alpha, 20 * fg + r);
            #pragma unroll
            for (int ni = 0; ni < 4; ni++) acc_o[ni][r] *= ar;
        }

        // pack P to f16 pairs (RNE hi + exact residual lo, same as before)
        u32 wh[8], wl[8];
        #pragma unroll
        for (int ni = 0; ni < 4; ni++) {
            #pragma unroll
            for (int pr = 0; pr < 2; pr++) {
                float pa = p[ni][pr*2], pb = p[ni][pr*2 + 1];
                f16 ha = (f16)pa, hb = (f16)pb;
                wh[ni*2 + pr] = (u32)f16bits(ha) | ((u32)f16bits(hb) << 16);
                f16 la = (f16)(pa - (float)ha), lb = (f16)(pb - (float)hb);
                wl[ni*2 + pr] = (u32)f16bits(la) | ((u32)f16bits(lb) << 16);
            }
        }

        // assemble PV A-fragments via bpermute (no LDS round-trip)
        union { u32 u[4]; f16x8 v; } fh0, fh1, fl0, fl1;
        {
            u32 a, c;
            a = __shfl((int)wh[0], idx0); c = __shfl((int)wh[2], idx0);
            fh0.u[0] = hiw ? c : a;
            a = __shfl((int)wh[1], idx0); c = __shfl((int)wh[3], idx0);
            fh0.u[1] = hiw ? c : a;
            a = __shfl((int)wh[0], idx1); c = __shfl((int)wh[2], idx1);
            fh0.u[2] = hiw ? c : a;
            a = __shfl((int)wh[1], idx1); c = __shfl((int)wh[3], idx1);
            fh0.u[3] = hiw ? c : a;
            a = __shfl((int)wh[4], idx0); c = __shfl((int)wh[6], idx0);
            fh1.u[0] = hiw ? c : a;
            a = __shfl((int)wh[5], idx0); c = __shfl((int)wh[7], idx0);
            fh1.u[1] = hiw ? c : a;
            a = __shfl((int)wh[4], idx1); c = __shfl((int)wh[6], idx1);
            fh1.u[2] = hiw ? c : a;
            a = __shfl((int)wh[5], idx1); c = __shfl((int)wh[7], idx1);
            fh1.u[3] = hiw ? c : a;
            a = __shfl((int)wl[0], idx0); c = __shfl((int)wl[2], idx0);
            fl0.u[0] = hiw ? c : a;
            a = __shfl((int)wl[1], idx0); c = __shfl((int)wl[3], idx0);
            fl0.u[1] = hiw ? c : a;
            a = __shfl((int)wl[0], idx1); c = __shfl((int)wl[2], idx1);
            fl0.u[2] = hiw ? c : a;
            a = __shfl((int)wl[1], idx1); c = __shfl((int)wl[3], idx1);
            fl0.u[3] = hiw ? c : a;
            a = __shfl((int)wl[4], idx0); c = __shfl((int)wl[6], idx0);
            fl1.u[0] = hiw ? c : a;
            a = __shfl((int)wl[5], idx0); c = __shfl((int)wl[7], idx0);
            fl1.u[1] = hiw ? c : a;
            a = __shfl((int)wl[4], idx1); c = __shfl((int)wl[6], idx1);
            fl1.u[2] = hiw ? c : a;
            a = __shfl((int)wl[5], idx1); c = __shfl((int)wl[7], idx1);
            fl1.u[3] = hiw ? c : a;
        }

        // O += P V (3-term split)
        __builtin_amdgcn_s_setprio(1);
        #pragma unroll
        for (int ni = 0; ni < 4; ni++) {
            int boff = (ni * 16 + fr) * AST + fg * 8;
            f16x8 vh0 = *(const f16x8*)(const void*)(Vh + boff);
            f16x8 vh1 = *(const f16x8*)(const void*)(Vh + boff + 32);
            f16x8 vl0 = *(const f16x8*)(const void*)(Vl + boff);
            f16x8 vl1 = *(const f16x8*)(const void*)(Vl + boff + 32);
            f32x4v t = acc_o[ni];
            t = __builtin_amdgcn_mfma_f32_16x16x32_f16(fh0.v, vh0, t, 0, 0, 0);
            t = __builtin_amdgcn_mfma_f32_16x16x32_f16(fh1.v, vh1, t, 0, 0, 0);
            t = __builtin_amdgcn_mfma_f32_16x16x32_f16(fh0.v, vl0, t, 0, 0, 0);
            t = __builtin_amdgcn_mfma_f32_16x16x32_f16(fh1.v, vl1, t, 0, 0, 0);
            t = __builtin_amdgcn_mfma_f32_16x16x32_f16(fl0.v, vh0, t, 0, 0, 0);
            t = __builtin_amdgcn_mfma_f32_16x16x32_f16(fl1.v, vh1, t, 0, 0, 0);
            acc_o[ni] = t;
        }
        __builtin_amdgcn_s_setprio(0);
    }

    // epilogue: split y write (acc rows q = fg*4+r; l from lane 20*fg+r)
    #pragma unroll
    for (int r = 0; r < 4; r++) {
        float lq = __shfl(l_i, 20 * fg + r);
        float inv = 1.0f / lq;
        int row = qt * 64 + wv * 16 + fg * 4 + r;
        size_t base = ((size_t)(b * Tq + row)) * Cq + h * Dq + fr;
        #pragma unroll
        for (int ni = 0; ni < 4; ni++) {
            float yv = acc_o[ni][r] * inv;
            f16 hi = (f16)yv;
            f16 lo = (f16)(yv - (float)hi);
            yh_g[base + ni * 16] = f16bits(hi);
            yl_g[base + ni * 16] = f16bits(lo);
        }
    }
}

// ---------------------------------------------------------------------------
// Router: fp32 logits, top-2; emit per-expert (token, gate) lists via atomics.
// ---------------------------------------------------------------------------
__global__ __launch_bounds__(64) void router_k(const float* __restrict__ hn,
                                               const float* __restrict__ rw,
                                               int* __restrict__ cnt,
                                               int* __restrict__ idxl,
                                               float* __restrict__ gvl) {
    int tkn = blockIdx.x;
    int lane = threadIdx.x;
    float acc[Eq] = {};
    for (int it = 0; it < Cq / 64; it++) {
        float hv = hn[(size_t)tkn * Cq + it * 64 + lane];
        #pragma unroll
        for (int e = 0; e < Eq; e++)
            acc[e] = fmaf(hv, rw[e * Cq + it * 64 + lane], acc[e]);
    }
    #pragma unroll
    for (int e = 0; e < Eq; e++) {
        #pragma unroll
        for (int off = 32; off; off >>= 1) acc[e] += __shfl_xor(acc[e], off);
    }
    int i0 = 0;
    #pragma unroll
    for (int e = 1; e < Eq; e++) if (acc[e] > acc[i0]) i0 = e;
    int i1 = (i0 == 0) ? 1 : 0;
    #pragma unroll
    for (int e = 0; e < Eq; e++)
        if (e != i0 && acc[e] > acc[i1]) i1 = e;
    float p1 = __expf(acc[i1] - acc[i0]);
    float g0 = 1.0f / (1.0f + p1);
    float g1 = p1 / (1.0f + p1);
    if (lane == 0) {
        int p0 = atomicAdd(&cnt[i0], 1);
        idxl[i0 * NTOK + p0] = tkn;
        gvl[i0 * NTOK + p0] = g0;
        int p1i = atomicAdd(&cnt[i1], 1);
        idxl[i1 * NTOK + p1i] = tkn;
        gvl[i1 * NTOK + p1i] = g1;
    }
}

// ---------------------------------------------------------------------------
// Setup: 128-padded segment offsets + tile->expert table (<= 72 tiles).
// ---------------------------------------------------------------------------
__global__ void setup_k(const int* __restrict__ cnt, int* __restrict__ seg,
                        int* __restrict__ texp, int* __restrict__ ttot) {
    if (threadIdx.x == 0) {
        int base = 0;
        for (int e = 0; e < Eq; e++) {
            seg[e] = base * 128;
            int t = (cnt[e] + 127) >> 7;
            for (int i = 0; i < t; i++) texp[base + i] = e;
            base += t;
        }
        *ttot = base;
    }
}

// ---------------------------------------------------------------------------
// MoE up-proj, bf16-weight fast path (m97 structure).
// ---------------------------------------------------------------------------
__global__ __launch_bounds__(256, 2) void moe_w13b(const u16* __restrict__ hnb,
                                                   const u16* __restrict__ w1b,
                                                   const u16* __restrict__ w3b,
                                                   u16* __restrict__ gbuf,
                                                   const int* __restrict__ cnt,
                                                   const int* __restrict__ seg,
                                                   const int* __restrict__ texp,
                                                   const int* __restrict__ ttot,
                                                   const int* __restrict__ idxl) {
    int by = blockIdx.y;
    if (by >= *ttot) return;
    int e = texp[by];
    const u16* w1e = w1b + (size_t)e * HDq * Cq;
    const u16* w3e = w3b + (size_t)e * HDq * Cq;
    int cnte = cnt[e], sege = seg[e];
    const int* idxe = idxl + e * NTOK;

    __shared__ u16 As[2][128*32], B1S[2][128*32], B3S[2][128*32];   // 48 KiB
    int tid = threadIdx.x;
    int wave = tid >> 6, lane = tid & 63;
    int wm = wave >> 1, wn = wave & 1;
    int bx = blockIdx.x;
    int srow = tid >> 2, sch = (tid & 3) * 8;

    int r0 = by*128 + srow, r1 = r0 + 64;
    int li0 = r0 - sege, li1 = r1 - sege;
    int tok0 = idxe[li0 < cnte ? li0 : 0];
    int tok1 = idxe[li1 < cnte ? li1 : 0];
    const u16* A0 = hnb + (size_t)tok0 * Cq + sch;
    const u16* A1 = hnb + (size_t)tok1 * Cq + sch;
    const u16* W10 = w1e + (size_t)(bx*128 + srow) * Cq + sch;
    const u16* W11 = W10 + (size_t)64 * Cq;
    const u16* W30 = w3e + (size_t)(bx*128 + srow) * Cq + sch;
    const u16* W31 = W30 + (size_t)64 * Cq;
    int lo0 = srow*32 + sch, lo1 = lo0 + 2048;

    f32x4v acc1[4][4], acc3[4][4];
    #pragma unroll
    for (int i = 0; i < 4; i++)
        #pragma unroll
        for (int j = 0; j < 4; j++)
            #pragma unroll
            for (int r = 0; r < 4; r++) { acc1[i][j][r] = 0.0f; acc3[i][j][r] = 0.0f; }

    stage16(A0,  &As[0][lo0]);  stage16(A1,  &As[0][lo1]);
    stage16(W10, &B1S[0][lo0]); stage16(W11, &B1S[0][lo1]);
    stage16(W30, &B3S[0][lo0]); stage16(W31, &B3S[0][lo1]);

    int fr = lane & 15, fk = (lane >> 4) * 8;
    int cur = 0;
    for (int k0 = 0; k0 < Cq; k0 += 32, cur ^= 1) {
        __syncthreads();
        int kn = k0 + 32;
        if (kn < Cq) {
            stage16(A0 + kn,  &As[cur^1][lo0]);  stage16(A1 + kn,  &As[cur^1][lo1]);
            stage16(W10 + kn, &B1S[cur^1][lo0]); stage16(W11 + kn, &B1S[cur^1][lo1]);
            stage16(W30 + kn, &B3S[cur^1][lo0]); stage16(W31 + kn, &B3S[cur^1][lo1]);
        }
        bf16x8 af[4];
        #pragma unroll
        for (int mi = 0; mi < 4; mi++)
            af[mi] = *(const bf16x8*)&As[cur][(wm*64 + mi*16 + fr) * 32 + fk];
        #pragma unroll
        for (int ni = 0; ni < 4; ni++) {
            bf16x8 b1f = *(const bf16x8*)&B1S[cur][(wn*64 + ni*16 + fr) * 32 + fk];
            bf16x8 b3f = *(const bf16x8*)&B3S[cur][(wn*64 + ni*16 + fr) * 32 + fk];
            #pragma unroll
            for (int mi = 0; mi < 4; mi++) {
                acc1[mi][ni] = __builtin_amdgcn_mfma_f32_16x16x32_bf16(af[mi], b1f, acc1[mi][ni], 0, 0, 0);
                acc3[mi][ni] = __builtin_amdgcn_mfma_f32_16x16x32_bf16(af[mi], b3f, acc3[mi][ni], 0, 0, 0);
            }
        }
    }

    int cr = (lane >> 4) * 4, cc = lane & 15;
    #pragma unroll
    for (int mi = 0; mi < 4; mi++)
        #pragma unroll
        for (int ni = 0; ni < 4; ni++)
            #pragma unroll
            for (int r = 0; r < 4; r++) {
                int row = by*128 + wm*64 + mi*16 + cr + r;
                int col = bx*128 + wn*64 + ni*16 + cc;
                gbuf[(size_t)row * HDq + col] = f2bf(silu_f(acc1[mi][ni][r]) * acc3[mi][ni][r]);
            }
}

// ---------------------------------------------------------------------------
// MoE down-proj, bf16-weight fast path (m97 structure).
// ---------------------------------------------------------------------------
__global__ __launch_bounds__(256, 3) void moe_w2b_k(const u16* __restrict__ gbuf,
                                                    const u16* __restrict__ w2b,
                                                    float* __restrict__ out,
                                                    const int* __restrict__ cnt,
                                                    const int* __restrict__ seg,
                                                    const int* __restrict__ texp,
                                                    const int* __restrict__ ttot,
                                                    const int* __restrict__ idxl,
                                                    const float* __restrict__ gvl) {
    int by = blockIdx.y;
    if (by >= *ttot) return;
    int e = texp[by];
    const u16* w2e = w2b + (size_t)e * Cq * HDq;
    int cnte = cnt[e], sege = seg[e];
    const int* idxe = idxl + e * NTOK;
    const float* gve = gvl + e * NTOK;

    __shared__ u16 As[2][128*32], Bs[2][128*32];   // 32 KiB
    int tid = threadIdx.x;
    int wave = tid >> 6, lane = tid & 63;
    int wm = wave >> 1, wn = wave & 1;
    int bx = blockIdx.x;
    int srow = tid >> 2, sch = (tid & 3) * 8;

    const u16* A0 = gbuf + (size_t)(by*128 + srow) * HDq + sch;
    const u16* A1 = A0 + (size_t)64 * HDq;
    const u16* W0 = w2e + (size_t)(bx*128 + srow) * HDq + sch;
    const u16* W1 = W0 + (size_t)64 * HDq;
    int lo0 = srow*32 + sch, lo1 = lo0 + 2048;

    f32x4v acc[4][4];
    #pragma unroll
    for (int i = 0; i < 4; i++)
        #pragma unroll
        for (int j = 0; j < 4; j++)
            #pragma unroll
            for (int r = 0; r < 4; r++) acc[i][j][r] = 0.0f;

    stage16(A0, &As[0][lo0]); stage16(A1, &As[0][lo1]);
    stage16(W0, &Bs[0][lo0]); stage16(W1, &Bs[0][lo1]);

    int fr = lane & 15, fk = (lane >> 4) * 8;
    int cur = 0;
    for (int k0 = 0; k0 < HDq; k0 += 32, cur ^= 1) {
        __syncthreads();
        int kn = k0 + 32;
        if (kn < HDq) {
            stage16(A0 + kn, &As[cur^1][lo0]); stage16(A1 + kn, &As[cur^1][lo1]);
            stage16(W0 + kn, &Bs[cur^1][lo0]); stage16(W1 + kn, &Bs[cur^1][lo1]);
        }
        bf16x8 af[4];
        #pragma unroll
        for (int mi = 0; mi < 4; mi++)
            af[mi] = *(const bf16x8*)&As[cur][(wm*64 + mi*16 + fr) * 32 + fk];
        #pragma unroll
        for (int ni = 0; ni < 4; ni++) {
            bf16x8 bf_ = *(const bf16x8*)&Bs[cur][(wn*64 + ni*16 + fr) * 32 + fk];
            #pragma unroll
            for (int mi = 0; mi < 4; mi++)
                acc[mi][ni] = __builtin_amdgcn_mfma_f32_16x16x32_bf16(af[mi], bf_, acc[mi][ni], 0, 0, 0);
        }
    }

    int cr = (lane >> 4) * 4, cc = lane & 15;
    #pragma unroll
    for (int mi = 0; mi < 4; mi++)
        #pragma unroll
        for (int r = 0; r < 4; r++) {
            int row = by*128 + wm*64 + mi*16 + cr + r;
            int local = row - sege;
            if (local < cnte) {
                int token = idxe[local];
                float g = gve[local];
                #pragma unroll
                for (int ni = 0; ni < 4; ni++) {
                    int col = bx*128 + wn*64 + ni*16 + cc;
                    atomicAdd(&out[(size_t)token * Cq + col], g * acc[mi][ni][r]);
                }
            }
        }
}

// ---------------------------------------------------------------------------
// MoE fp32-weight fallbacks (ws too small for bf16 planes).
// ---------------------------------------------------------------------------
__global__ __launch_bounds__(256, 2) void moe_w13(const u16* __restrict__ hnb,
                                                  const float* __restrict__ w1,
                                                  const float* __restrict__ w3,
                                                  u16* __restrict__ gbuf,
                                                  const int* __restrict__ cnt,
                                                  const int* __restrict__ seg,
                                                  const int* __restrict__ texp,
                                                  const int* __restrict__ ttot,
                                                  const int* __restrict__ idxl) {
    int by = blockIdx.y;
    if (by >= *ttot) return;
    int e = texp[by];
    const float* w1e = w1 + (size_t)e * HDq * Cq;
    const float* w3e = w3 + (size_t)e * HDq * Cq;
    int cnte = cnt[e], sege = seg[e];
    const int* idxe = idxl + e * NTOK;

    __shared__ u16 As[2][128*32], B1S[128*32], B3S[128*32];
    int tid = threadIdx.x;
    int wave = tid >> 6, lane = tid & 63;
    int wm = wave >> 1, wn = wave & 1;
    int bx = blockIdx.x;
    int srow = tid >> 2, sch = (tid & 3) * 8;

    int r0 = by*128 + srow, r1 = r0 + 64;
    int li0 = r0 - sege, li1 = r1 - sege;
    int tok0 = idxe[li0 < cnte ? li0 : 0];
    int tok1 = idxe[li1 < cnte ? li1 : 0];
    const u16* A0 = hnb + (size_t)tok0 * Cq + sch;
    const u16* A1 = hnb + (size_t)tok1 * Cq + sch;
    const float* W10 = w1e + (size_t)(bx*128 + srow) * Cq + sch;
    const float* W11 = W10 + (size_t)64 * Cq;
    const float* W30 = w3e + (size_t)(bx*128 + srow) * Cq + sch;
    const float* W31 = W30 + (size_t)64 * Cq;
    int lo0 = srow*32 + sch, lo1 = lo0 + 2048;

    f32x4v acc1[4][4], acc3[4][4];
    #pragma unroll
    for (int i = 0; i < 4; i++)
        #pragma unroll
        for (int j = 0; j < 4; j++)
            #pragma unroll
            for (int r = 0; r < 4; r++) { acc1[i][j][r] = 0.0f; acc3[i][j][r] = 0.0f; }

    float x1a[8], x1b[8], x3a[8], x3b[8];
    stage16(A0, &As[0][lo0]);
    stage16(A1, &As[0][lo1]);
    *(float4*)&x1a[0] = *(const float4*)(W10);
    *(float4*)&x1a[4] = *(const float4*)(W10 + 4);
    *(float4*)&x1b[0] = *(const float4*)(W11);
    *(float4*)&x1b[4] = *(const float4*)(W11 + 4);
    *(float4*)&x3a[0] = *(const float4*)(W30);
    *(float4*)&x3a[4] = *(const float4*)(W30 + 4);
    *(float4*)&x3b[0] = *(const float4*)(W31);
    *(float4*)&x3b[4] = *(const float4*)(W31 + 4);

    int fr = lane & 15, fk = (lane >> 4) * 8;
    int cur = 0;
    for (int k0 = 0; k0 < Cq; k0 += 32, cur ^= 1) {
        __syncthreads();
        {
            u16 t0[8], t1[8], t2[8], t3[8];
            #pragma unroll
            for (int i = 0; i < 8; i++) {
                t0[i] = f2bf(x1a[i]); t1[i] = f2bf(x1b[i]);
                t2[i] = f2bf(x3a[i]); t3[i] = f2bf(x3b[i]);
            }
            *(uint4*)&B1S[lo0] = *(uint4*)t0;
            *(uint4*)&B1S[lo1] = *(uint4*)t1;
            *(uint4*)&B3S[lo0] = *(uint4*)t2;
            *(uint4*)&B3S[lo1] = *(uint4*)t3;
        }
        __syncthreads();
        int kn = k0 + 32;
        if (kn < Cq) {
            stage16(A0 + kn, &As[cur^1][lo0]);
            stage16(A1 + kn, &As[cur^1][lo1]);
            *(float4*)&x1a[0] = *(const float4*)(W10 + kn);
            *(float4*)&x1a[4] = *(const float4*)(W10 + kn + 4);
            *(float4*)&x1b[0] = *(const float4*)(W11 + kn);
            *(float4*)&x1b[4] = *(const float4*)(W11 + kn + 4);
            *(float4*)&x3a[0] = *(const float4*)(W30 + kn);
            *(float4*)&x3a[4] = *(const float4*)(W30 + kn + 4);
            *(float4*)&x3b[0] = *(const float4*)(W31 + kn);
            *(float4*)&x3b[4] = *(const float4*)(W31 + kn + 4);
        }
        bf16x8 af[4];
        #pragma unroll
        for (int mi = 0; mi < 4; mi++)
            af[mi] = *(const bf16x8*)&As[cur][(wm*64 + mi*16 + fr) * 32 + fk];
        #pragma unroll
        for (int ni = 0; ni < 4; ni++) {
            bf16x8 b1f = *(const bf16x8*)&B1S[(wn*64 + ni*16 + fr) * 32 + fk];
            bf16x8 b3f = *(const bf16x8*)&B3S[(wn*64 + ni*16 + fr) * 32 + fk];
            #pragma unroll
            for (int mi = 0; mi < 4; mi++) {
                acc1[mi][ni] = __builtin_amdgcn_mfma_f32_16x16x32_bf16(af[mi], b1f, acc1[mi][ni], 0, 0, 0);
                acc3[mi][ni] = __builtin_amdgcn_mfma_f32_16x16x32_bf16(af[mi], b3f, acc3[mi][ni], 0, 0, 0);
            }
        }
    }

    int cr = (lane >> 4) * 4, cc = lane & 15;
    #pragma unroll
    for (int mi = 0; mi < 4; mi++)
        #pragma unroll
        for (int ni = 0; ni < 4; ni++)
            #pragma unroll
            for (int r = 0; r < 4; r++) {
                int row = by*128 + wm*64 + mi*16 + cr + r;
                int col = bx*128 + wn*64 + ni*16 + cc;
                gbuf[(size_t)row * HDq + col] = f2bf(silu_f(acc1[mi][ni][r]) * acc3[mi][ni][r]);
            }
}

__global__ __launch_bounds__(256, 3) void moe_w2(const u16* __restrict__ gbuf,
                                                 const float* __restrict__ w2,
                                                 float* __restrict__ out,
                                                 const int* __restrict__ cnt,
                                                 const int* __restrict__ seg,
                                                 const int* __restrict__ texp,
                                                 const int* __restrict__ ttot,
                                                 const int* __restrict__ idxl,
                                                 const float* __restrict__ gvl) {
    int by = blockIdx.y;
    if (by >= *ttot) return;
    int e = texp[by];
    const float* w2e = w2 + (size_t)e * Cq * HDq;
    int cnte = cnt[e], sege = seg[e];
    const int* idxe = idxl + e * NTOK;
    const float* gve = gvl + e * NTOK;

    __shared__ u16 As[2][128*32], Bs[128*32];
    int tid = threadIdx.x;
    int wave = tid >> 6, lane = tid & 63;
    int wm = wave >> 1, wn = wave & 1;
    int bx = blockIdx.x;
    int srow = tid >> 2, sch = (tid & 3) * 8;

    const u16* A0 = gbuf + (size_t)(by*128 + srow) * HDq + sch;
    const u16* A1 = A0 + (size_t)64 * HDq;
    const float* W0 = w2e + (size_t)(bx*128 + srow) * HDq + sch;
    const float* W1 = W0 + (size_t)64 * HDq;
    int lo0 = srow*32 + sch, lo1 = lo0 + 2048;

    f32x4v acc[4][4];
    #pragma unroll
    for (int i = 0; i < 4; i++)
        #pragma unroll
        for (int j = 0; j < 4; j++)
            #pragma unroll
            for (int r = 0; r < 4; r++) acc[i][j][r] = 0.0f;

    float xa[8], xb[8];
    stage16(A0, &As[0][lo0]);
    stage16(A1, &As[0][lo1]);
    *(float4*)&xa[0] = *(const float4*)(W0);
    *(float4*)&xa[4] = *(const float4*)(W0 + 4);
    *(float4*)&xb[0] = *(const float4*)(W1);
    *(float4*)&xb[4] = *(const float4*)(W1 + 4);

    int fr = lane & 15, fk = (lane >> 4) * 8;
    int cur = 0;
    for (int k0 = 0; k0 < HDq; k0 += 32, cur ^= 1) {
        __syncthreads();
        {
            u16 ta[8], tb[8];
            #pragma unroll
            for (int i = 0; i < 8; i++) { ta[i] = f2bf(xa[i]); tb[i] = f2bf(xb[i]); }
            *(uint4*)&Bs[lo0] = *(uint4*)ta;
            *(uint4*)&Bs[lo1] = *(uint4*)tb;
        }
        __syncthreads();
        int kn = k0 + 32;
        if (kn < HDq) {
            stage16(A0 + kn, &As[cur^1][lo0]);
            stage16(A1 + kn, &As[cur^1][lo1]);
            *(float4*)&xa[0] = *(const float4*)(W0 + kn);
            *(float4*)&xa[4] = *(const float4*)(W0 + kn + 4);
            *(float4*)&xb[0] = *(const float4*)(W1 + kn);
            *(float4*)&xb[4] = *(const float4*)(W1 + kn + 4);
        }
        bf16x8 af[4];
        #pragma unroll
        for (int mi = 0; mi < 4; mi++)
            af[mi] = *(const bf16x8*)&As[cur][(wm*64 + mi*16 + fr) * 32 + fk];
        #pragma unroll
        for (int ni = 0; ni < 4; ni++) {
            bf16x8 bf_ = *(const bf16x8*)&Bs[(wn*64 + ni*16 + fr) * 32 + fk];
            #pragma unroll
            for (int mi = 0; mi < 4; mi++)
                acc[mi][ni] = __builtin_amdgcn_mfma_f32_16x16x32_bf16(af[mi], bf_, acc[mi][ni], 0, 0, 0);
        }
    }

    int cr = (lane >> 4) * 4, cc = lane & 15;
    #pragma unroll
    for (int mi = 0; mi < 4; mi++)
        #pragma unroll
        for (int r = 0; r < 4; r++) {
            int row = by*128 + wm*64 + mi*16 + cr + r;
            int local = row - sege;
            if (local < cnte) {
                int token = idxe[local];
                float g = gve[local];
                #pragma unroll
                for (int ni = 0; ni < 4; ni++) {
                    int col = bx*128 + wn*64 + ni*16 + cc;
                    atomicAdd(&out[(size_t)token * Cq + col], g * acc[mi][ni][r]);
                }
            }
        }
}

// ---------------------------------------------------------------------------
// Launch
// ---------------------------------------------------------------------------
extern "C" void kernel_launch(void* const* d_in, const int* in_sizes, int n_in,
                              void* d_out, int out_size, void* d_ws, size_t ws_size,
                              hipStream_t stream) {
    (void)in_sizes; (void)n_in; (void)out_size;

    const float* x     = (const float*)d_in[0];
    const float* ropec = (const float*)d_in[1];
    const float* ropes = (const float*)d_in[2];
    const float* anw   = (const float*)d_in[3];
    const float* q_w   = (const float*)d_in[4];
    const float* k_w   = (const float*)d_in[5];
    const float* v_w   = (const float*)d_in[6];
    const float* o_w   = (const float*)d_in[7];
    const float* fnw   = (const float*)d_in[8];
    const float* rtw   = (const float*)d_in[9];
    const float* w1    = (const float*)d_in[10];
    const float* w2    = (const float*)d_in[11];
    const float* w3    = (const float*)d_in[12];
    float* out = (float*)d_out;

    // workspace map (MiB offsets):
    //  P1 (QKV): hh@0-8 hl@8-16 | vf fp32@16-32 | qh@32-40 ql@40-48 kh@48-56 kl@56-64
    //  P2 (attn): vth@0-8 vtl@8-16 (vf dead) | yh@16-24 yl@24-32 (after attn)
    //  P3 (MoE): gbuf@0-28 | hn@32-48 hnb@48-56 meta@56-57
    //  pre  (>=136 MiB): MoE bf16 weights w1b@64-88 w3b@88-112 w2b@112-136
    //  pre2 (>=152 MiB): attn f16 weight planes q@136-140 k@140-144 v@144-148 o@148-152
    float* ws = (float*)d_ws;
    u16* hh = (u16*)(ws + MB(0));
    u16* hl = (u16*)(ws + MB(8));
    float* vf = ws + MB(16);
    u16* qh = (u16*)(ws + MB(32));
    u16* ql = (u16*)(ws + MB(40));
    u16* kh = (u16*)(ws + MB(48));
    u16* kl = (u16*)(ws + MB(56));
    u16* vth = (u16*)(ws + MB(0));
    u16* vtl = (u16*)(ws + MB(8));
    u16* yh  = (u16*)(ws + MB(16));
    u16* yl  = (u16*)(ws + MB(24));
    u16* gbuf = (u16*)(ws + MB(0));           // 9216x1536 bf16 = 27 MiB
    float* hn = ws + MB(32);                  // 16 MiB fp32
    u16* hnb  = (u16*)(ws + MB(48));          // 8 MiB
    int* cntp = (int*)(ws + MB(56));
    int* segp = cntp + 8;
    int* texp = cntp + 16;    // 72 entries
    int* ttot = cntp + 96;
    int* idxl = cntp + 256;                   // 8*4096 ints
    float* gvl = (float*)(cntp + 256 + Eq*NTOK);
    u16* w1b = (u16*)(ws + MB(64));           // 24 MiB bf16
    u16* w3b = (u16*)(ws + MB(88));           // 24 MiB bf16
    u16* w2b = (u16*)(ws + MB(112));          // 24 MiB bf16
    u16* wqh = (u16*)(ws + MB(136));          // f16 planes, 2 MiB each
    u16* wql = (u16*)(ws + MB(138));
    u16* wkh = (u16*)(ws + MB(140));
    u16* wkl = (u16*)(ws + MB(142));
    u16* wvh = (u16*)(ws + MB(144));
    u16* wvl = (u16*)(ws + MB(146));
    u16* woh = (u16*)(ws + MB(148));
    u16* wol = (u16*)(ws + MB(150));

    const int M = NTOK;
    const bool pre  = ws_size >= ((size_t)136 << 20);   // MoE bf16 path
    const bool pre2 = ws_size >= ((size_t)152 << 20);   // attn f16-plane path

    // 0. merged weight prep (one launch; y=3 slice only when pre2 fits)
    if (pre)
        hipLaunchKernelGGL(wprep_k, dim3(6144, pre2 ? 4 : 3), dim3(256), 0, stream,
                           w1, w3, w2, q_w, k_w, v_w, o_w,
                           w1b, w3b, w2b,
                           wqh, wql, wkh, wkl, wvh, wvl, woh, wol);

    // 1. attn rmsnorm -> split hi/lo
    hipLaunchKernelGGL(rmsnorm_split_k, dim3(M), dim3(256), 0, stream, x, anw, hh, hl);

    // 2. fused Q,K,V projection + RoPE + split epilogues (V -> fp32 vf)
    if (pre2)
        hipLaunchKernelGGL(gemm_fused2, dim3(24, M/128), dim3(256), 0, stream,
                           hh, hl, wqh, wql, wkh, wkl, wvh, wvl,
                           qh, ql, kh, kl, vf,
                           ropec, ropes, (const float*)nullptr, (float*)nullptr, 0);
    else
        hipLaunchKernelGGL(gemm_fused, dim3(24, M/128), dim3(256), 0, stream,
                           hh, hl, q_w, k_w, v_w, qh, ql, kh, kl, vf,
                           ropec, ropes, (const float*)nullptr, (float*)nullptr, 0);

    // 3. V transpose+split -> vth/vtl (hh/hl region, dead)
    hipLaunchKernelGGL(vtrans_k, dim3(32, 32), dim3(256), 0, stream, vf, vth, vtl);

    // 4. flash attention (swapped-QK^T, 1024 blocks = 4/CU, LPT order) -> yh/yl
    hipLaunchKernelGGL(attn_f16, dim3(1024), dim3(256), 0, stream,
                       qh, ql, kh, kl, vth, vtl, yh, yl);

    // 5. O projection + residual -> out
    if (pre2)
        hipLaunchKernelGGL(gemm_fused2, dim3(8, M/128), dim3(256), 0, stream,
                           yh, yl, woh, wol,
                           (const u16*)nullptr, (const u16*)nullptr,
                           (const u16*)nullptr, (const u16*)nullptr,
                           (u16*)nullptr, (u16*)nullptr, (u16*)nullptr, (u16*)nullptr,
                           (float*)nullptr, ropec, ropes, x, out, 1);
    else
        hipLaunchKernelGGL(gemm_fused, dim3(8, M/128), dim3(256), 0, stream,
                           yh, yl, o_w, (const float*)nullptr, (const float*)nullptr,
                           (u16*)nullptr, (u16*)nullptr, (u16*)nullptr, (u16*)nullptr,
                           (float*)nullptr, ropec, ropes, x, out, 1);

    // 6. ffn rmsnorm -> hn fp32 + hnb bf16 (+ zero expert counters)
    hipLaunchKernelGGL(rmsnorm2_k, dim3(M), dim3(256), 0, stream, out, fnw, hn, hnb, cntp);

    // 7. router (fp32) -> per-expert lists; then tile table
    hipLaunchKernelGGL(router_k, dim3(M), dim3(64), 0, stream, hn, rtw, cntp, idxl, gvl);
    hipLaunchKernelGGL(setup_k, dim3(1), dim3(64), 0, stream, cntp, segp, texp, ttot);

    // 8. MoE over gathered tokens
    if (pre) {
        hipLaunchKernelGGL(moe_w13b, dim3(HDq/128, 72), dim3(256), 0, stream,
                           hnb, w1b, w3b, gbuf, cntp, segp, texp, ttot, idxl);
        hipLaunchKernelGGL(moe_w2b_k, dim3(Cq/128, 72), dim3(256), 0, stream,
                           gbuf, w2b, out, cntp, segp, texp, ttot, idxl, gvl);
    } else {
        hipLaunchKernelGGL(moe_w13, dim3(HDq/128, 72), dim3(256), 0, stream,
                           hnb, w1, w3, gbuf, cntp, segp, texp, ttot, idxl);
        hipLaunchKernelGGL(moe_w2, dim3(Cq/128, 72), dim3(256), 0, stream,
                           gbuf, w2, out, cntp, segp, texp, ttot, idxl, gvl);
    }
}